// Round 5
// baseline (545.165 us; speedup 1.0000x reference)
//
#include <hip/hip_runtime.h>
#include <stdint.h>

// LocalWindowAttention: B=2,T=4096,D=2048,H=16,HK=4,HD=128,WIN=512
// R7: attn occupancy + pipeline rework (R6 attn was flat: latency-bound at
//     2 blocks/CU, not VALU-bound):
//     (1) single-buffer V -> LDS 64->48KB -> 3 blocks/CU (launch_bounds 256,3).
//         New wait discipline: top vmcnt(8) drains K[ci]; mid vmcnt(4) drains
//         V[ci] (staged at top of its own iter, lands under S+softmax); last
//         iter 4/0. No more vmcnt(0) full drain per chunk (T4).
//     (2) Q pre-scaled by scale*log2(e); exp via raw v_exp_f32 (=exp2) ->
//         no per-element log2e mul. Defer-gate threshold 8 in log2 units.
//     (3) interior-chunk fast path: only doff in {0,64} chunks are partially
//         masked (4 of ~10); others skip the mask pass (uniform branch).
//     GEMMs unchanged from R6.

typedef unsigned short u16;
typedef __attribute__((ext_vector_type(8))) short frag8;   // 8 bf16 = 4 VGPRs
typedef __attribute__((ext_vector_type(4))) float f32x4;   // MFMA acc

#define TILE 128

__device__ __forceinline__ u16 f2bf(float f) {
  union { float f; unsigned u; } c; c.f = f;
  unsigned u = c.u;
  return (u16)((u + 0x7fffu + ((u >> 16) & 1u)) >> 16);
}

__device__ __forceinline__ float fexp2(float x) {  // D = 2^S0 (v_exp_f32)
  float r;
  asm("v_exp_f32 %0, %1" : "=v"(r) : "v"(x));
  return r;
}

// async global->LDS, 16B per lane; LDS dest = wave-uniform base + lane*16
__device__ __forceinline__ void async16(const u16* g, u16* l) {
  __builtin_amdgcn_global_load_lds((const __attribute__((address_space(1))) void*)g,
                                   (__attribute__((address_space(3))) void*)l, 16, 0, 0);
}

// T1: XCD-chunked remap. Requires gridDim.x % 8 == 0.
__device__ __forceinline__ void xcd_map(int& bx, int& by) {
  const int gx = gridDim.x;
  const int cx = gx >> 3;
  int id = blockIdx.y * gx + blockIdx.x;
  int xcd = id & 7, local = id >> 3;
  bx = xcd * cx + (local % cx);
  by = local / cx;
}

// ======================= 256^2 4-phase GEMM ==============================
template <typename OutT>
__global__ __launch_bounds__(512, 2) void k_gemm256(const u16* __restrict__ A, int lda,
                                                    const u16* __restrict__ Bt, int ldb,
                                                    OutT* __restrict__ C, int ldc, int K,
                                                    float oscale) {
  __shared__ alignas(16) u16 Ab[2][256 * 64];  // 64 KB
  __shared__ alignas(16) u16 Bb[2][256 * 64];  // 64 KB
  const int tid = threadIdx.x, lane = tid & 63, wave = tid >> 6;
  const int wm = wave >> 2, wn = wave & 3;     // 2M x 4N wave grid
  const int quad = lane >> 4, l16 = lane & 15;

  int bx, by;
  xcd_map(bx, by);

  // staging coords: issue c, wave w, lane l -> row = c*64+w*8+(l>>3),
  // src col = ((l&7)^(l>>3))*8  (row&7 == l>>3 -> involution holds)
  const int rsub = wave * 8 + (lane >> 3);
  const int csub = ((lane & 7) ^ (lane >> 3)) * 8;
  const u16* Ag = A + ((long)bx * 256 + rsub) * lda + csub;
  const u16* Bg = Bt + ((long)by * 256 + rsub) * ldb + csub;
  const long a64 = (long)64 * lda, b64 = (long)64 * ldb;

  const int rsw = (l16 & 7) << 3;  // read-side XOR (u16 units)

  f32x4 acc[8][4];
#pragma unroll
  for (int i = 0; i < 8; ++i)
#pragma unroll
    for (int j = 0; j < 4; ++j) acc[i][j] = (f32x4){0.f, 0.f, 0.f, 0.f};

  const int nt = K >> 6;

  // prologue: stage tile 0 (8 inst/wave)
#pragma unroll
  for (int c = 0; c < 4; ++c) {
    async16(Ag + c * a64, &Ab[0][c * 4096 + wave * 512]);
    async16(Bg + c * b64, &Bb[0][c * 4096 + wave * 512]);
  }

  for (int t = 0; t < nt; ++t) {
    const int buf = t & 1, nb = buf ^ 1;
    const long koff = (long)(t + 1) << 6;
    frag8 af[4][2], bf[2][2];

    // ---- phase 0: issue ALL next-tile loads, then drain tile t ----------
    if (t + 1 < nt) {
#pragma unroll
      for (int c = 0; c < 4; ++c) {
        async16(Ag + c * a64 + koff, &Ab[nb][c * 4096 + wave * 512]);
        async16(Bg + c * b64 + koff, &Bb[nb][c * 4096 + wave * 512]);
      }
      asm volatile("s_waitcnt vmcnt(8)" ::: "memory");  // tile t fully landed
    } else {
      asm volatile("s_waitcnt vmcnt(0)" ::: "memory");
    }
    __builtin_amdgcn_s_barrier();
    asm volatile("" ::: "memory");

    // quadrant (M0, N0)
#pragma unroll
    for (int i = 0; i < 4; ++i)
#pragma unroll
      for (int kk = 0; kk < 2; ++kk)
        af[i][kk] = *(const frag8*)(&Ab[buf][(wm * 128 + i * 16 + l16) * 64 +
                                             ((kk * 32 + quad * 8) ^ rsw)]);
#pragma unroll
    for (int j = 0; j < 2; ++j)
#pragma unroll
      for (int kk = 0; kk < 2; ++kk)
        bf[j][kk] = *(const frag8*)(&Bb[buf][(wn * 64 + j * 16 + l16) * 64 +
                                             ((kk * 32 + quad * 8) ^ rsw)]);
    __builtin_amdgcn_s_setprio(1);
#pragma unroll
    for (int kk = 0; kk < 2; ++kk)
#pragma unroll
      for (int i = 0; i < 4; ++i)
#pragma unroll
        for (int j = 0; j < 2; ++j)
          acc[i][j] = __builtin_amdgcn_mfma_f32_16x16x32_bf16(af[i][kk], bf[j][kk], acc[i][j], 0, 0, 0);
    __builtin_amdgcn_s_setprio(0);
    __builtin_amdgcn_s_barrier();

    // quadrant (M0, N1) — reuse af
#pragma unroll
    for (int j = 0; j < 2; ++j)
#pragma unroll
      for (int kk = 0; kk < 2; ++kk)
        bf[j][kk] = *(const frag8*)(&Bb[buf][(wn * 64 + (j + 2) * 16 + l16) * 64 +
                                             ((kk * 32 + quad * 8) ^ rsw)]);
    __builtin_amdgcn_s_setprio(1);
#pragma unroll
    for (int kk = 0; kk < 2; ++kk)
#pragma unroll
      for (int i = 0; i < 4; ++i)
#pragma unroll
        for (int j = 0; j < 2; ++j)
          acc[i][j + 2] = __builtin_amdgcn_mfma_f32_16x16x32_bf16(af[i][kk], bf[j][kk], acc[i][j + 2], 0, 0, 0);
    __builtin_amdgcn_s_setprio(0);
    __builtin_amdgcn_s_barrier();

    // quadrant (M1, N0)
#pragma unroll
    for (int i = 0; i < 4; ++i)
#pragma unroll
      for (int kk = 0; kk < 2; ++kk)
        af[i][kk] = *(const frag8*)(&Ab[buf][(wm * 128 + (i + 4) * 16 + l16) * 64 +
                                             ((kk * 32 + quad * 8) ^ rsw)]);
#pragma unroll
    for (int j = 0; j < 2; ++j)
#pragma unroll
      for (int kk = 0; kk < 2; ++kk)
        bf[j][kk] = *(const frag8*)(&Bb[buf][(wn * 64 + j * 16 + l16) * 64 +
                                             ((kk * 32 + quad * 8) ^ rsw)]);
    __builtin_amdgcn_s_setprio(1);
#pragma unroll
    for (int kk = 0; kk < 2; ++kk)
#pragma unroll
      for (int i = 0; i < 4; ++i)
#pragma unroll
        for (int j = 0; j < 2; ++j)
          acc[i + 4][j] = __builtin_amdgcn_mfma_f32_16x16x32_bf16(af[i][kk], bf[j][kk], acc[i + 4][j], 0, 0, 0);
    __builtin_amdgcn_s_setprio(0);
    __builtin_amdgcn_s_barrier();

    // quadrant (M1, N1) — reuse af
#pragma unroll
    for (int j = 0; j < 2; ++j)
#pragma unroll
      for (int kk = 0; kk < 2; ++kk)
        bf[j][kk] = *(const frag8*)(&Bb[buf][(wn * 64 + (j + 2) * 16 + l16) * 64 +
                                             ((kk * 32 + quad * 8) ^ rsw)]);
    __builtin_amdgcn_s_setprio(1);
#pragma unroll
    for (int kk = 0; kk < 2; ++kk)
#pragma unroll
      for (int i = 0; i < 4; ++i)
#pragma unroll
        for (int j = 0; j < 2; ++j)
          acc[i + 4][j + 2] = __builtin_amdgcn_mfma_f32_16x16x32_bf16(af[i][kk], bf[j][kk], acc[i + 4][j + 2], 0, 0, 0);
    __builtin_amdgcn_s_setprio(0);
    __builtin_amdgcn_s_barrier();
  }

  // epilogue (oscale folded; used to pre-scale Q)
  OutT* Ct = C + ((long)bx * 256 + wm * 128) * ldc + (long)by * 256 + wn * 64;
#pragma unroll
  for (int i = 0; i < 8; ++i)
#pragma unroll
    for (int j = 0; j < 4; ++j) {
      int r0 = i * 16 + quad * 4, cc = j * 16 + l16;
#pragma unroll
      for (int r = 0; r < 4; ++r) {
        float v = acc[i][j][r] * oscale;
        if constexpr (sizeof(OutT) == 2)
          Ct[(long)(r0 + r) * ldc + cc] = f2bf(v);
        else
          Ct[(long)(r0 + r) * ldc + cc] = v;
      }
    }
}

// ---- 128x128 GEMM core, double-buffered + counted vmcnt (T3-min) --------
__device__ __forceinline__ void gemm_core(const u16* __restrict__ A, int lda,
                                          const u16* __restrict__ Bt, int ldb,
                                          int K, u16* As, u16* Bs, f32x4 acc[4][4]) {
  const int tid = threadIdx.x;
  const int lane = tid & 63, wave = tid >> 6;
  const int wr = wave >> 1, wc = wave & 1;
  const int quad = lane >> 4, l16 = lane & 15;
#pragma unroll
  for (int i = 0; i < 4; ++i)
#pragma unroll
    for (int j = 0; j < 4; ++j) acc[i][j] = (f32x4){0.f, 0.f, 0.f, 0.f};

  const int row0 = tid >> 2, offc = (tid & 3) * 8;  // 128 rows x 32 k, 16B chunks
  const int nt = K >> 5;

  // prologue: tile 0
#pragma unroll
  for (int r = 0; r < 2; ++r) {
    int row = r * 64 + row0;
    async16(A + (long)row * lda + offc, As + r * 2048 + wave * 512);
    async16(Bt + (long)row * ldb + offc, Bs + r * 2048 + wave * 512);
  }

  for (int t = 0; t < nt; ++t) {
    const int bo = (t & 1) * 4096, nbo = bo ^ 4096;
    if (t + 1 < nt) {
      const int k0 = (t + 1) * 32;
#pragma unroll
      for (int r = 0; r < 2; ++r) {
        int row = r * 64 + row0;
        async16(A + (long)row * lda + k0 + offc, As + nbo + r * 2048 + wave * 512);
        async16(Bt + (long)row * ldb + k0 + offc, Bs + nbo + r * 2048 + wave * 512);
      }
      asm volatile("s_waitcnt vmcnt(4)" ::: "memory");  // tile t landed
    } else {
      asm volatile("s_waitcnt vmcnt(0)" ::: "memory");
    }
    __builtin_amdgcn_s_barrier();
    asm volatile("" ::: "memory");

    frag8 af[4], bf[4];
#pragma unroll
    for (int i = 0; i < 4; ++i)
      af[i] = *(const frag8*)(As + bo + (wr * 64 + i * 16 + l16) * 32 + quad * 8);
#pragma unroll
    for (int j = 0; j < 4; ++j)
      bf[j] = *(const frag8*)(Bs + bo + (wc * 64 + j * 16 + l16) * 32 + quad * 8);
#pragma unroll
    for (int i = 0; i < 4; ++i)
#pragma unroll
      for (int j = 0; j < 4; ++j)
        acc[i][j] = __builtin_amdgcn_mfma_f32_16x16x32_bf16(af[i], bf[j], acc[i][j], 0, 0, 0);
    asm volatile("" ::: "memory");
    __builtin_amdgcn_s_barrier();  // all reads of buf done before restage
  }
}

#define EPI_COORDS                                             \
  const int lane = threadIdx.x & 63, wave = threadIdx.x >> 6;  \
  const int wr = wave >> 1, wc = wave & 1;                     \
  const int quad = lane >> 4, l16 = lane & 15;

__global__ __launch_bounds__(256) void k_gemm_bf16(const u16* __restrict__ A, int lda,
                                                   const u16* __restrict__ Bt, int ldb,
                                                   u16* __restrict__ C, int ldc, int K) {
  __shared__ alignas(16) u16 smem[4 * TILE * 32];  // 2 bufs x (A,B)
  int bx, by; xcd_map(bx, by);
  f32x4 acc[4][4];
  gemm_core(A + (long)bx * TILE * lda, lda,
            Bt + (long)by * TILE * ldb, ldb, K, smem, smem + 2 * TILE * 32, acc);
  EPI_COORDS
  u16* Ct = C + (long)bx * TILE * ldc + (long)by * TILE;
#pragma unroll
  for (int i = 0; i < 4; ++i)
#pragma unroll
    for (int j = 0; j < 4; ++j) {
      int r0 = wr * 64 + i * 16 + quad * 4, cc = wc * 64 + j * 16 + l16;
#pragma unroll
      for (int r = 0; r < 4; ++r) Ct[(long)(r0 + r) * ldc + cc] = f2bf(acc[i][j][r]);
    }
}

// writes C^T: contiguous 4-element store per acc tile (for V^T layout)
__global__ __launch_bounds__(256) void k_gemm_bf16t(const u16* __restrict__ A, int lda,
                                                    const u16* __restrict__ Bt, int ldb,
                                                    u16* __restrict__ Ct, int ldct, int K) {
  __shared__ alignas(16) u16 smem[4 * TILE * 32];
  int bx, by; xcd_map(bx, by);
  f32x4 acc[4][4];
  gemm_core(A + (long)bx * TILE * lda, lda,
            Bt + (long)by * TILE * ldb, ldb, K, smem, smem + 2 * TILE * 32, acc);
  EPI_COORDS
  u16* Cb = Ct + (long)by * TILE * ldct + (long)bx * TILE;
#pragma unroll
  for (int i = 0; i < 4; ++i)
#pragma unroll
    for (int j = 0; j < 4; ++j) {
      int n = wc * 64 + j * 16 + l16, m0 = wr * 64 + i * 16 + quad * 4;
      ushort4 o;
      o.x = f2bf(acc[i][j][0]); o.y = f2bf(acc[i][j][1]);
      o.z = f2bf(acc[i][j][2]); o.w = f2bf(acc[i][j][3]);
      *(ushort4*)(Cb + (long)n * ldct + m0) = o;
    }
}

// ---- fused local-window attention --------------------------------------
// Q arrives pre-scaled by scale*log2(e); softmax in exp2 domain.
// LDS 48KB: K double-buffered (2x16KB), V single (16KB) -> 3 blocks/CU.
// Per-iter wait discipline (counted, never a full drain mid-loop):
//   top:  [ci>c0: issue V[ci]] [ci<c1: issue K[ci+1]] vmcnt(8|4) barrier
//   mid:  vmcnt(4|0) barrier  (V[ci] landed; S reads of Ks[cur] done)
//   end:  barrier             (PV reads of Vs/P done -> restage safe)
__global__ __launch_bounds__(256, 3) void k_attn(const u16* __restrict__ qb,
                                                 const u16* __restrict__ kb,
                                                 const u16* __restrict__ vT,
                                                 u16* __restrict__ O) {
  __shared__ alignas(16) u16 Ks[2][64 * 128];  // [key][hd]; P overlays cur after S
  __shared__ alignas(16) u16 Vs[128 * 64];     // [hd][key], single buffer
  const int tid = threadIdx.x, lane = tid & 63, wave = tid >> 6;
  const int quad = lane >> 4, l16 = lane & 15;

  // XCD-group decode: 16 siblings sharing (b,hk,blk) land on one XCD
  const int id = blockIdx.x + 4 * blockIdx.y + 32 * blockIdx.z;  // 0..1023
  const int g = (id & 7) | ((id >> 7) << 3);                     // group 0..63
  const int w = (id >> 3) & 15;                                  // member 0..15
  const int hk = g & 3, blk = (g >> 2) & 7, b = g >> 5;
  const int h = hk * 4 + (w & 3), qi = w >> 2;

  const long tok_q = (long)b * 4096 + blk * 512 + qi * 128;

  frag8 qf[2][4];
#pragma unroll
  for (int i = 0; i < 2; ++i)
#pragma unroll
    for (int kt = 0; kt < 4; ++kt)
      qf[i][kt] = *(const frag8*)(qb + (tok_q + wave * 32 + i * 16 + l16) * 2048 +
                                  h * 128 + kt * 32 + quad * 8);

  f32x4 o_acc[2][8];
  float m_r[2][4], l_r[2][4];
#pragma unroll
  for (int i = 0; i < 2; ++i) {
#pragma unroll
    for (int j = 0; j < 8; ++j) o_acc[i][j] = (f32x4){0.f, 0.f, 0.f, 0.f};
#pragma unroll
    for (int r = 0; r < 4; ++r) { m_r[i][r] = -1e30f; l_r[i][r] = 0.f; }
  }

  const int rsw = (l16 & 7) << 3;  // read-side XOR (u16)

  auto stageK = [&](int buf, int ci) {
    const long tk = (long)b * 4096 + (blk - 1) * 512 + ci * 64;
#pragma unroll
    for (int c = 0; c < 4; ++c) {
      const int idx = (wave * 4 + c) * 512 + lane * 8;  // u16 index, linear
      int row = idx >> 7, col = idx & 127;
      async16(kb + (tk + row) * 512 + hk * 128 + (col ^ ((row & 7) << 3)),
              &Ks[buf][(wave * 4 + c) * 512]);
    }
  };
  auto stageV = [&](int ci) {
    const long tk = (long)b * 4096 + (blk - 1) * 512 + ci * 64;
#pragma unroll
    for (int c = 0; c < 4; ++c) {
      const int idx = (wave * 4 + c) * 512 + lane * 8;
      int row = idx >> 6, col = idx & 63;
      async16(vT + ((long)hk * 128 + row) * 8192 + tk + (col ^ ((row & 7) << 3)),
              &Vs[(wave * 4 + c) * 512]);
    }
  };

  const int c0 = blk ? 2 * qi : 8, c1 = 9 + 2 * qi;
  int cur = 0;
  stageK(0, c0);
  stageV(c0);
  asm volatile("s_waitcnt vmcnt(0)" ::: "memory");
  __builtin_amdgcn_s_barrier();
  asm volatile("" ::: "memory");

  for (int ci = c0; ci <= c1; ++ci) {
    if (ci > c0) stageV(ci);              // Vs freed by prev end barrier
    if (ci < c1) {
      stageK(cur ^ 1, ci + 1);            // K prefetch into the free buffer
      asm volatile("s_waitcnt vmcnt(8)" ::: "memory");  // own K[ci] landed
    } else {
      asm volatile("s_waitcnt vmcnt(4)" ::: "memory");  // drain K[c1], keep V[c1]
    }
    __builtin_amdgcn_s_barrier();         // all waves' K[ci] landed
    asm volatile("" ::: "memory");

    // S = Q @ K^T  (32 rows x 64 keys per wave)
    f32x4 s_acc[2][4];
#pragma unroll
    for (int i = 0; i < 2; ++i)
#pragma unroll
      for (int j = 0; j < 4; ++j) s_acc[i][j] = (f32x4){0.f, 0.f, 0.f, 0.f};
#pragma unroll
    for (int kt = 0; kt < 4; ++kt) {
      frag8 bfr[4];
#pragma unroll
      for (int j = 0; j < 4; ++j)
        bfr[j] = *(const frag8*)(&Ks[cur][(j * 16 + l16) * 128 + ((kt * 32 + quad * 8) ^ rsw)]);
#pragma unroll
      for (int i = 0; i < 2; ++i)
#pragma unroll
        for (int j = 0; j < 4; ++j)
          s_acc[i][j] = __builtin_amdgcn_mfma_f32_16x16x32_bf16(qf[i][kt], bfr[j], s_acc[i][j], 0, 0, 0);
    }

    // mask + per-row chunk max. Only doff in {0,64} chunks are partial.
    const bool prev = (ci < 8);
    const int doff = (prev ? ci * 64 : (ci - 8) * 64) - qi * 128;
    float mc[2][4];
#pragma unroll
    for (int i = 0; i < 2; ++i)
#pragma unroll
      for (int r = 0; r < 4; ++r) mc[i][r] = -1e30f;
    if (doff >= 0 && doff <= 64) {  // partial chunk: apply mask
#pragma unroll
      for (int i = 0; i < 2; ++i)
#pragma unroll
        for (int j = 0; j < 4; ++j)
#pragma unroll
          for (int r = 0; r < 4; ++r) {
            int rl = wave * 32 + i * 16 + quad * 4 + r;
            int lk = j * 16 + l16;
            bool ok = prev ? (lk + doff > rl) : (lk + doff <= rl);
            float s = ok ? s_acc[i][j][r] : -1e30f;
            s_acc[i][j][r] = s;
            mc[i][r] = fmaxf(mc[i][r], s);
          }
    } else {  // interior: all keys valid
#pragma unroll
      for (int i = 0; i < 2; ++i)
#pragma unroll
        for (int j = 0; j < 4; ++j)
#pragma unroll
          for (int r = 0; r < 4; ++r) mc[i][r] = fmaxf(mc[i][r], s_acc[i][j][r]);
    }
#pragma unroll
    for (int o = 1; o < 16; o <<= 1)
#pragma unroll
      for (int i = 0; i < 2; ++i)
#pragma unroll
        for (int r = 0; r < 4; ++r)
          mc[i][r] = fmaxf(mc[i][r], __shfl_xor(mc[i][r], o));

    // defer-max (T13, log2 domain, THR=8 -> P <= 256)
    bool need = false;
#pragma unroll
    for (int i = 0; i < 2; ++i)
#pragma unroll
      for (int r = 0; r < 4; ++r) need = need || (mc[i][r] > m_r[i][r] + 8.f);
    if (__any(need)) {
      float alpha[2][4];
#pragma unroll
      for (int i = 0; i < 2; ++i)
#pragma unroll
        for (int r = 0; r < 4; ++r) {
          float mn = fmaxf(m_r[i][r], mc[i][r]);
          alpha[i][r] = fexp2(m_r[i][r] - mn);
          m_r[i][r] = mn;
          l_r[i][r] *= alpha[i][r];
        }
#pragma unroll
      for (int i = 0; i < 2; ++i)
#pragma unroll
        for (int j = 0; j < 8; ++j)
#pragma unroll
          for (int r = 0; r < 4; ++r) o_acc[i][j][r] *= alpha[i][r];
    }

    float ps[2][4];
#pragma unroll
    for (int i = 0; i < 2; ++i)
#pragma unroll
      for (int r = 0; r < 4; ++r) ps[i][r] = 0.f;
#pragma unroll
    for (int i = 0; i < 2; ++i)
#pragma unroll
      for (int j = 0; j < 4; ++j)
#pragma unroll
        for (int r = 0; r < 4; ++r) {
          float s = s_acc[i][j][r];
          float e = fexp2(s - m_r[i][r]);
          e = (s == -1e30f) ? 0.f : e;
          s_acc[i][j][r] = e;
          ps[i][r] += e;
        }
#pragma unroll
    for (int o = 1; o < 16; o <<= 1)
#pragma unroll
      for (int i = 0; i < 2; ++i)
#pragma unroll
        for (int r = 0; r < 4; ++r) ps[i][r] += __shfl_xor(ps[i][r], o);
#pragma unroll
    for (int i = 0; i < 2; ++i)
#pragma unroll
      for (int r = 0; r < 4; ++r) l_r[i][r] += ps[i][r];

    // mid: V[ci] landed (own) + all waves done reading Ks[cur] -> P overlay
    if (ci < c1)
      asm volatile("s_waitcnt vmcnt(4)" ::: "memory");  // drain V[ci], keep K[ci+1]
    else
      asm volatile("s_waitcnt vmcnt(0)" ::: "memory");
    __builtin_amdgcn_s_barrier();
    asm volatile("" ::: "memory");

    u16* PsW = &Ks[cur][wave * 2048];
#pragma unroll
    for (int i = 0; i < 2; ++i)
#pragma unroll
      for (int r = 0; r < 4; ++r) {
        int xw = ((quad * 4 + r) & 7) << 3;
#pragma unroll
        for (int j = 0; j < 4; ++j)
          PsW[(i * 16 + quad * 4 + r) * 64 + ((j * 16 + l16) ^ xw)] = f2bf(s_acc[i][j][r]);
      }

#pragma unroll
    for (int kt = 0; kt < 2; ++kt) {
      frag8 pf[2], vf[8];
#pragma unroll
      for (int i = 0; i < 2; ++i)
        pf[i] = *(const frag8*)(PsW + (i * 16 + l16) * 64 + ((kt * 32 + quad * 8) ^ rsw));
#pragma unroll
      for (int j = 0; j < 8; ++j)
        vf[j] = *(const frag8*)(&Vs[(j * 16 + l16) * 64 + ((kt * 32 + quad * 8) ^ rsw)]);
#pragma unroll
      for (int i = 0; i < 2; ++i)
#pragma unroll
        for (int j = 0; j < 8; ++j)
          o_acc[i][j] = __builtin_amdgcn_mfma_f32_16x16x32_bf16(pf[i], vf[j], o_acc[i][j], 0, 0, 0);
    }

    // end: all waves' PV reads of Vs/P done -> next iter may restage
    asm volatile("" ::: "memory");
    __builtin_amdgcn_s_barrier();
    asm volatile("" ::: "memory");
    cur ^= 1;
  }

  float inv[2][4];
#pragma unroll
  for (int i = 0; i < 2; ++i)
#pragma unroll
    for (int r = 0; r < 4; ++r) inv[i][r] = 1.0f / l_r[i][r];
  u16* Ob = &Ks[0][0];  // 32KB contiguous: [128 row][128 u16]
#pragma unroll
  for (int i = 0; i < 2; ++i)
#pragma unroll
    for (int j = 0; j < 8; ++j)
#pragma unroll
      for (int r = 0; r < 4; ++r)
        Ob[(wave * 32 + i * 16 + quad * 4 + r) * 128 + j * 16 + l16] =
            f2bf(o_acc[i][j][r] * inv[i][r]);
  __syncthreads();
#pragma unroll
  for (int p = 0; p < 8; ++p) {
    int idx = p * 256 + tid;
    int row = idx >> 4, col = (idx & 15) * 8;
    *(frag8*)(O + (tok_q + row) * 2048 + h * 128 + col) = *(const frag8*)(Ob + row * 128 + col);
  }
}

__global__ void k_convert(const float4* __restrict__ x, ushort4* __restrict__ xb) {
  int i = blockIdx.x * 256 + threadIdx.x;
  float4 f = x[i];
  ushort4 o;
  o.x = f2bf(f.x); o.y = f2bf(f.y); o.z = f2bf(f.z); o.w = f2bf(f.w);
  xb[i] = o;
}

// W [K,N] fp32 -> W^T [N,K] bf16
__global__ void k_transpose(const float* __restrict__ W, u16* __restrict__ WT, int K, int N) {
  __shared__ float sh[32][33];
  int n0 = blockIdx.x * 32, k0 = blockIdx.y * 32;
  int tx = threadIdx.x, ty = threadIdx.y;  // (32, 8)
#pragma unroll
  for (int i = 0; i < 32; i += 8) sh[ty + i][tx] = W[(long)(k0 + ty + i) * N + n0 + tx];
  __syncthreads();
#pragma unroll
  for (int i = 0; i < 32; i += 8) WT[(long)(n0 + ty + i) * K + k0 + tx] = f2bf(sh[tx][ty + i]);
}

extern "C" void kernel_launch(void* const* d_in, const int* in_sizes, int n_in,
                              void* d_out, int out_size, void* d_ws, size_t ws_size,
                              hipStream_t stream) {
  const float* x  = (const float*)d_in[0];
  const float* Wq = (const float*)d_in[1];
  const float* Wk = (const float*)d_in[2];
  const float* Wv = (const float*)d_in[3];
  const float* Wo = (const float*)d_in[4];
  float* out = (float*)d_out;

  const long BT = 8192, D = 2048, NKV = 512;
  size_t off = 0;
  auto alloc = [&](size_t bytes) -> char* {
    off = (off + 255) & ~(size_t)255;
    char* p = (char*)d_ws + off;
    off += bytes;
    return p;
  };

  u16* xb  = (u16*)alloc((size_t)BT * D * 2);  // reused as attention output
  u16* WqT = (u16*)alloc((size_t)D * D * 2);
  u16* WkT = (u16*)alloc((size_t)NKV * D * 2);
  u16* WvT = (u16*)alloc((size_t)NKV * D * 2);
  u16* WoT = (u16*)alloc((size_t)D * D * 2);
  u16* qb  = (u16*)alloc((size_t)BT * D * 2);
  u16* kb  = (u16*)alloc((size_t)BT * NKV * 2);
  u16* vT  = (u16*)alloc((size_t)NKV * BT * 2);
  u16* Oa  = xb;

  k_convert<<<16384, 256, 0, stream>>>((const float4*)x, (ushort4*)xb);
  dim3 tb(32, 8);
  k_transpose<<<dim3(64, 64), tb, 0, stream>>>(Wq, WqT, 2048, 2048);
  k_transpose<<<dim3(16, 64), tb, 0, stream>>>(Wk, WkT, 2048, 512);
  k_transpose<<<dim3(16, 64), tb, 0, stream>>>(Wv, WvT, 2048, 512);
  k_transpose<<<dim3(64, 64), tb, 0, stream>>>(Wo, WoT, 2048, 2048);

  // Q projection pre-scales by (1/sqrt(HD)) * log2(e)  (softmax in exp2 domain)
  const float qscale = 0.08838834764831845f * 1.4426950408889634f;
  k_gemm256<u16><<<dim3(32, 8), 512, 0, stream>>>(xb, 2048, WqT, 2048, qb, 2048, 2048,
                                                  qscale);
  k_gemm_bf16 <<<dim3(64, 4),  256, 0, stream>>>(xb, 2048, WkT, 2048, kb, 512, 2048);
  k_gemm_bf16t<<<dim3(64, 4),  256, 0, stream>>>(xb, 2048, WvT, 2048, vT, 8192, 2048);

  k_attn<<<dim3(4, 8, 32), 256, 0, stream>>>(qb, kb, vT, Oa);

  k_gemm256<float><<<dim3(32, 8), 512, 0, stream>>>(Oa, 2048, WoT, 2048, out, 2048, 2048,
                                                    1.0f);
}

// Round 6
// 456.094 us; speedup vs baseline: 1.1953x; 1.1953x over previous
//
#include <hip/hip_runtime.h>
#include <stdint.h>

// LocalWindowAttention: B=2,T=4096,D=2048,H=16,HK=4,HD=128,WIN=512
// R8: revert attn to the verified R6 structure (R7's 3-blocks/CU regressed:
//     VGPR 120->84 => scratch spills, and 6 groups/XCD > 4MB L2 => K/V
//     refetch storm, FETCH 31.8->306MB). Kept from R7 (structure-neutral):
//     exp2-domain softmax (Q pre-scaled by scale*log2e, raw v_exp_f32) and
//     the interior-chunk mask fast path. GEMMs unchanged from R6.

typedef unsigned short u16;
typedef __attribute__((ext_vector_type(8))) short frag8;   // 8 bf16 = 4 VGPRs
typedef __attribute__((ext_vector_type(4))) float f32x4;   // MFMA acc

#define TILE 128

__device__ __forceinline__ u16 f2bf(float f) {
  union { float f; unsigned u; } c; c.f = f;
  unsigned u = c.u;
  return (u16)((u + 0x7fffu + ((u >> 16) & 1u)) >> 16);
}

__device__ __forceinline__ float fexp2(float x) {  // D = 2^S0 (v_exp_f32)
  float r;
  asm("v_exp_f32 %0, %1" : "=v"(r) : "v"(x));
  return r;
}

// async global->LDS, 16B per lane; LDS dest = wave-uniform base + lane*16
__device__ __forceinline__ void async16(const u16* g, u16* l) {
  __builtin_amdgcn_global_load_lds((const __attribute__((address_space(1))) void*)g,
                                   (__attribute__((address_space(3))) void*)l, 16, 0, 0);
}

// T1: XCD-chunked remap. Requires gridDim.x % 8 == 0.
__device__ __forceinline__ void xcd_map(int& bx, int& by) {
  const int gx = gridDim.x;
  const int cx = gx >> 3;
  int id = blockIdx.y * gx + blockIdx.x;
  int xcd = id & 7, local = id >> 3;
  bx = xcd * cx + (local % cx);
  by = local / cx;
}

// ======================= 256^2 4-phase GEMM ==============================
template <typename OutT>
__global__ __launch_bounds__(512, 2) void k_gemm256(const u16* __restrict__ A, int lda,
                                                    const u16* __restrict__ Bt, int ldb,
                                                    OutT* __restrict__ C, int ldc, int K,
                                                    float oscale) {
  __shared__ alignas(16) u16 Ab[2][256 * 64];  // 64 KB
  __shared__ alignas(16) u16 Bb[2][256 * 64];  // 64 KB
  const int tid = threadIdx.x, lane = tid & 63, wave = tid >> 6;
  const int wm = wave >> 2, wn = wave & 3;     // 2M x 4N wave grid
  const int quad = lane >> 4, l16 = lane & 15;

  int bx, by;
  xcd_map(bx, by);

  // staging coords: issue c, wave w, lane l -> row = c*64+w*8+(l>>3),
  // src col = ((l&7)^(l>>3))*8  (row&7 == l>>3 -> involution holds)
  const int rsub = wave * 8 + (lane >> 3);
  const int csub = ((lane & 7) ^ (lane >> 3)) * 8;
  const u16* Ag = A + ((long)bx * 256 + rsub) * lda + csub;
  const u16* Bg = Bt + ((long)by * 256 + rsub) * ldb + csub;
  const long a64 = (long)64 * lda, b64 = (long)64 * ldb;

  const int rsw = (l16 & 7) << 3;  // read-side XOR (u16 units)

  f32x4 acc[8][4];
#pragma unroll
  for (int i = 0; i < 8; ++i)
#pragma unroll
    for (int j = 0; j < 4; ++j) acc[i][j] = (f32x4){0.f, 0.f, 0.f, 0.f};

  const int nt = K >> 6;

  // prologue: stage tile 0 (8 inst/wave)
#pragma unroll
  for (int c = 0; c < 4; ++c) {
    async16(Ag + c * a64, &Ab[0][c * 4096 + wave * 512]);
    async16(Bg + c * b64, &Bb[0][c * 4096 + wave * 512]);
  }

  for (int t = 0; t < nt; ++t) {
    const int buf = t & 1, nb = buf ^ 1;
    const long koff = (long)(t + 1) << 6;
    frag8 af[4][2], bf[2][2];

    // ---- phase 0: issue ALL next-tile loads, then drain tile t ----------
    if (t + 1 < nt) {
#pragma unroll
      for (int c = 0; c < 4; ++c) {
        async16(Ag + c * a64 + koff, &Ab[nb][c * 4096 + wave * 512]);
        async16(Bg + c * b64 + koff, &Bb[nb][c * 4096 + wave * 512]);
      }
      asm volatile("s_waitcnt vmcnt(8)" ::: "memory");  // tile t fully landed
    } else {
      asm volatile("s_waitcnt vmcnt(0)" ::: "memory");
    }
    __builtin_amdgcn_s_barrier();
    asm volatile("" ::: "memory");

    // quadrant (M0, N0)
#pragma unroll
    for (int i = 0; i < 4; ++i)
#pragma unroll
      for (int kk = 0; kk < 2; ++kk)
        af[i][kk] = *(const frag8*)(&Ab[buf][(wm * 128 + i * 16 + l16) * 64 +
                                             ((kk * 32 + quad * 8) ^ rsw)]);
#pragma unroll
    for (int j = 0; j < 2; ++j)
#pragma unroll
      for (int kk = 0; kk < 2; ++kk)
        bf[j][kk] = *(const frag8*)(&Bb[buf][(wn * 64 + j * 16 + l16) * 64 +
                                             ((kk * 32 + quad * 8) ^ rsw)]);
    __builtin_amdgcn_s_setprio(1);
#pragma unroll
    for (int kk = 0; kk < 2; ++kk)
#pragma unroll
      for (int i = 0; i < 4; ++i)
#pragma unroll
        for (int j = 0; j < 2; ++j)
          acc[i][j] = __builtin_amdgcn_mfma_f32_16x16x32_bf16(af[i][kk], bf[j][kk], acc[i][j], 0, 0, 0);
    __builtin_amdgcn_s_setprio(0);
    __builtin_amdgcn_s_barrier();

    // quadrant (M0, N1) — reuse af
#pragma unroll
    for (int j = 0; j < 2; ++j)
#pragma unroll
      for (int kk = 0; kk < 2; ++kk)
        bf[j][kk] = *(const frag8*)(&Bb[buf][(wn * 64 + (j + 2) * 16 + l16) * 64 +
                                             ((kk * 32 + quad * 8) ^ rsw)]);
    __builtin_amdgcn_s_setprio(1);
#pragma unroll
    for (int kk = 0; kk < 2; ++kk)
#pragma unroll
      for (int i = 0; i < 4; ++i)
#pragma unroll
        for (int j = 0; j < 2; ++j)
          acc[i][j + 2] = __builtin_amdgcn_mfma_f32_16x16x32_bf16(af[i][kk], bf[j][kk], acc[i][j + 2], 0, 0, 0);
    __builtin_amdgcn_s_setprio(0);
    __builtin_amdgcn_s_barrier();

    // quadrant (M1, N0)
#pragma unroll
    for (int i = 0; i < 4; ++i)
#pragma unroll
      for (int kk = 0; kk < 2; ++kk)
        af[i][kk] = *(const frag8*)(&Ab[buf][(wm * 128 + (i + 4) * 16 + l16) * 64 +
                                             ((kk * 32 + quad * 8) ^ rsw)]);
#pragma unroll
    for (int j = 0; j < 2; ++j)
#pragma unroll
      for (int kk = 0; kk < 2; ++kk)
        bf[j][kk] = *(const frag8*)(&Bb[buf][(wn * 64 + j * 16 + l16) * 64 +
                                             ((kk * 32 + quad * 8) ^ rsw)]);
    __builtin_amdgcn_s_setprio(1);
#pragma unroll
    for (int kk = 0; kk < 2; ++kk)
#pragma unroll
      for (int i = 0; i < 4; ++i)
#pragma unroll
        for (int j = 0; j < 2; ++j)
          acc[i + 4][j] = __builtin_amdgcn_mfma_f32_16x16x32_bf16(af[i][kk], bf[j][kk], acc[i + 4][j], 0, 0, 0);
    __builtin_amdgcn_s_setprio(0);
    __builtin_amdgcn_s_barrier();

    // quadrant (M1, N1) — reuse af
#pragma unroll
    for (int j = 0; j < 2; ++j)
#pragma unroll
      for (int kk = 0; kk < 2; ++kk)
        bf[j][kk] = *(const frag8*)(&Bb[buf][(wn * 64 + (j + 2) * 16 + l16) * 64 +
                                             ((kk * 32 + quad * 8) ^ rsw)]);
    __builtin_amdgcn_s_setprio(1);
#pragma unroll
    for (int kk = 0; kk < 2; ++kk)
#pragma unroll
      for (int i = 0; i < 4; ++i)
#pragma unroll
        for (int j = 0; j < 2; ++j)
          acc[i + 4][j + 2] = __builtin_amdgcn_mfma_f32_16x16x32_bf16(af[i][kk], bf[j][kk], acc[i + 4][j + 2], 0, 0, 0);
    __builtin_amdgcn_s_setprio(0);
    __builtin_amdgcn_s_barrier();
  }

  // epilogue (oscale folded; used to pre-scale Q)
  OutT* Ct = C + ((long)bx * 256 + wm * 128) * ldc + (long)by * 256 + wn * 64;
#pragma unroll
  for (int i = 0; i < 8; ++i)
#pragma unroll
    for (int j = 0; j < 4; ++j) {
      int r0 = i * 16 + quad * 4, cc = j * 16 + l16;
#pragma unroll
      for (int r = 0; r < 4; ++r) {
        float v = acc[i][j][r] * oscale;
        if constexpr (sizeof(OutT) == 2)
          Ct[(long)(r0 + r) * ldc + cc] = f2bf(v);
        else
          Ct[(long)(r0 + r) * ldc + cc] = v;
      }
    }
}

// ---- 128x128 GEMM core, double-buffered + counted vmcnt (T3-min) --------
__device__ __forceinline__ void gemm_core(const u16* __restrict__ A, int lda,
                                          const u16* __restrict__ Bt, int ldb,
                                          int K, u16* As, u16* Bs, f32x4 acc[4][4]) {
  const int tid = threadIdx.x;
  const int lane = tid & 63, wave = tid >> 6;
  const int wr = wave >> 1, wc = wave & 1;
  const int quad = lane >> 4, l16 = lane & 15;
#pragma unroll
  for (int i = 0; i < 4; ++i)
#pragma unroll
    for (int j = 0; j < 4; ++j) acc[i][j] = (f32x4){0.f, 0.f, 0.f, 0.f};

  const int row0 = tid >> 2, offc = (tid & 3) * 8;  // 128 rows x 32 k, 16B chunks
  const int nt = K >> 5;

  // prologue: tile 0
#pragma unroll
  for (int r = 0; r < 2; ++r) {
    int row = r * 64 + row0;
    async16(A + (long)row * lda + offc, As + r * 2048 + wave * 512);
    async16(Bt + (long)row * ldb + offc, Bs + r * 2048 + wave * 512);
  }

  for (int t = 0; t < nt; ++t) {
    const int bo = (t & 1) * 4096, nbo = bo ^ 4096;
    if (t + 1 < nt) {
      const int k0 = (t + 1) * 32;
#pragma unroll
      for (int r = 0; r < 2; ++r) {
        int row = r * 64 + row0;
        async16(A + (long)row * lda + k0 + offc, As + nbo + r * 2048 + wave * 512);
        async16(Bt + (long)row * ldb + k0 + offc, Bs + nbo + r * 2048 + wave * 512);
      }
      asm volatile("s_waitcnt vmcnt(4)" ::: "memory");  // tile t landed
    } else {
      asm volatile("s_waitcnt vmcnt(0)" ::: "memory");
    }
    __builtin_amdgcn_s_barrier();
    asm volatile("" ::: "memory");

    frag8 af[4], bf[4];
#pragma unroll
    for (int i = 0; i < 4; ++i)
      af[i] = *(const frag8*)(As + bo + (wr * 64 + i * 16 + l16) * 32 + quad * 8);
#pragma unroll
    for (int j = 0; j < 4; ++j)
      bf[j] = *(const frag8*)(Bs + bo + (wc * 64 + j * 16 + l16) * 32 + quad * 8);
#pragma unroll
    for (int i = 0; i < 4; ++i)
#pragma unroll
      for (int j = 0; j < 4; ++j)
        acc[i][j] = __builtin_amdgcn_mfma_f32_16x16x32_bf16(af[i], bf[j], acc[i][j], 0, 0, 0);
    asm volatile("" ::: "memory");
    __builtin_amdgcn_s_barrier();  // all reads of buf done before restage
  }
}

#define EPI_COORDS                                             \
  const int lane = threadIdx.x & 63, wave = threadIdx.x >> 6;  \
  const int wr = wave >> 1, wc = wave & 1;                     \
  const int quad = lane >> 4, l16 = lane & 15;

__global__ __launch_bounds__(256) void k_gemm_bf16(const u16* __restrict__ A, int lda,
                                                   const u16* __restrict__ Bt, int ldb,
                                                   u16* __restrict__ C, int ldc, int K) {
  __shared__ alignas(16) u16 smem[4 * TILE * 32];  // 2 bufs x (A,B)
  int bx, by; xcd_map(bx, by);
  f32x4 acc[4][4];
  gemm_core(A + (long)bx * TILE * lda, lda,
            Bt + (long)by * TILE * ldb, ldb, K, smem, smem + 2 * TILE * 32, acc);
  EPI_COORDS
  u16* Ct = C + (long)bx * TILE * ldc + (long)by * TILE;
#pragma unroll
  for (int i = 0; i < 4; ++i)
#pragma unroll
    for (int j = 0; j < 4; ++j) {
      int r0 = wr * 64 + i * 16 + quad * 4, cc = wc * 64 + j * 16 + l16;
#pragma unroll
      for (int r = 0; r < 4; ++r) Ct[(long)(r0 + r) * ldc + cc] = f2bf(acc[i][j][r]);
    }
}

// writes C^T: contiguous 4-element store per acc tile (for V^T layout)
__global__ __launch_bounds__(256) void k_gemm_bf16t(const u16* __restrict__ A, int lda,
                                                    const u16* __restrict__ Bt, int ldb,
                                                    u16* __restrict__ Ct, int ldct, int K) {
  __shared__ alignas(16) u16 smem[4 * TILE * 32];
  int bx, by; xcd_map(bx, by);
  f32x4 acc[4][4];
  gemm_core(A + (long)bx * TILE * lda, lda,
            Bt + (long)by * TILE * ldb, ldb, K, smem, smem + 2 * TILE * 32, acc);
  EPI_COORDS
  u16* Cb = Ct + (long)by * TILE * ldct + (long)bx * TILE;
#pragma unroll
  for (int i = 0; i < 4; ++i)
#pragma unroll
    for (int j = 0; j < 4; ++j) {
      int n = wc * 64 + j * 16 + l16, m0 = wr * 64 + i * 16 + quad * 4;
      ushort4 o;
      o.x = f2bf(acc[i][j][0]); o.y = f2bf(acc[i][j][1]);
      o.z = f2bf(acc[i][j][2]); o.w = f2bf(acc[i][j][3]);
      *(ushort4*)(Cb + (long)n * ldct + m0) = o;
    }
}

// ---- fused local-window attention (R6 structure) ------------------------
// Q arrives pre-scaled by scale*log2(e); softmax in exp2 domain.
// LDS 64KB: K and V both double-buffered -> 2 blocks/CU (co-location
// capacity optimum: ~4 (b,hk,blk) groups/XCD = 4MB = XCD L2 size).
// Per-iter: stage(next) at top; mid raw barrier (no drain -> PV overlaps
// prefetch); end barrier takes vmcnt(0) (prefetch had the whole iter).
__global__ __launch_bounds__(256, 2) void k_attn(const u16* __restrict__ qb,
                                                 const u16* __restrict__ kb,
                                                 const u16* __restrict__ vT,
                                                 u16* __restrict__ O) {
  __shared__ alignas(16) u16 Ks[2][64 * 128];  // [key][hd]; P overlays cur after S
  __shared__ alignas(16) u16 Vs[2][128 * 64];  // [hd][key]
  const int tid = threadIdx.x, lane = tid & 63, wave = tid >> 6;
  const int quad = lane >> 4, l16 = lane & 15;

  // XCD-group decode: 16 siblings sharing (b,hk,blk) land on one XCD
  const int id = blockIdx.x + 4 * blockIdx.y + 32 * blockIdx.z;  // 0..1023
  const int g = (id & 7) | ((id >> 7) << 3);                     // group 0..63
  const int w = (id >> 3) & 15;                                  // member 0..15
  const int hk = g & 3, blk = (g >> 2) & 7, b = g >> 5;
  const int h = hk * 4 + (w & 3), qi = w >> 2;

  const long tok_q = (long)b * 4096 + blk * 512 + qi * 128;

  frag8 qf[2][4];
#pragma unroll
  for (int i = 0; i < 2; ++i)
#pragma unroll
    for (int kt = 0; kt < 4; ++kt)
      qf[i][kt] = *(const frag8*)(qb + (tok_q + wave * 32 + i * 16 + l16) * 2048 +
                                  h * 128 + kt * 32 + quad * 8);

  f32x4 o_acc[2][8];
  float m_r[2][4], l_r[2][4];
#pragma unroll
  for (int i = 0; i < 2; ++i) {
#pragma unroll
    for (int j = 0; j < 8; ++j) o_acc[i][j] = (f32x4){0.f, 0.f, 0.f, 0.f};
#pragma unroll
    for (int r = 0; r < 4; ++r) { m_r[i][r] = -1e30f; l_r[i][r] = 0.f; }
  }

  const int rsw = (l16 & 7) << 3;  // read-side XOR (u16)

  auto stage = [&](int buf, int ci) {
    const long tk = (long)b * 4096 + (blk - 1) * 512 + ci * 64;
#pragma unroll
    for (int c = 0; c < 4; ++c) {
      const int idx = (wave * 4 + c) * 512 + lane * 8;  // u16 index, linear
      {  // K: row = idx/128, col = idx%128
        int row = idx >> 7, col = idx & 127;
        async16(kb + (tk + row) * 512 + hk * 128 + (col ^ ((row & 7) << 3)),
                &Ks[buf][(wave * 4 + c) * 512]);
      }
      {  // V: row = idx/64, col = idx%64
        int row = idx >> 6, col = idx & 63;
        async16(vT + ((long)hk * 128 + row) * 8192 + tk + (col ^ ((row & 7) << 3)),
                &Vs[buf][(wave * 4 + c) * 512]);
      }
    }
  };

  const int c0 = blk ? 2 * qi : 8, c1 = 9 + 2 * qi;
  int cur = 0;
  stage(0, c0);
  asm volatile("s_waitcnt vmcnt(0)" ::: "memory");
  __builtin_amdgcn_s_barrier();
  asm volatile("" ::: "memory");

  for (int ci = c0; ci <= c1; ++ci) {
    if (ci < c1) stage(cur ^ 1, ci + 1);  // issue-early prefetch

    // S = Q @ K^T  (32 rows x 64 keys per wave)
    f32x4 s_acc[2][4];
#pragma unroll
    for (int i = 0; i < 2; ++i)
#pragma unroll
      for (int j = 0; j < 4; ++j) s_acc[i][j] = (f32x4){0.f, 0.f, 0.f, 0.f};
#pragma unroll
    for (int kt = 0; kt < 4; ++kt) {
      frag8 bfr[4];
#pragma unroll
      for (int j = 0; j < 4; ++j)
        bfr[j] = *(const frag8*)(&Ks[cur][(j * 16 + l16) * 128 + ((kt * 32 + quad * 8) ^ rsw)]);
#pragma unroll
      for (int i = 0; i < 2; ++i)
#pragma unroll
        for (int j = 0; j < 4; ++j)
          s_acc[i][j] = __builtin_amdgcn_mfma_f32_16x16x32_bf16(qf[i][kt], bfr[j], s_acc[i][j], 0, 0, 0);
    }

    // mask + per-row chunk max. Only doff in {0,64} chunks are partial.
    const bool prev = (ci < 8);
    const int doff = (prev ? ci * 64 : (ci - 8) * 64) - qi * 128;
    float mc[2][4];
#pragma unroll
    for (int i = 0; i < 2; ++i)
#pragma unroll
      for (int r = 0; r < 4; ++r) mc[i][r] = -1e30f;
    if (doff >= 0 && doff <= 64) {  // partial chunk: apply mask
#pragma unroll
      for (int i = 0; i < 2; ++i)
#pragma unroll
        for (int j = 0; j < 4; ++j)
#pragma unroll
          for (int r = 0; r < 4; ++r) {
            int rl = wave * 32 + i * 16 + quad * 4 + r;
            int lk = j * 16 + l16;
            bool ok = prev ? (lk + doff > rl) : (lk + doff <= rl);
            float s = ok ? s_acc[i][j][r] : -1e30f;
            s_acc[i][j][r] = s;
            mc[i][r] = fmaxf(mc[i][r], s);
          }
    } else {  // interior: all keys valid
#pragma unroll
      for (int i = 0; i < 2; ++i)
#pragma unroll
        for (int j = 0; j < 4; ++j)
#pragma unroll
          for (int r = 0; r < 4; ++r) mc[i][r] = fmaxf(mc[i][r], s_acc[i][j][r]);
    }
#pragma unroll
    for (int o = 1; o < 16; o <<= 1)
#pragma unroll
      for (int i = 0; i < 2; ++i)
#pragma unroll
        for (int r = 0; r < 4; ++r)
          mc[i][r] = fmaxf(mc[i][r], __shfl_xor(mc[i][r], o));

    // defer-max (T13, log2 domain, THR=8 -> P <= 256)
    bool need = false;
#pragma unroll
    for (int i = 0; i < 2; ++i)
#pragma unroll
      for (int r = 0; r < 4; ++r) need = need || (mc[i][r] > m_r[i][r] + 8.f);
    if (__any(need)) {
      float alpha[2][4];
#pragma unroll
      for (int i = 0; i < 2; ++i)
#pragma unroll
        for (int r = 0; r < 4; ++r) {
          float mn = fmaxf(m_r[i][r], mc[i][r]);
          alpha[i][r] = fexp2(m_r[i][r] - mn);
          m_r[i][r] = mn;
          l_r[i][r] *= alpha[i][r];
        }
#pragma unroll
      for (int i = 0; i < 2; ++i)
#pragma unroll
        for (int j = 0; j < 8; ++j)
#pragma unroll
          for (int r = 0; r < 4; ++r) o_acc[i][j][r] *= alpha[i][r];
    }

    float ps[2][4];
#pragma unroll
    for (int i = 0; i < 2; ++i)
#pragma unroll
      for (int r = 0; r < 4; ++r) ps[i][r] = 0.f;
#pragma unroll
    for (int i = 0; i < 2; ++i)
#pragma unroll
      for (int j = 0; j < 4; ++j)
#pragma unroll
        for (int r = 0; r < 4; ++r) {
          float s = s_acc[i][j][r];
          float e = fexp2(s - m_r[i][r]);
          e = (s == -1e30f) ? 0.f : e;
          s_acc[i][j][r] = e;
          ps[i][r] += e;
        }
#pragma unroll
    for (int o = 1; o < 16; o <<= 1)
#pragma unroll
      for (int i = 0; i < 2; ++i)
#pragma unroll
        for (int r = 0; r < 4; ++r) ps[i][r] += __shfl_xor(ps[i][r], o);
#pragma unroll
    for (int i = 0; i < 2; ++i)
#pragma unroll
      for (int r = 0; r < 4; ++r) l_r[i][r] += ps[i][r];

    // mid barrier: all waves' K-reads done -> P may overlay Ks[cur].
    // NO vmcnt drain: prefetch (into cur^1) keeps flying through PV.
    asm volatile("" ::: "memory");
    __builtin_amdgcn_s_barrier();
    asm volatile("" ::: "memory");

    u16* PsW = &Ks[cur][wave * 2048];
#pragma unroll
    for (int i = 0; i < 2; ++i)
#pragma unroll
      for (int r = 0; r < 4; ++r) {
        int xw = ((quad * 4 + r) & 7) << 3;
#pragma unroll
        for (int j = 0; j < 4; ++j)
          PsW[(i * 16 + quad * 4 + r) * 64 + ((j * 16 + l16) ^ xw)] = f2bf(s_acc[i][j][r]);
      }

#pragma unroll
    for (int kt = 0; kt < 2; ++kt) {
      frag8 pf[2], vf[8];
#pragma unroll
      for (int i = 0; i < 2; ++i)
        pf[i] = *(const frag8*)(PsW + (i * 16 + l16) * 64 + ((kt * 32 + quad * 8) ^ rsw));
#pragma unroll
      for (int j = 0; j < 8; ++j)
        vf[j] = *(const frag8*)(&Vs[cur][(j * 16 + l16) * 64 + ((kt * 32 + quad * 8) ^ rsw)]);
#pragma unroll
      for (int i = 0; i < 2; ++i)
#pragma unroll
        for (int j = 0; j < 8; ++j)
          o_acc[i][j] = __builtin_amdgcn_mfma_f32_16x16x32_bf16(pf[i], vf[j], o_acc[i][j], 0, 0, 0);
    }

    // end barrier: prefetch landed + all PV reads done before restage
    asm volatile("s_waitcnt vmcnt(0)" ::: "memory");
    __builtin_amdgcn_s_barrier();
    asm volatile("" ::: "memory");
    cur ^= 1;
  }

  float inv[2][4];
#pragma unroll
  for (int i = 0; i < 2; ++i)
#pragma unroll
    for (int r = 0; r < 4; ++r) inv[i][r] = 1.0f / l_r[i][r];
  u16* Ob = &Ks[0][0];  // 32KB contiguous: [128 row][128 u16]
#pragma unroll
  for (int i = 0; i < 2; ++i)
#pragma unroll
    for (int j = 0; j < 8; ++j)
#pragma unroll
      for (int r = 0; r < 4; ++r)
        Ob[(wave * 32 + i * 16 + quad * 4 + r) * 128 + j * 16 + l16] =
            f2bf(o_acc[i][j][r] * inv[i][r]);
  __syncthreads();
#pragma unroll
  for (int p = 0; p < 8; ++p) {
    int idx = p * 256 + tid;
    int row = idx >> 4, col = (idx & 15) * 8;
    *(frag8*)(O + (tok_q + row) * 2048 + h * 128 + col) = *(const frag8*)(Ob + row * 128 + col);
  }
}

__global__ void k_convert(const float4* __restrict__ x, ushort4* __restrict__ xb) {
  int i = blockIdx.x * 256 + threadIdx.x;
  float4 f = x[i];
  ushort4 o;
  o.x = f2bf(f.x); o.y = f2bf(f.y); o.z = f2bf(f.z); o.w = f2bf(f.w);
  xb[i] = o;
}

// W [K,N] fp32 -> W^T [N,K] bf16
__global__ void k_transpose(const float* __restrict__ W, u16* __restrict__ WT, int K, int N) {
  __shared__ float sh[32][33];
  int n0 = blockIdx.x * 32, k0 = blockIdx.y * 32;
  int tx = threadIdx.x, ty = threadIdx.y;  // (32, 8)
#pragma unroll
  for (int i = 0; i < 32; i += 8) sh[ty + i][tx] = W[(long)(k0 + ty + i) * N + n0 + tx];
  __syncthreads();
#pragma unroll
  for (int i = 0; i < 32; i += 8) WT[(long)(n0 + ty + i) * K + k0 + tx] = f2bf(sh[tx][ty + i]);
}

extern "C" void kernel_launch(void* const* d_in, const int* in_sizes, int n_in,
                              void* d_out, int out_size, void* d_ws, size_t ws_size,
                              hipStream_t stream) {
  const float* x  = (const float*)d_in[0];
  const float* Wq = (const float*)d_in[1];
  const float* Wk = (const float*)d_in[2];
  const float* Wv = (const float*)d_in[3];
  const float* Wo = (const float*)d_in[4];
  float* out = (float*)d_out;

  const long BT = 8192, D = 2048, NKV = 512;
  size_t off = 0;
  auto alloc = [&](size_t bytes) -> char* {
    off = (off + 255) & ~(size_t)255;
    char* p = (char*)d_ws + off;
    off += bytes;
    return p;
  };

  u16* xb  = (u16*)alloc((size_t)BT * D * 2);  // reused as attention output
  u16* WqT = (u16*)alloc((size_t)D * D * 2);
  u16* WkT = (u16*)alloc((size_t)NKV * D * 2);
  u16* WvT = (u16*)alloc((size_t)NKV * D * 2);
  u16* WoT = (u16*)alloc((size_t)D * D * 2);
  u16* qb  = (u16*)alloc((size_t)BT * D * 2);
  u16* kb  = (u16*)alloc((size_t)BT * NKV * 2);
  u16* vT  = (u16*)alloc((size_t)NKV * BT * 2);
  u16* Oa  = xb;

  k_convert<<<16384, 256, 0, stream>>>((const float4*)x, (ushort4*)xb);
  dim3 tb(32, 8);
  k_transpose<<<dim3(64, 64), tb, 0, stream>>>(Wq, WqT, 2048, 2048);
  k_transpose<<<dim3(16, 64), tb, 0, stream>>>(Wk, WkT, 2048, 512);
  k_transpose<<<dim3(16, 64), tb, 0, stream>>>(Wv, WvT, 2048, 512);
  k_transpose<<<dim3(64, 64), tb, 0, stream>>>(Wo, WoT, 2048, 2048);

  // Q projection pre-scales by (1/sqrt(HD)) * log2(e)  (softmax in exp2 domain)
  const float qscale = 0.08838834764831845f * 1.4426950408889634f;
  k_gemm256<u16><<<dim3(32, 8), 512, 0, stream>>>(xb, 2048, WqT, 2048, qb, 2048, 2048,
                                                  qscale);
  k_gemm_bf16 <<<dim3(64, 4),  256, 0, stream>>>(xb, 2048, WkT, 2048, kb, 512, 2048);
  k_gemm_bf16t<<<dim3(64, 4),  256, 0, stream>>>(xb, 2048, WvT, 2048, vT, 8192, 2048);

  k_attn<<<dim3(4, 8, 32), 256, 0, stream>>>(qb, kb, vT, Oa);

  k_gemm256<float><<<dim3(32, 8), 512, 0, stream>>>(Oa, 2048, WoT, 2048, out, 2048, 2048,
                                                    1.0f);
}

// Round 7
// 451.870 us; speedup vs baseline: 1.2065x; 1.0093x over previous
//
#include <hip/hip_runtime.h>
#include <stdint.h>

// LocalWindowAttention: B=2,T=4096,D=2048,H=16,HK=4,HD=128,WIN=512
// R9: attn 1-barrier chunk loop. P moves to a wave-private LDS buffer (Ps,
//     16KB) -> the mid barrier (P overlaid shared Ks[cur]) disappears. V
//     drops to a single buffer (staged at iter top, drained by counted
//     vmcnt(4) pre-PV, T4) -> LDS stays 64KB = 2 blocks/CU (R7 lesson:
//     never buy occupancy with VGPRs or L2 residency; this buys sync
//     freedom at constant occupancy). One barrier + vmcnt(0) per chunk.
//     GEMMs unchanged from R6/R8.

typedef unsigned short u16;
typedef __attribute__((ext_vector_type(8))) short frag8;   // 8 bf16 = 4 VGPRs
typedef __attribute__((ext_vector_type(4))) float f32x4;   // MFMA acc

#define TILE 128

__device__ __forceinline__ u16 f2bf(float f) {
  union { float f; unsigned u; } c; c.f = f;
  unsigned u = c.u;
  return (u16)((u + 0x7fffu + ((u >> 16) & 1u)) >> 16);
}

__device__ __forceinline__ float fexp2(float x) {  // D = 2^S0 (v_exp_f32)
  float r;
  asm("v_exp_f32 %0, %1" : "=v"(r) : "v"(x));
  return r;
}

// async global->LDS, 16B per lane; LDS dest = wave-uniform base + lane*16
__device__ __forceinline__ void async16(const u16* g, u16* l) {
  __builtin_amdgcn_global_load_lds((const __attribute__((address_space(1))) void*)g,
                                   (__attribute__((address_space(3))) void*)l, 16, 0, 0);
}

// T1: XCD-chunked remap. Requires gridDim.x % 8 == 0.
__device__ __forceinline__ void xcd_map(int& bx, int& by) {
  const int gx = gridDim.x;
  const int cx = gx >> 3;
  int id = blockIdx.y * gx + blockIdx.x;
  int xcd = id & 7, local = id >> 3;
  bx = xcd * cx + (local % cx);
  by = local / cx;
}

// ======================= 256^2 4-phase GEMM ==============================
template <typename OutT>
__global__ __launch_bounds__(512, 2) void k_gemm256(const u16* __restrict__ A, int lda,
                                                    const u16* __restrict__ Bt, int ldb,
                                                    OutT* __restrict__ C, int ldc, int K,
                                                    float oscale) {
  __shared__ alignas(16) u16 Ab[2][256 * 64];  // 64 KB
  __shared__ alignas(16) u16 Bb[2][256 * 64];  // 64 KB
  const int tid = threadIdx.x, lane = tid & 63, wave = tid >> 6;
  const int wm = wave >> 2, wn = wave & 3;     // 2M x 4N wave grid
  const int quad = lane >> 4, l16 = lane & 15;

  int bx, by;
  xcd_map(bx, by);

  // staging coords: issue c, wave w, lane l -> row = c*64+w*8+(l>>3),
  // src col = ((l&7)^(l>>3))*8  (row&7 == l>>3 -> involution holds)
  const int rsub = wave * 8 + (lane >> 3);
  const int csub = ((lane & 7) ^ (lane >> 3)) * 8;
  const u16* Ag = A + ((long)bx * 256 + rsub) * lda + csub;
  const u16* Bg = Bt + ((long)by * 256 + rsub) * ldb + csub;
  const long a64 = (long)64 * lda, b64 = (long)64 * ldb;

  const int rsw = (l16 & 7) << 3;  // read-side XOR (u16 units)

  f32x4 acc[8][4];
#pragma unroll
  for (int i = 0; i < 8; ++i)
#pragma unroll
    for (int j = 0; j < 4; ++j) acc[i][j] = (f32x4){0.f, 0.f, 0.f, 0.f};

  const int nt = K >> 6;

  // prologue: stage tile 0 (8 inst/wave)
#pragma unroll
  for (int c = 0; c < 4; ++c) {
    async16(Ag + c * a64, &Ab[0][c * 4096 + wave * 512]);
    async16(Bg + c * b64, &Bb[0][c * 4096 + wave * 512]);
  }

  for (int t = 0; t < nt; ++t) {
    const int buf = t & 1, nb = buf ^ 1;
    const long koff = (long)(t + 1) << 6;
    frag8 af[4][2], bf[2][2];

    // ---- phase 0: issue ALL next-tile loads, then drain tile t ----------
    if (t + 1 < nt) {
#pragma unroll
      for (int c = 0; c < 4; ++c) {
        async16(Ag + c * a64 + koff, &Ab[nb][c * 4096 + wave * 512]);
        async16(Bg + c * b64 + koff, &Bb[nb][c * 4096 + wave * 512]);
      }
      asm volatile("s_waitcnt vmcnt(8)" ::: "memory");  // tile t fully landed
    } else {
      asm volatile("s_waitcnt vmcnt(0)" ::: "memory");
    }
    __builtin_amdgcn_s_barrier();
    asm volatile("" ::: "memory");

    // quadrant (M0, N0)
#pragma unroll
    for (int i = 0; i < 4; ++i)
#pragma unroll
      for (int kk = 0; kk < 2; ++kk)
        af[i][kk] = *(const frag8*)(&Ab[buf][(wm * 128 + i * 16 + l16) * 64 +
                                             ((kk * 32 + quad * 8) ^ rsw)]);
#pragma unroll
    for (int j = 0; j < 2; ++j)
#pragma unroll
      for (int kk = 0; kk < 2; ++kk)
        bf[j][kk] = *(const frag8*)(&Bb[buf][(wn * 64 + j * 16 + l16) * 64 +
                                             ((kk * 32 + quad * 8) ^ rsw)]);
    __builtin_amdgcn_s_setprio(1);
#pragma unroll
    for (int kk = 0; kk < 2; ++kk)
#pragma unroll
      for (int i = 0; i < 4; ++i)
#pragma unroll
        for (int j = 0; j < 2; ++j)
          acc[i][j] = __builtin_amdgcn_mfma_f32_16x16x32_bf16(af[i][kk], bf[j][kk], acc[i][j], 0, 0, 0);
    __builtin_amdgcn_s_setprio(0);
    __builtin_amdgcn_s_barrier();

    // quadrant (M0, N1) — reuse af
#pragma unroll
    for (int j = 0; j < 2; ++j)
#pragma unroll
      for (int kk = 0; kk < 2; ++kk)
        bf[j][kk] = *(const frag8*)(&Bb[buf][(wn * 64 + (j + 2) * 16 + l16) * 64 +
                                             ((kk * 32 + quad * 8) ^ rsw)]);
    __builtin_amdgcn_s_setprio(1);
#pragma unroll
    for (int kk = 0; kk < 2; ++kk)
#pragma unroll
      for (int i = 0; i < 4; ++i)
#pragma unroll
        for (int j = 0; j < 2; ++j)
          acc[i][j + 2] = __builtin_amdgcn_mfma_f32_16x16x32_bf16(af[i][kk], bf[j][kk], acc[i][j + 2], 0, 0, 0);
    __builtin_amdgcn_s_setprio(0);
    __builtin_amdgcn_s_barrier();

    // quadrant (M1, N0)
#pragma unroll
    for (int i = 0; i < 4; ++i)
#pragma unroll
      for (int kk = 0; kk < 2; ++kk)
        af[i][kk] = *(const frag8*)(&Ab[buf][(wm * 128 + (i + 4) * 16 + l16) * 64 +
                                             ((kk * 32 + quad * 8) ^ rsw)]);
#pragma unroll
    for (int j = 0; j < 2; ++j)
#pragma unroll
      for (int kk = 0; kk < 2; ++kk)
        bf[j][kk] = *(const frag8*)(&Bb[buf][(wn * 64 + j * 16 + l16) * 64 +
                                             ((kk * 32 + quad * 8) ^ rsw)]);
    __builtin_amdgcn_s_setprio(1);
#pragma unroll
    for (int kk = 0; kk < 2; ++kk)
#pragma unroll
      for (int i = 0; i < 4; ++i)
#pragma unroll
        for (int j = 0; j < 2; ++j)
          acc[i + 4][j] = __builtin_amdgcn_mfma_f32_16x16x32_bf16(af[i][kk], bf[j][kk], acc[i + 4][j], 0, 0, 0);
    __builtin_amdgcn_s_setprio(0);
    __builtin_amdgcn_s_barrier();

    // quadrant (M1, N1) — reuse af
#pragma unroll
    for (int j = 0; j < 2; ++j)
#pragma unroll
      for (int kk = 0; kk < 2; ++kk)
        bf[j][kk] = *(const frag8*)(&Bb[buf][(wn * 64 + (j + 2) * 16 + l16) * 64 +
                                             ((kk * 32 + quad * 8) ^ rsw)]);
    __builtin_amdgcn_s_setprio(1);
#pragma unroll
    for (int kk = 0; kk < 2; ++kk)
#pragma unroll
      for (int i = 0; i < 4; ++i)
#pragma unroll
        for (int j = 0; j < 2; ++j)
          acc[i + 4][j + 2] = __builtin_amdgcn_mfma_f32_16x16x32_bf16(af[i][kk], bf[j][kk], acc[i + 4][j + 2], 0, 0, 0);
    __builtin_amdgcn_s_setprio(0);
    __builtin_amdgcn_s_barrier();
  }

  // epilogue (oscale folded; used to pre-scale Q)
  OutT* Ct = C + ((long)bx * 256 + wm * 128) * ldc + (long)by * 256 + wn * 64;
#pragma unroll
  for (int i = 0; i < 8; ++i)
#pragma unroll
    for (int j = 0; j < 4; ++j) {
      int r0 = i * 16 + quad * 4, cc = j * 16 + l16;
#pragma unroll
      for (int r = 0; r < 4; ++r) {
        float v = acc[i][j][r] * oscale;
        if constexpr (sizeof(OutT) == 2)
          Ct[(long)(r0 + r) * ldc + cc] = f2bf(v);
        else
          Ct[(long)(r0 + r) * ldc + cc] = v;
      }
    }
}

// ---- 128x128 GEMM core, double-buffered + counted vmcnt (T3-min) --------
__device__ __forceinline__ void gemm_core(const u16* __restrict__ A, int lda,
                                          const u16* __restrict__ Bt, int ldb,
                                          int K, u16* As, u16* Bs, f32x4 acc[4][4]) {
  const int tid = threadIdx.x;
  const int lane = tid & 63, wave = tid >> 6;
  const int wr = wave >> 1, wc = wave & 1;
  const int quad = lane >> 4, l16 = lane & 15;
#pragma unroll
  for (int i = 0; i < 4; ++i)
#pragma unroll
    for (int j = 0; j < 4; ++j) acc[i][j] = (f32x4){0.f, 0.f, 0.f, 0.f};

  const int row0 = tid >> 2, offc = (tid & 3) * 8;  // 128 rows x 32 k, 16B chunks
  const int nt = K >> 5;

  // prologue: tile 0
#pragma unroll
  for (int r = 0; r < 2; ++r) {
    int row = r * 64 + row0;
    async16(A + (long)row * lda + offc, As + r * 2048 + wave * 512);
    async16(Bt + (long)row * ldb + offc, Bs + r * 2048 + wave * 512);
  }

  for (int t = 0; t < nt; ++t) {
    const int bo = (t & 1) * 4096, nbo = bo ^ 4096;
    if (t + 1 < nt) {
      const int k0 = (t + 1) * 32;
#pragma unroll
      for (int r = 0; r < 2; ++r) {
        int row = r * 64 + row0;
        async16(A + (long)row * lda + k0 + offc, As + nbo + r * 2048 + wave * 512);
        async16(Bt + (long)row * ldb + k0 + offc, Bs + nbo + r * 2048 + wave * 512);
      }
      asm volatile("s_waitcnt vmcnt(4)" ::: "memory");  // tile t landed
    } else {
      asm volatile("s_waitcnt vmcnt(0)" ::: "memory");
    }
    __builtin_amdgcn_s_barrier();
    asm volatile("" ::: "memory");

    frag8 af[4], bf[4];
#pragma unroll
    for (int i = 0; i < 4; ++i)
      af[i] = *(const frag8*)(As + bo + (wr * 64 + i * 16 + l16) * 32 + quad * 8);
#pragma unroll
    for (int j = 0; j < 4; ++j)
      bf[j] = *(const frag8*)(Bs + bo + (wc * 64 + j * 16 + l16) * 32 + quad * 8);
#pragma unroll
    for (int i = 0; i < 4; ++i)
#pragma unroll
      for (int j = 0; j < 4; ++j)
        acc[i][j] = __builtin_amdgcn_mfma_f32_16x16x32_bf16(af[i], bf[j], acc[i][j], 0, 0, 0);
    asm volatile("" ::: "memory");
    __builtin_amdgcn_s_barrier();  // all reads of buf done before restage
  }
}

#define EPI_COORDS                                             \
  const int lane = threadIdx.x & 63, wave = threadIdx.x >> 6;  \
  const int wr = wave >> 1, wc = wave & 1;                     \
  const int quad = lane >> 4, l16 = lane & 15;

__global__ __launch_bounds__(256) void k_gemm_bf16(const u16* __restrict__ A, int lda,
                                                   const u16* __restrict__ Bt, int ldb,
                                                   u16* __restrict__ C, int ldc, int K) {
  __shared__ alignas(16) u16 smem[4 * TILE * 32];  // 2 bufs x (A,B)
  int bx, by; xcd_map(bx, by);
  f32x4 acc[4][4];
  gemm_core(A + (long)bx * TILE * lda, lda,
            Bt + (long)by * TILE * ldb, ldb, K, smem, smem + 2 * TILE * 32, acc);
  EPI_COORDS
  u16* Ct = C + (long)bx * TILE * ldc + (long)by * TILE;
#pragma unroll
  for (int i = 0; i < 4; ++i)
#pragma unroll
    for (int j = 0; j < 4; ++j) {
      int r0 = wr * 64 + i * 16 + quad * 4, cc = wc * 64 + j * 16 + l16;
#pragma unroll
      for (int r = 0; r < 4; ++r) Ct[(long)(r0 + r) * ldc + cc] = f2bf(acc[i][j][r]);
    }
}

// writes C^T: contiguous 4-element store per acc tile (for V^T layout)
__global__ __launch_bounds__(256) void k_gemm_bf16t(const u16* __restrict__ A, int lda,
                                                    const u16* __restrict__ Bt, int ldb,
                                                    u16* __restrict__ Ct, int ldct, int K) {
  __shared__ alignas(16) u16 smem[4 * TILE * 32];
  int bx, by; xcd_map(bx, by);
  f32x4 acc[4][4];
  gemm_core(A + (long)bx * TILE * lda, lda,
            Bt + (long)by * TILE * ldb, ldb, K, smem, smem + 2 * TILE * 32, acc);
  EPI_COORDS
  u16* Cb = Ct + (long)by * TILE * ldct + (long)bx * TILE;
#pragma unroll
  for (int i = 0; i < 4; ++i)
#pragma unroll
    for (int j = 0; j < 4; ++j) {
      int n = wc * 64 + j * 16 + l16, m0 = wr * 64 + i * 16 + quad * 4;
      ushort4 o;
      o.x = f2bf(acc[i][j][0]); o.y = f2bf(acc[i][j][1]);
      o.z = f2bf(acc[i][j][2]); o.w = f2bf(acc[i][j][3]);
      *(ushort4*)(Cb + (long)n * ldct + m0) = o;
    }
}

// ---- fused local-window attention (1-barrier chunk loop) -----------------
// Q arrives pre-scaled by scale*log2(e); softmax in exp2 domain.
// LDS 64KB: Ks dbuf 32KB + Vs single 16KB + Ps (wave-private P) 16KB
// -> 2 blocks/CU. Per chunk: ONE barrier.
//   top:  [ci>c0: issue V[ci]] [ci<c1: issue K[ci+1]]   (no wait)
//   S(Ks[cur]) -> softmax -> P write to own Ps region   (no sync)
//   pre-PV: vmcnt(4|0)  — V[ci] landed, K[ci+1] still flying (T4)
//   PV(Ps, Vs)
//   end:  vmcnt(0) + barrier  — K[ci+1] landed; all waves done with
//         Ks[cur]/Vs -> next iter may restage.
__global__ __launch_bounds__(256, 2) void k_attn(const u16* __restrict__ qb,
                                                 const u16* __restrict__ kb,
                                                 const u16* __restrict__ vT,
                                                 u16* __restrict__ O) {
  __shared__ alignas(16) u16 Ks[2][64 * 128];  // [key][hd] swizzled, 32KB
  __shared__ alignas(16) u16 Vs[128 * 64];     // [hd][key] swizzled, 16KB
  __shared__ alignas(16) u16 Ps[4 * 32 * 64];  // wave-private P, 16KB
  const int tid = threadIdx.x, lane = tid & 63, wave = tid >> 6;
  const int quad = lane >> 4, l16 = lane & 15;

  // XCD-group decode: 16 siblings sharing (b,hk,blk) land on one XCD
  const int id = blockIdx.x + 4 * blockIdx.y + 32 * blockIdx.z;  // 0..1023
  const int g = (id & 7) | ((id >> 7) << 3);                     // group 0..63
  const int w = (id >> 3) & 15;                                  // member 0..15
  const int hk = g & 3, blk = (g >> 2) & 7, b = g >> 5;
  const int h = hk * 4 + (w & 3), qi = w >> 2;

  const long tok_q = (long)b * 4096 + blk * 512 + qi * 128;

  frag8 qf[2][4];
#pragma unroll
  for (int i = 0; i < 2; ++i)
#pragma unroll
    for (int kt = 0; kt < 4; ++kt)
      qf[i][kt] = *(const frag8*)(qb + (tok_q + wave * 32 + i * 16 + l16) * 2048 +
                                  h * 128 + kt * 32 + quad * 8);

  f32x4 o_acc[2][8];
  float m_r[2][4], l_r[2][4];
#pragma unroll
  for (int i = 0; i < 2; ++i) {
#pragma unroll
    for (int j = 0; j < 8; ++j) o_acc[i][j] = (f32x4){0.f, 0.f, 0.f, 0.f};
#pragma unroll
    for (int r = 0; r < 4; ++r) { m_r[i][r] = -1e30f; l_r[i][r] = 0.f; }
  }

  const int rsw = (l16 & 7) << 3;  // read-side XOR (u16)

  auto stageK = [&](int buf, int ci) {
    const long tk = (long)b * 4096 + (blk - 1) * 512 + ci * 64;
#pragma unroll
    for (int c = 0; c < 4; ++c) {
      const int idx = (wave * 4 + c) * 512 + lane * 8;  // u16 index, linear
      int row = idx >> 7, col = idx & 127;
      async16(kb + (tk + row) * 512 + hk * 128 + (col ^ ((row & 7) << 3)),
              &Ks[buf][(wave * 4 + c) * 512]);
    }
  };
  auto stageV = [&](int ci) {
    const long tk = (long)b * 4096 + (blk - 1) * 512 + ci * 64;
#pragma unroll
    for (int c = 0; c < 4; ++c) {
      const int idx = (wave * 4 + c) * 512 + lane * 8;
      int row = idx >> 6, col = idx & 63;
      async16(vT + ((long)hk * 128 + row) * 8192 + tk + (col ^ ((row & 7) << 3)),
              &Vs[(wave * 4 + c) * 512]);
    }
  };

  const int c0 = blk ? 2 * qi : 8, c1 = 9 + 2 * qi;
  int cur = 0;
  stageK(0, c0);
  stageV(c0);
  asm volatile("s_waitcnt vmcnt(0)" ::: "memory");
  __builtin_amdgcn_s_barrier();
  asm volatile("" ::: "memory");

  for (int ci = c0; ci <= c1; ++ci) {
    if (ci > c0) stageV(ci);              // Vs free: prev end barrier passed
    if (ci < c1) stageK(cur ^ 1, ci + 1); // K prefetch into free buffer

    // S = Q @ K^T  (32 rows x 64 keys per wave)
    f32x4 s_acc[2][4];
#pragma unroll
    for (int i = 0; i < 2; ++i)
#pragma unroll
      for (int j = 0; j < 4; ++j) s_acc[i][j] = (f32x4){0.f, 0.f, 0.f, 0.f};
#pragma unroll
    for (int kt = 0; kt < 4; ++kt) {
      frag8 bfr[4];
#pragma unroll
      for (int j = 0; j < 4; ++j)
        bfr[j] = *(const frag8*)(&Ks[cur][(j * 16 + l16) * 128 + ((kt * 32 + quad * 8) ^ rsw)]);
#pragma unroll
      for (int i = 0; i < 2; ++i)
#pragma unroll
        for (int j = 0; j < 4; ++j)
          s_acc[i][j] = __builtin_amdgcn_mfma_f32_16x16x32_bf16(qf[i][kt], bfr[j], s_acc[i][j], 0, 0, 0);
    }

    // mask + per-row chunk max. Only doff in {0,64} chunks are partial.
    const bool prev = (ci < 8);
    const int doff = (prev ? ci * 64 : (ci - 8) * 64) - qi * 128;
    float mc[2][4];
#pragma unroll
    for (int i = 0; i < 2; ++i)
#pragma unroll
      for (int r = 0; r < 4; ++r) mc[i][r] = -1e30f;
    if (doff >= 0 && doff <= 64) {  // partial chunk: apply mask
#pragma unroll
      for (int i = 0; i < 2; ++i)
#pragma unroll
        for (int j = 0; j < 4; ++j)
#pragma unroll
          for (int r = 0; r < 4; ++r) {
            int rl = wave * 32 + i * 16 + quad * 4 + r;
            int lk = j * 16 + l16;
            bool ok = prev ? (lk + doff > rl) : (lk + doff <= rl);
            float s = ok ? s_acc[i][j][r] : -1e30f;
            s_acc[i][j][r] = s;
            mc[i][r] = fmaxf(mc[i][r], s);
          }
    } else {  // interior: all keys valid
#pragma unroll
      for (int i = 0; i < 2; ++i)
#pragma unroll
        for (int j = 0; j < 4; ++j)
#pragma unroll
          for (int r = 0; r < 4; ++r) mc[i][r] = fmaxf(mc[i][r], s_acc[i][j][r]);
    }
#pragma unroll
    for (int o = 1; o < 16; o <<= 1)
#pragma unroll
      for (int i = 0; i < 2; ++i)
#pragma unroll
        for (int r = 0; r < 4; ++r)
          mc[i][r] = fmaxf(mc[i][r], __shfl_xor(mc[i][r], o));

    // defer-max (T13, log2 domain, THR=8 -> P <= 256)
    bool need = false;
#pragma unroll
    for (int i = 0; i < 2; ++i)
#pragma unroll
      for (int r = 0; r < 4; ++r) need = need || (mc[i][r] > m_r[i][r] + 8.f);
    if (__any(need)) {
      float alpha[2][4];
#pragma unroll
      for (int i = 0; i < 2; ++i)
#pragma unroll
        for (int r = 0; r < 4; ++r) {
          float mn = fmaxf(m_r[i][r], mc[i][r]);
          alpha[i][r] = fexp2(m_r[i][r] - mn);
          m_r[i][r] = mn;
          l_r[i][r] *= alpha[i][r];
        }
#pragma unroll
      for (int i = 0; i < 2; ++i)
#pragma unroll
        for (int j = 0; j < 8; ++j)
#pragma unroll
          for (int r = 0; r < 4; ++r) o_acc[i][j][r] *= alpha[i][r];
    }

    float ps[2][4];
#pragma unroll
    for (int i = 0; i < 2; ++i)
#pragma unroll
      for (int r = 0; r < 4; ++r) ps[i][r] = 0.f;
#pragma unroll
    for (int i = 0; i < 2; ++i)
#pragma unroll
      for (int j = 0; j < 4; ++j)
#pragma unroll
        for (int r = 0; r < 4; ++r) {
          float s = s_acc[i][j][r];
          float e = fexp2(s - m_r[i][r]);
          e = (s == -1e30f) ? 0.f : e;
          s_acc[i][j][r] = e;
          ps[i][r] += e;
        }
#pragma unroll
    for (int o = 1; o < 16; o <<= 1)
#pragma unroll
      for (int i = 0; i < 2; ++i)
#pragma unroll
        for (int r = 0; r < 4; ++r) ps[i][r] += __shfl_xor(ps[i][r], o);
#pragma unroll
    for (int i = 0; i < 2; ++i)
#pragma unroll
      for (int r = 0; r < 4; ++r) l_r[i][r] += ps[i][r];

    // P -> wave-private Ps region (no barrier needed)
    u16* PsW = &Ps[wave * 2048];
#pragma unroll
    for (int i = 0; i < 2; ++i)
#pragma unroll
      for (int r = 0; r < 4; ++r) {
        int xw = ((quad * 4 + r) & 7) << 3;
#pragma unroll
        for (int j = 0; j < 4; ++j)
          PsW[(i * 16 + quad * 4 + r) * 64 + ((j * 16 + l16) ^ xw)] = f2bf(s_acc[i][j][r]);
      }

    // pre-PV: V[ci] landed; K[ci+1] (newest 4) stays in flight (T4)
    if (ci < c1)
      asm volatile("s_waitcnt vmcnt(4)" ::: "memory");
    else
      asm volatile("s_waitcnt vmcnt(0)" ::: "memory");

    // O += P @ V
#pragma unroll
    for (int kt = 0; kt < 2; ++kt) {
      frag8 pf[2], vf[8];
#pragma unroll
      for (int i = 0; i < 2; ++i)
        pf[i] = *(const frag8*)(PsW + (i * 16 + l16) * 64 + ((kt * 32 + quad * 8) ^ rsw));
#pragma unroll
      for (int j = 0; j < 8; ++j)
        vf[j] = *(const frag8*)(&Vs[(j * 16 + l16) * 64 + ((kt * 32 + quad * 8) ^ rsw)]);
#pragma unroll
      for (int i = 0; i < 2; ++i)
#pragma unroll
        for (int j = 0; j < 8; ++j)
          o_acc[i][j] = __builtin_amdgcn_mfma_f32_16x16x32_bf16(pf[i], vf[j], o_acc[i][j], 0, 0, 0);
    }

    // end: K[ci+1] landed; all waves done with Ks[cur]/Vs -> restage safe
    asm volatile("s_waitcnt vmcnt(0)" ::: "memory");
    __builtin_amdgcn_s_barrier();
    asm volatile("" ::: "memory");
    cur ^= 1;
  }

  float inv[2][4];
#pragma unroll
  for (int i = 0; i < 2; ++i)
#pragma unroll
    for (int r = 0; r < 4; ++r) inv[i][r] = 1.0f / l_r[i][r];
  u16* Ob = &Ks[0][0];  // 32KB contiguous: [128 row][128 u16]
#pragma unroll
  for (int i = 0; i < 2; ++i)
#pragma unroll
    for (int j = 0; j < 8; ++j)
#pragma unroll
      for (int r = 0; r < 4; ++r)
        Ob[(wave * 32 + i * 16 + quad * 4 + r) * 128 + j * 16 + l16] =
            f2bf(o_acc[i][j][r] * inv[i][r]);
  __syncthreads();
#pragma unroll
  for (int p = 0; p < 8; ++p) {
    int idx = p * 256 + tid;
    int row = idx >> 4, col = (idx & 15) * 8;
    *(frag8*)(O + (tok_q + row) * 2048 + h * 128 + col) = *(const frag8*)(Ob + row * 128 + col);
  }
}

__global__ void k_convert(const float4* __restrict__ x, ushort4* __restrict__ xb) {
  int i = blockIdx.x * 256 + threadIdx.x;
  float4 f = x[i];
  ushort4 o;
  o.x = f2bf(f.x); o.y = f2bf(f.y); o.z = f2bf(f.z); o.w = f2bf(f.w);
  xb[i] = o;
}

// W [K,N] fp32 -> W^T [N,K] bf16
__global__ void k_transpose(const float* __restrict__ W, u16* __restrict__ WT, int K, int N) {
  __shared__ float sh[32][33];
  int n0 = blockIdx.x * 32, k0 = blockIdx.y * 32;
  int tx = threadIdx.x, ty = threadIdx.y;  // (32, 8)
#pragma unroll
  for (int i = 0; i < 32; i += 8) sh[ty + i][tx] = W[(long)(k0 + ty + i) * N + n0 + tx];
  __syncthreads();
#pragma unroll
  for (int i = 0; i < 32; i += 8) WT[(long)(n0 + ty + i) * K + k0 + tx] = f2bf(sh[tx][ty + i]);
}

extern "C" void kernel_launch(void* const* d_in, const int* in_sizes, int n_in,
                              void* d_out, int out_size, void* d_ws, size_t ws_size,
                              hipStream_t stream) {
  const float* x  = (const float*)d_in[0];
  const float* Wq = (const float*)d_in[1];
  const float* Wk = (const float*)d_in[2];
  const float* Wv = (const float*)d_in[3];
  const float* Wo = (const float*)d_in[4];
  float* out = (float*)d_out;

  const long BT = 8192, D = 2048, NKV = 512;
  size_t off = 0;
  auto alloc = [&](size_t bytes) -> char* {
    off = (off + 255) & ~(size_t)255;
    char* p = (char*)d_ws + off;
    off += bytes;
    return p;
  };

  u16* xb  = (u16*)alloc((size_t)BT * D * 2);  // reused as attention output
  u16* WqT = (u16*)alloc((size_t)D * D * 2);
  u16* WkT = (u16*)alloc((size_t)NKV * D * 2);
  u16* WvT = (u16*)alloc((size_t)NKV * D * 2);
  u16* WoT = (u16*)alloc((size_t)D * D * 2);
  u16* qb  = (u16*)alloc((size_t)BT * D * 2);
  u16* kb  = (u16*)alloc((size_t)BT * NKV * 2);
  u16* vT  = (u16*)alloc((size_t)NKV * BT * 2);
  u16* Oa  = xb;

  k_convert<<<16384, 256, 0, stream>>>((const float4*)x, (ushort4*)xb);
  dim3 tb(32, 8);
  k_transpose<<<dim3(64, 64), tb, 0, stream>>>(Wq, WqT, 2048, 2048);
  k_transpose<<<dim3(16, 64), tb, 0, stream>>>(Wk, WkT, 2048, 512);
  k_transpose<<<dim3(16, 64), tb, 0, stream>>>(Wv, WvT, 2048, 512);
  k_transpose<<<dim3(64, 64), tb, 0, stream>>>(Wo, WoT, 2048, 2048);

  // Q projection pre-scales by (1/sqrt(HD)) * log2(e)  (softmax in exp2 domain)
  const float qscale = 0.08838834764831845f * 1.4426950408889634f;
  k_gemm256<u16><<<dim3(32, 8), 512, 0, stream>>>(xb, 2048, WqT, 2048, qb, 2048, 2048,
                                                  qscale);
  k_gemm_bf16 <<<dim3(64, 4),  256, 0, stream>>>(xb, 2048, WkT, 2048, kb, 512, 2048);
  k_gemm_bf16t<<<dim3(64, 4),  256, 0, stream>>>(xb, 2048, WvT, 2048, vT, 8192, 2048);

  k_attn<<<dim3(4, 8, 32), 256, 0, stream>>>(qb, kb, vT, Oa);

  k_gemm256<float><<<dim3(32, 8), 512, 0, stream>>>(Oa, 2048, WoT, 2048, out, 2048, 2048,
                                                    1.0f);
}

// Round 8
// 421.960 us; speedup vs baseline: 1.2920x; 1.0709x over previous
//
#include <hip/hip_runtime.h>
#include <stdint.h>

// LocalWindowAttention: B=2,T=4096,D=2048,H=16,HK=4,HD=128,WIN=512
// R10: attn de-shuffle. The chunk loop was DS-pipe/latency-bound on two
//      4-step __shfl_xor butterflies (64 ds_bpermute/chunk):
//      (1) softmax denominator via MFMA ones-column: l_acc = P @ 1 (4 extra
//          MFMA/chunk) -- sum butterfly deleted; l sums quantized bf16 P,
//          exactly consistent with O's numerator.
//      (2) defer-max gate on PER-LANE max via __any (exec-mask op): true
//          max > thr iff some lane partial > thr. m init 0; slow path
//          (butterfly + o/l rescale) only if gate fires (never, for this
//          data distribution; correct if it does).
//      (3) masked e: exp2(-1e30 - m) underflows to 0 in HW -> cndmask gone.
//      Structure/barriers/vmcnt/LDS identical to R9. GEMMs unchanged.

typedef unsigned short u16;
typedef __attribute__((ext_vector_type(8))) short frag8;   // 8 bf16 = 4 VGPRs
typedef __attribute__((ext_vector_type(4))) float f32x4;   // MFMA acc

#define TILE 128

__device__ __forceinline__ u16 f2bf(float f) {
  union { float f; unsigned u; } c; c.f = f;
  unsigned u = c.u;
  return (u16)((u + 0x7fffu + ((u >> 16) & 1u)) >> 16);
}

__device__ __forceinline__ float fexp2(float x) {  // D = 2^S0 (v_exp_f32)
  float r;
  asm("v_exp_f32 %0, %1" : "=v"(r) : "v"(x));
  return r;
}

// async global->LDS, 16B per lane; LDS dest = wave-uniform base + lane*16
__device__ __forceinline__ void async16(const u16* g, u16* l) {
  __builtin_amdgcn_global_load_lds((const __attribute__((address_space(1))) void*)g,
                                   (__attribute__((address_space(3))) void*)l, 16, 0, 0);
}

// T1: XCD-chunked remap. Requires gridDim.x % 8 == 0.
__device__ __forceinline__ void xcd_map(int& bx, int& by) {
  const int gx = gridDim.x;
  const int cx = gx >> 3;
  int id = blockIdx.y * gx + blockIdx.x;
  int xcd = id & 7, local = id >> 3;
  bx = xcd * cx + (local % cx);
  by = local / cx;
}

// ======================= 256^2 4-phase GEMM ==============================
template <typename OutT>
__global__ __launch_bounds__(512, 2) void k_gemm256(const u16* __restrict__ A, int lda,
                                                    const u16* __restrict__ Bt, int ldb,
                                                    OutT* __restrict__ C, int ldc, int K,
                                                    float oscale) {
  __shared__ alignas(16) u16 Ab[2][256 * 64];  // 64 KB
  __shared__ alignas(16) u16 Bb[2][256 * 64];  // 64 KB
  const int tid = threadIdx.x, lane = tid & 63, wave = tid >> 6;
  const int wm = wave >> 2, wn = wave & 3;     // 2M x 4N wave grid
  const int quad = lane >> 4, l16 = lane & 15;

  int bx, by;
  xcd_map(bx, by);

  // staging coords: issue c, wave w, lane l -> row = c*64+w*8+(l>>3),
  // src col = ((l&7)^(l>>3))*8  (row&7 == l>>3 -> involution holds)
  const int rsub = wave * 8 + (lane >> 3);
  const int csub = ((lane & 7) ^ (lane >> 3)) * 8;
  const u16* Ag = A + ((long)bx * 256 + rsub) * lda + csub;
  const u16* Bg = Bt + ((long)by * 256 + rsub) * ldb + csub;
  const long a64 = (long)64 * lda, b64 = (long)64 * ldb;

  const int rsw = (l16 & 7) << 3;  // read-side XOR (u16 units)

  f32x4 acc[8][4];
#pragma unroll
  for (int i = 0; i < 8; ++i)
#pragma unroll
    for (int j = 0; j < 4; ++j) acc[i][j] = (f32x4){0.f, 0.f, 0.f, 0.f};

  const int nt = K >> 6;

  // prologue: stage tile 0 (8 inst/wave)
#pragma unroll
  for (int c = 0; c < 4; ++c) {
    async16(Ag + c * a64, &Ab[0][c * 4096 + wave * 512]);
    async16(Bg + c * b64, &Bb[0][c * 4096 + wave * 512]);
  }

  for (int t = 0; t < nt; ++t) {
    const int buf = t & 1, nb = buf ^ 1;
    const long koff = (long)(t + 1) << 6;
    frag8 af[4][2], bf[2][2];

    // ---- phase 0: issue ALL next-tile loads, then drain tile t ----------
    if (t + 1 < nt) {
#pragma unroll
      for (int c = 0; c < 4; ++c) {
        async16(Ag + c * a64 + koff, &Ab[nb][c * 4096 + wave * 512]);
        async16(Bg + c * b64 + koff, &Bb[nb][c * 4096 + wave * 512]);
      }
      asm volatile("s_waitcnt vmcnt(8)" ::: "memory");  // tile t fully landed
    } else {
      asm volatile("s_waitcnt vmcnt(0)" ::: "memory");
    }
    __builtin_amdgcn_s_barrier();
    asm volatile("" ::: "memory");

    // quadrant (M0, N0)
#pragma unroll
    for (int i = 0; i < 4; ++i)
#pragma unroll
      for (int kk = 0; kk < 2; ++kk)
        af[i][kk] = *(const frag8*)(&Ab[buf][(wm * 128 + i * 16 + l16) * 64 +
                                             ((kk * 32 + quad * 8) ^ rsw)]);
#pragma unroll
    for (int j = 0; j < 2; ++j)
#pragma unroll
      for (int kk = 0; kk < 2; ++kk)
        bf[j][kk] = *(const frag8*)(&Bb[buf][(wn * 64 + j * 16 + l16) * 64 +
                                             ((kk * 32 + quad * 8) ^ rsw)]);
    __builtin_amdgcn_s_setprio(1);
#pragma unroll
    for (int kk = 0; kk < 2; ++kk)
#pragma unroll
      for (int i = 0; i < 4; ++i)
#pragma unroll
        for (int j = 0; j < 2; ++j)
          acc[i][j] = __builtin_amdgcn_mfma_f32_16x16x32_bf16(af[i][kk], bf[j][kk], acc[i][j], 0, 0, 0);
    __builtin_amdgcn_s_setprio(0);
    __builtin_amdgcn_s_barrier();

    // quadrant (M0, N1) — reuse af
#pragma unroll
    for (int j = 0; j < 2; ++j)
#pragma unroll
      for (int kk = 0; kk < 2; ++kk)
        bf[j][kk] = *(const frag8*)(&Bb[buf][(wn * 64 + (j + 2) * 16 + l16) * 64 +
                                             ((kk * 32 + quad * 8) ^ rsw)]);
    __builtin_amdgcn_s_setprio(1);
#pragma unroll
    for (int kk = 0; kk < 2; ++kk)
#pragma unroll
      for (int i = 0; i < 4; ++i)
#pragma unroll
        for (int j = 0; j < 2; ++j)
          acc[i][j + 2] = __builtin_amdgcn_mfma_f32_16x16x32_bf16(af[i][kk], bf[j][kk], acc[i][j + 2], 0, 0, 0);
    __builtin_amdgcn_s_setprio(0);
    __builtin_amdgcn_s_barrier();

    // quadrant (M1, N0)
#pragma unroll
    for (int i = 0; i < 4; ++i)
#pragma unroll
      for (int kk = 0; kk < 2; ++kk)
        af[i][kk] = *(const frag8*)(&Ab[buf][(wm * 128 + (i + 4) * 16 + l16) * 64 +
                                             ((kk * 32 + quad * 8) ^ rsw)]);
#pragma unroll
    for (int j = 0; j < 2; ++j)
#pragma unroll
      for (int kk = 0; kk < 2; ++kk)
        bf[j][kk] = *(const frag8*)(&Bb[buf][(wn * 64 + j * 16 + l16) * 64 +
                                             ((kk * 32 + quad * 8) ^ rsw)]);
    __builtin_amdgcn_s_setprio(1);
#pragma unroll
    for (int kk = 0; kk < 2; ++kk)
#pragma unroll
      for (int i = 0; i < 4; ++i)
#pragma unroll
        for (int j = 0; j < 2; ++j)
          acc[i + 4][j] = __builtin_amdgcn_mfma_f32_16x16x32_bf16(af[i][kk], bf[j][kk], acc[i + 4][j], 0, 0, 0);
    __builtin_amdgcn_s_setprio(0);
    __builtin_amdgcn_s_barrier();

    // quadrant (M1, N1) — reuse af
#pragma unroll
    for (int j = 0; j < 2; ++j)
#pragma unroll
      for (int kk = 0; kk < 2; ++kk)
        bf[j][kk] = *(const frag8*)(&Bb[buf][(wn * 64 + (j + 2) * 16 + l16) * 64 +
                                             ((kk * 32 + quad * 8) ^ rsw)]);
    __builtin_amdgcn_s_setprio(1);
#pragma unroll
    for (int kk = 0; kk < 2; ++kk)
#pragma unroll
      for (int i = 0; i < 4; ++i)
#pragma unroll
        for (int j = 0; j < 2; ++j)
          acc[i + 4][j + 2] = __builtin_amdgcn_mfma_f32_16x16x32_bf16(af[i][kk], bf[j][kk], acc[i + 4][j + 2], 0, 0, 0);
    __builtin_amdgcn_s_setprio(0);
    __builtin_amdgcn_s_barrier();
  }

  // epilogue (oscale folded; used to pre-scale Q)
  OutT* Ct = C + ((long)bx * 256 + wm * 128) * ldc + (long)by * 256 + wn * 64;
#pragma unroll
  for (int i = 0; i < 8; ++i)
#pragma unroll
    for (int j = 0; j < 4; ++j) {
      int r0 = i * 16 + quad * 4, cc = j * 16 + l16;
#pragma unroll
      for (int r = 0; r < 4; ++r) {
        float v = acc[i][j][r] * oscale;
        if constexpr (sizeof(OutT) == 2)
          Ct[(long)(r0 + r) * ldc + cc] = f2bf(v);
        else
          Ct[(long)(r0 + r) * ldc + cc] = v;
      }
    }
}

// ---- 128x128 GEMM core, double-buffered + counted vmcnt (T3-min) --------
__device__ __forceinline__ void gemm_core(const u16* __restrict__ A, int lda,
                                          const u16* __restrict__ Bt, int ldb,
                                          int K, u16* As, u16* Bs, f32x4 acc[4][4]) {
  const int tid = threadIdx.x;
  const int lane = tid & 63, wave = tid >> 6;
  const int wr = wave >> 1, wc = wave & 1;
  const int quad = lane >> 4, l16 = lane & 15;
#pragma unroll
  for (int i = 0; i < 4; ++i)
#pragma unroll
    for (int j = 0; j < 4; ++j) acc[i][j] = (f32x4){0.f, 0.f, 0.f, 0.f};

  const int row0 = tid >> 2, offc = (tid & 3) * 8;  // 128 rows x 32 k, 16B chunks
  const int nt = K >> 5;

  // prologue: tile 0
#pragma unroll
  for (int r = 0; r < 2; ++r) {
    int row = r * 64 + row0;
    async16(A + (long)row * lda + offc, As + r * 2048 + wave * 512);
    async16(Bt + (long)row * ldb + offc, Bs + r * 2048 + wave * 512);
  }

  for (int t = 0; t < nt; ++t) {
    const int bo = (t & 1) * 4096, nbo = bo ^ 4096;
    if (t + 1 < nt) {
      const int k0 = (t + 1) * 32;
#pragma unroll
      for (int r = 0; r < 2; ++r) {
        int row = r * 64 + row0;
        async16(A + (long)row * lda + k0 + offc, As + nbo + r * 2048 + wave * 512);
        async16(Bt + (long)row * ldb + k0 + offc, Bs + nbo + r * 2048 + wave * 512);
      }
      asm volatile("s_waitcnt vmcnt(4)" ::: "memory");  // tile t landed
    } else {
      asm volatile("s_waitcnt vmcnt(0)" ::: "memory");
    }
    __builtin_amdgcn_s_barrier();
    asm volatile("" ::: "memory");

    frag8 af[4], bf[4];
#pragma unroll
    for (int i = 0; i < 4; ++i)
      af[i] = *(const frag8*)(As + bo + (wr * 64 + i * 16 + l16) * 32 + quad * 8);
#pragma unroll
    for (int j = 0; j < 4; ++j)
      bf[j] = *(const frag8*)(Bs + bo + (wc * 64 + j * 16 + l16) * 32 + quad * 8);
#pragma unroll
    for (int i = 0; i < 4; ++i)
#pragma unroll
      for (int j = 0; j < 4; ++j)
        acc[i][j] = __builtin_amdgcn_mfma_f32_16x16x32_bf16(af[i], bf[j], acc[i][j], 0, 0, 0);
    asm volatile("" ::: "memory");
    __builtin_amdgcn_s_barrier();  // all reads of buf done before restage
  }
}

#define EPI_COORDS                                             \
  const int lane = threadIdx.x & 63, wave = threadIdx.x >> 6;  \
  const int wr = wave >> 1, wc = wave & 1;                     \
  const int quad = lane >> 4, l16 = lane & 15;

__global__ __launch_bounds__(256) void k_gemm_bf16(const u16* __restrict__ A, int lda,
                                                   const u16* __restrict__ Bt, int ldb,
                                                   u16* __restrict__ C, int ldc, int K) {
  __shared__ alignas(16) u16 smem[4 * TILE * 32];  // 2 bufs x (A,B)
  int bx, by; xcd_map(bx, by);
  f32x4 acc[4][4];
  gemm_core(A + (long)bx * TILE * lda, lda,
            Bt + (long)by * TILE * ldb, ldb, K, smem, smem + 2 * TILE * 32, acc);
  EPI_COORDS
  u16* Ct = C + (long)bx * TILE * ldc + (long)by * TILE;
#pragma unroll
  for (int i = 0; i < 4; ++i)
#pragma unroll
    for (int j = 0; j < 4; ++j) {
      int r0 = wr * 64 + i * 16 + quad * 4, cc = wc * 64 + j * 16 + l16;
#pragma unroll
      for (int r = 0; r < 4; ++r) Ct[(long)(r0 + r) * ldc + cc] = f2bf(acc[i][j][r]);
    }
}

// writes C^T: contiguous 4-element store per acc tile (for V^T layout)
__global__ __launch_bounds__(256) void k_gemm_bf16t(const u16* __restrict__ A, int lda,
                                                    const u16* __restrict__ Bt, int ldb,
                                                    u16* __restrict__ Ct, int ldct, int K) {
  __shared__ alignas(16) u16 smem[4 * TILE * 32];
  int bx, by; xcd_map(bx, by);
  f32x4 acc[4][4];
  gemm_core(A + (long)bx * TILE * lda, lda,
            Bt + (long)by * TILE * ldb, ldb, K, smem, smem + 2 * TILE * 32, acc);
  EPI_COORDS
  u16* Cb = Ct + (long)by * TILE * ldct + (long)bx * TILE;
#pragma unroll
  for (int i = 0; i < 4; ++i)
#pragma unroll
    for (int j = 0; j < 4; ++j) {
      int n = wc * 64 + j * 16 + l16, m0 = wr * 64 + i * 16 + quad * 4;
      ushort4 o;
      o.x = f2bf(acc[i][j][0]); o.y = f2bf(acc[i][j][1]);
      o.z = f2bf(acc[i][j][2]); o.w = f2bf(acc[i][j][3]);
      *(ushort4*)(Cb + (long)n * ldct + m0) = o;
    }
}

// ---- fused local-window attention (1-barrier, shuffle-free softmax) ------
// Q arrives pre-scaled by scale*log2(e); softmax in exp2 domain.
// LDS 64KB: Ks dbuf 32KB + Vs single 16KB + Ps (wave-private P) 16KB
// -> 2 blocks/CU. Per chunk: ONE barrier (see R9 ledger).
// Softmax: m starts 0; per-lane partial max only, gate = __any(partial >
// m+8) (true-max>thr iff some partial>thr). Gate off => no rescale, no
// reduce. l via MFMA ones-column in PV. Masked e underflows to 0.
__global__ __launch_bounds__(256, 2) void k_attn(const u16* __restrict__ qb,
                                                 const u16* __restrict__ kb,
                                                 const u16* __restrict__ vT,
                                                 u16* __restrict__ O) {
  __shared__ alignas(16) u16 Ks[2][64 * 128];  // [key][hd] swizzled, 32KB
  __shared__ alignas(16) u16 Vs[128 * 64];     // [hd][key] swizzled, 16KB
  __shared__ alignas(16) u16 Ps[4 * 32 * 64];  // wave-private P, 16KB
  const int tid = threadIdx.x, lane = tid & 63, wave = tid >> 6;
  const int quad = lane >> 4, l16 = lane & 15;

  // XCD-group decode: 16 siblings sharing (b,hk,blk) land on one XCD
  const int id = blockIdx.x + 4 * blockIdx.y + 32 * blockIdx.z;  // 0..1023
  const int g = (id & 7) | ((id >> 7) << 3);                     // group 0..63
  const int w = (id >> 3) & 15;                                  // member 0..15
  const int hk = g & 3, blk = (g >> 2) & 7, b = g >> 5;
  const int h = hk * 4 + (w & 3), qi = w >> 2;

  const long tok_q = (long)b * 4096 + blk * 512 + qi * 128;

  frag8 qf[2][4];
#pragma unroll
  for (int i = 0; i < 2; ++i)
#pragma unroll
    for (int kt = 0; kt < 4; ++kt)
      qf[i][kt] = *(const frag8*)(qb + (tok_q + wave * 32 + i * 16 + l16) * 2048 +
                                  h * 128 + kt * 32 + quad * 8);

  // ones fragment (bf16 1.0) for the l = P @ 1 column
  frag8 onef;
#pragma unroll
  for (int e = 0; e < 8; ++e) onef[e] = (short)0x3F80;

  f32x4 o_acc[2][8], l_acc[2];
  float m_r[2][4];
#pragma unroll
  for (int i = 0; i < 2; ++i) {
#pragma unroll
    for (int j = 0; j < 8; ++j) o_acc[i][j] = (f32x4){0.f, 0.f, 0.f, 0.f};
    l_acc[i] = (f32x4){0.f, 0.f, 0.f, 0.f};
#pragma unroll
    for (int r = 0; r < 4; ++r) m_r[i][r] = 0.f;  // finite start: exp2(s) direct
  }

  const int rsw = (l16 & 7) << 3;  // read-side XOR (u16)

  auto stageK = [&](int buf, int ci) {
    const long tk = (long)b * 4096 + (blk - 1) * 512 + ci * 64;
#pragma unroll
    for (int c = 0; c < 4; ++c) {
      const int idx = (wave * 4 + c) * 512 + lane * 8;  // u16 index, linear
      int row = idx >> 7, col = idx & 127;
      async16(kb + (tk + row) * 512 + hk * 128 + (col ^ ((row & 7) << 3)),
              &Ks[buf][(wave * 4 + c) * 512]);
    }
  };
  auto stageV = [&](int ci) {
    const long tk = (long)b * 4096 + (blk - 1) * 512 + ci * 64;
#pragma unroll
    for (int c = 0; c < 4; ++c) {
      const int idx = (wave * 4 + c) * 512 + lane * 8;
      int row = idx >> 6, col = idx & 63;
      async16(vT + ((long)hk * 128 + row) * 8192 + tk + (col ^ ((row & 7) << 3)),
              &Vs[(wave * 4 + c) * 512]);
    }
  };

  const int c0 = blk ? 2 * qi : 8, c1 = 9 + 2 * qi;
  int cur = 0;
  stageK(0, c0);
  stageV(c0);
  asm volatile("s_waitcnt vmcnt(0)" ::: "memory");
  __builtin_amdgcn_s_barrier();
  asm volatile("" ::: "memory");

  for (int ci = c0; ci <= c1; ++ci) {
    if (ci > c0) stageV(ci);              // Vs free: prev end barrier passed
    if (ci < c1) stageK(cur ^ 1, ci + 1); // K prefetch into free buffer

    // S = Q @ K^T  (32 rows x 64 keys per wave)
    f32x4 s_acc[2][4];
#pragma unroll
    for (int i = 0; i < 2; ++i)
#pragma unroll
      for (int j = 0; j < 4; ++j) s_acc[i][j] = (f32x4){0.f, 0.f, 0.f, 0.f};
#pragma unroll
    for (int kt = 0; kt < 4; ++kt) {
      frag8 bfr[4];
#pragma unroll
      for (int j = 0; j < 4; ++j)
        bfr[j] = *(const frag8*)(&Ks[cur][(j * 16 + l16) * 128 + ((kt * 32 + quad * 8) ^ rsw)]);
#pragma unroll
      for (int i = 0; i < 2; ++i)
#pragma unroll
        for (int j = 0; j < 4; ++j)
          s_acc[i][j] = __builtin_amdgcn_mfma_f32_16x16x32_bf16(qf[i][kt], bfr[j], s_acc[i][j], 0, 0, 0);
    }

    // mask + PER-LANE partial max (no cross-lane reduce).
    const bool prev = (ci < 8);
    const int doff = (prev ? ci * 64 : (ci - 8) * 64) - qi * 128;
    float mc[2][4];
#pragma unroll
    for (int i = 0; i < 2; ++i)
#pragma unroll
      for (int r = 0; r < 4; ++r) mc[i][r] = -1e30f;
    if (doff >= 0 && doff <= 64) {  // partial chunk: apply mask
#pragma unroll
      for (int i = 0; i < 2; ++i)
#pragma unroll
        for (int j = 0; j < 4; ++j)
#pragma unroll
          for (int r = 0; r < 4; ++r) {
            int rl = wave * 32 + i * 16 + quad * 4 + r;
            int lk = j * 16 + l16;
            bool ok = prev ? (lk + doff > rl) : (lk + doff <= rl);
            float s = ok ? s_acc[i][j][r] : -1e30f;
            s_acc[i][j][r] = s;
            mc[i][r] = fmaxf(mc[i][r], s);
          }
    } else {  // interior: all keys valid
#pragma unroll
      for (int i = 0; i < 2; ++i)
#pragma unroll
        for (int j = 0; j < 4; ++j)
#pragma unroll
          for (int r = 0; r < 4; ++r) mc[i][r] = fmaxf(mc[i][r], s_acc[i][j][r]);
    }

    // defer-max gate on per-lane partials: true-max > m+8 iff __any(partial).
    bool need = false;
#pragma unroll
    for (int i = 0; i < 2; ++i)
#pragma unroll
      for (int r = 0; r < 4; ++r) need = need || (mc[i][r] > m_r[i][r] + 8.f);
    if (__any(need)) {  // rare slow path: true max + rescale (exact)
#pragma unroll
      for (int o = 1; o < 16; o <<= 1)
#pragma unroll
        for (int i = 0; i < 2; ++i)
#pragma unroll
          for (int r = 0; r < 4; ++r)
            mc[i][r] = fmaxf(mc[i][r], __shfl_xor(mc[i][r], o));
      float alpha[2][4];
#pragma unroll
      for (int i = 0; i < 2; ++i)
#pragma unroll
        for (int r = 0; r < 4; ++r) {
          float mn = fmaxf(m_r[i][r], mc[i][r]);
          alpha[i][r] = fexp2(m_r[i][r] - mn);
          m_r[i][r] = mn;
        }
#pragma unroll
      for (int i = 0; i < 2; ++i) {
#pragma unroll
        for (int j = 0; j < 8; ++j)
#pragma unroll
          for (int r = 0; r < 4; ++r) o_acc[i][j][r] *= alpha[i][r];
#pragma unroll
        for (int r = 0; r < 4; ++r) l_acc[i][r] *= alpha[i][r];
      }
    }

    // P = exp2(S - m); masked entries underflow to 0 (s = -1e30)
#pragma unroll
    for (int i = 0; i < 2; ++i)
#pragma unroll
      for (int j = 0; j < 4; ++j)
#pragma unroll
        for (int r = 0; r < 4; ++r)
          s_acc[i][j][r] = fexp2(s_acc[i][j][r] - m_r[i][r]);

    // P -> wave-private Ps region (no barrier needed)
    u16* PsW = &Ps[wave * 2048];
#pragma unroll
    for (int i = 0; i < 2; ++i)
#pragma unroll
      for (int r = 0; r < 4; ++r) {
        int xw = ((quad * 4 + r) & 7) << 3;
#pragma unroll
        for (int j = 0; j < 4; ++j)
          PsW[(i * 16 + quad * 4 + r) * 64 + ((j * 16 + l16) ^ xw)] = f2bf(s_acc[i][j][r]);
      }

    // pre-PV: V[ci] landed; K[ci+1] (newest 4) stays in flight (T4)
    if (ci < c1)
      asm volatile("s_waitcnt vmcnt(4)" ::: "memory");
    else
      asm volatile("s_waitcnt vmcnt(0)" ::: "memory");

    // O += P @ V ; l += P @ 1 (ones-column MFMA, replaces sum butterfly)
#pragma unroll
    for (int kt = 0; kt < 2; ++kt) {
      frag8 pf[2], vf[8];
#pragma unroll
      for (int i = 0; i < 2; ++i)
        pf[i] = *(const frag8*)(PsW + (i * 16 + l16) * 64 + ((kt * 32 + quad * 8) ^ rsw));
#pragma unroll
      for (int j = 0; j < 8; ++j)
        vf[j] = *(const frag8*)(&Vs[(j * 16 + l16) * 64 + ((kt * 32 + quad * 8) ^ rsw)]);
#pragma unroll
      for (int i = 0; i < 2; ++i) {
#pragma unroll
        for (int j = 0; j < 8; ++j)
          o_acc[i][j] = __builtin_amdgcn_mfma_f32_16x16x32_bf16(pf[i], vf[j], o_acc[i][j], 0, 0, 0);
        l_acc[i] = __builtin_amdgcn_mfma_f32_16x16x32_bf16(pf[i], onef, l_acc[i], 0, 0, 0);
      }
    }

    // end: K[ci+1] landed; all waves done with Ks[cur]/Vs -> restage safe
    asm volatile("s_waitcnt vmcnt(0)" ::: "memory");
    __builtin_amdgcn_s_barrier();
    asm volatile("" ::: "memory");
    cur ^= 1;
  }

  float inv[2][4];
#pragma unroll
  for (int i = 0; i < 2; ++i)
#pragma unroll
    for (int r = 0; r < 4; ++r) inv[i][r] = 1.0f / l_acc[i][r];
  u16* Ob = &Ks[0][0];  // 32KB contiguous: [128 row][128 u16]
#pragma unroll
  for (int i = 0; i < 2; ++i)
#pragma unroll
    for (int j = 0; j < 8; ++j)
#pragma unroll
      for (int r = 0; r < 4; ++r)
        Ob[(wave * 32 + i * 16 + quad * 4 + r) * 128 + j * 16 + l16] =
            f2bf(o_acc[i][j][r] * inv[i][r]);
  __syncthreads();
#pragma unroll
  for (int p = 0; p < 8; ++p) {
    int idx = p * 256 + tid;
    int row = idx >> 4, col = (idx & 15) * 8;
    *(frag8*)(O + (tok_q + row) * 2048 + h * 128 + col) = *(const frag8*)(Ob + row * 128 + col);
  }
}

__global__ void k_convert(const float4* __restrict__ x, ushort4* __restrict__ xb) {
  int i = blockIdx.x * 256 + threadIdx.x;
  float4 f = x[i];
  ushort4 o;
  o.x = f2bf(f.x); o.y = f2bf(f.y); o.z = f2bf(f.z); o.w = f2bf(f.w);
  xb[i] = o;
}

// W [K,N] fp32 -> W^T [N,K] bf16
__global__ void k_transpose(const float* __restrict__ W, u16* __restrict__ WT, int K, int N) {
  __shared__ float sh[32][33];
  int n0 = blockIdx.x * 32, k0 = blockIdx.y * 32;
  int tx = threadIdx.x, ty = threadIdx.y;  // (32, 8)
#pragma unroll
  for (int i = 0; i < 32; i += 8) sh[ty + i][tx] = W[(long)(k0 + ty + i) * N + n0 + tx];
  __syncthreads();
#pragma unroll
  for (int i = 0; i < 32; i += 8) WT[(long)(n0 + ty + i) * K + k0 + tx] = f2bf(sh[tx][ty + i]);
}

extern "C" void kernel_launch(void* const* d_in, const int* in_sizes, int n_in,
                              void* d_out, int out_size, void* d_ws, size_t ws_size,
                              hipStream_t stream) {
  const float* x  = (const float*)d_in[0];
  const float* Wq = (const float*)d_in[1];
  const float* Wk = (const float*)d_in[2];
  const float* Wv = (const float*)d_in[3];
  const float* Wo = (const float*)d_in[4];
  float* out = (float*)d_out;

  const long BT = 8192, D = 2048, NKV = 512;
  size_t off = 0;
  auto alloc = [&](size_t bytes) -> char* {
    off = (off + 255) & ~(size_t)255;
    char* p = (char*)d_ws + off;
    off += bytes;
    return p;
  };

  u16* xb  = (u16*)alloc((size_t)BT * D * 2);  // reused as attention output
  u16* WqT = (u16*)alloc((size_t)D * D * 2);
  u16* WkT = (u16*)alloc((size_t)NKV * D * 2);
  u16* WvT = (u16*)alloc((size_t)NKV * D * 2);
  u16* WoT = (u16*)alloc((size_t)D * D * 2);
  u16* qb  = (u16*)alloc((size_t)BT * D * 2);
  u16* kb  = (u16*)alloc((size_t)BT * NKV * 2);
  u16* vT  = (u16*)alloc((size_t)NKV * BT * 2);
  u16* Oa  = xb;

  k_convert<<<16384, 256, 0, stream>>>((const float4*)x, (ushort4*)xb);
  dim3 tb(32, 8);
  k_transpose<<<dim3(64, 64), tb, 0, stream>>>(Wq, WqT, 2048, 2048);
  k_transpose<<<dim3(16, 64), tb, 0, stream>>>(Wk, WkT, 2048, 512);
  k_transpose<<<dim3(16, 64), tb, 0, stream>>>(Wv, WvT, 2048, 512);
  k_transpose<<<dim3(64, 64), tb, 0, stream>>>(Wo, WoT, 2048, 2048);

  // Q projection pre-scales by (1/sqrt(HD)) * log2(e)  (softmax in exp2 domain)
  const float qscale = 0.08838834764831845f * 1.4426950408889634f;
  k_gemm256<u16><<<dim3(32, 8), 512, 0, stream>>>(xb, 2048, WqT, 2048, qb, 2048, 2048,
                                                  qscale);
  k_gemm_bf16 <<<dim3(64, 4),  256, 0, stream>>>(xb, 2048, WkT, 2048, kb, 512, 2048);
  k_gemm_bf16t<<<dim3(64, 4),  256, 0, stream>>>(xb, 2048, WvT, 2048, vT, 8192, 2048);

  k_attn<<<dim3(4, 8, 32), 256, 0, stream>>>(qb, kb, vT, Oa);

  k_gemm256<float><<<dim3(32, 8), 512, 0, stream>>>(Oa, 2048, WoT, 2048, out, 2048, 2048,
                                                    1.0f);
}

// Round 9
// 412.158 us; speedup vs baseline: 1.3227x; 1.0238x over previous
//
#include <hip/hip_runtime.h>
#include <stdint.h>

// LocalWindowAttention: B=2,T=4096,D=2048,H=16,HK=4,HD=128,WIN=512
// R11: k_gemm256 K-tile restructure (was 4-phase/8-barrier, B read twice):
//      - B fragments read ONCE per tile (32->24 ds_read_b128/wave/tile;
//        DS pipe is the dominant resource at 8 waves/CU).
//      - ONE compute region per tile (24 reads + 64 MFMA, compiler's
//        fine-grained lgkmcnt interleaves them), TWO barriers/tile:
//        publish (after gload-issue + counted vmcnt(8)) and end (protects
//        the just-read buffer from next iter's staging).
//      - af-hi in a separate named array (no WAR chain on af regs).
//      attn (R10) and 128^2 gemms unchanged.

typedef unsigned short u16;
typedef __attribute__((ext_vector_type(8))) short frag8;   // 8 bf16 = 4 VGPRs
typedef __attribute__((ext_vector_type(4))) float f32x4;   // MFMA acc

#define TILE 128

__device__ __forceinline__ u16 f2bf(float f) {
  union { float f; unsigned u; } c; c.f = f;
  unsigned u = c.u;
  return (u16)((u + 0x7fffu + ((u >> 16) & 1u)) >> 16);
}

__device__ __forceinline__ float fexp2(float x) {  // D = 2^S0 (v_exp_f32)
  float r;
  asm("v_exp_f32 %0, %1" : "=v"(r) : "v"(x));
  return r;
}

// async global->LDS, 16B per lane; LDS dest = wave-uniform base + lane*16
__device__ __forceinline__ void async16(const u16* g, u16* l) {
  __builtin_amdgcn_global_load_lds((const __attribute__((address_space(1))) void*)g,
                                   (__attribute__((address_space(3))) void*)l, 16, 0, 0);
}

// T1: XCD-chunked remap. Requires gridDim.x % 8 == 0.
__device__ __forceinline__ void xcd_map(int& bx, int& by) {
  const int gx = gridDim.x;
  const int cx = gx >> 3;
  int id = blockIdx.y * gx + blockIdx.x;
  int xcd = id & 7, local = id >> 3;
  bx = xcd * cx + (local % cx);
  by = local / cx;
}

// ======================= 256^2 GEMM (2-barrier/tile) =====================
// A [M,K] row-major bf16, Bt = B^T [N,K] row-major bf16, C [M,N] (u16|f32).
// Tile 256x256, BK=64, dbuf. LDS [256 rows][64 k] with col^=(row&7)<<3
// swizzle via inverse-swizzled global src. All 8 next-tile gloads at tile
// top; counted vmcnt(8) (tile t's 8 loads had a full tile-time in flight).
template <typename OutT>
__global__ __launch_bounds__(512, 2) void k_gemm256(const u16* __restrict__ A, int lda,
                                                    const u16* __restrict__ Bt, int ldb,
                                                    OutT* __restrict__ C, int ldc, int K,
                                                    float oscale) {
  __shared__ alignas(16) u16 Ab[2][256 * 64];  // 64 KB
  __shared__ alignas(16) u16 Bb[2][256 * 64];  // 64 KB
  const int tid = threadIdx.x, lane = tid & 63, wave = tid >> 6;
  const int wm = wave >> 2, wn = wave & 3;     // 2M x 4N wave grid
  const int quad = lane >> 4, l16 = lane & 15;

  int bx, by;
  xcd_map(bx, by);

  // staging coords: issue c, wave w, lane l -> row = c*64+w*8+(l>>3),
  // src col = ((l&7)^(l>>3))*8  (row&7 == l>>3 -> involution holds)
  const int rsub = wave * 8 + (lane >> 3);
  const int csub = ((lane & 7) ^ (lane >> 3)) * 8;
  const u16* Ag = A + ((long)bx * 256 + rsub) * lda + csub;
  const u16* Bg = Bt + ((long)by * 256 + rsub) * ldb + csub;
  const long a64 = (long)64 * lda, b64 = (long)64 * ldb;

  const int rsw = (l16 & 7) << 3;  // read-side XOR (u16 units)

  f32x4 acc[8][4];
#pragma unroll
  for (int i = 0; i < 8; ++i)
#pragma unroll
    for (int j = 0; j < 4; ++j) acc[i][j] = (f32x4){0.f, 0.f, 0.f, 0.f};

  const int nt = K >> 6;

  // prologue: stage tile 0 (8 inst/wave)
#pragma unroll
  for (int c = 0; c < 4; ++c) {
    async16(Ag + c * a64, &Ab[0][c * 4096 + wave * 512]);
    async16(Bg + c * b64, &Bb[0][c * 4096 + wave * 512]);
  }

  for (int t = 0; t < nt; ++t) {
    const int buf = t & 1, nb = buf ^ 1;
    const long koff = (long)(t + 1) << 6;

    // issue ALL next-tile loads, then drain tile t (counted, T4)
    if (t + 1 < nt) {
#pragma unroll
      for (int c = 0; c < 4; ++c) {
        async16(Ag + c * a64 + koff, &Ab[nb][c * 4096 + wave * 512]);
        async16(Bg + c * b64 + koff, &Bb[nb][c * 4096 + wave * 512]);
      }
      asm volatile("s_waitcnt vmcnt(8)" ::: "memory");  // tile t fully landed
    } else {
      asm volatile("s_waitcnt vmcnt(0)" ::: "memory");
    }
    __builtin_amdgcn_s_barrier();  // publish tile t
    asm volatile("" ::: "memory");

    // all 24 reads: af (M-half 0), af2 (M-half 1), bf (all N, ONCE)
    frag8 af[4][2], af2[4][2], bf[4][2];
#pragma unroll
    for (int i = 0; i < 4; ++i)
#pragma unroll
      for (int kk = 0; kk < 2; ++kk) {
        af[i][kk]  = *(const frag8*)(&Ab[buf][(wm * 128 + i * 16 + l16) * 64 +
                                              ((kk * 32 + quad * 8) ^ rsw)]);
        af2[i][kk] = *(const frag8*)(&Ab[buf][(wm * 128 + (i + 4) * 16 + l16) * 64 +
                                              ((kk * 32 + quad * 8) ^ rsw)]);
      }
#pragma unroll
    for (int j = 0; j < 4; ++j)
#pragma unroll
      for (int kk = 0; kk < 2; ++kk)
        bf[j][kk] = *(const frag8*)(&Bb[buf][(wn * 64 + j * 16 + l16) * 64 +
                                             ((kk * 32 + quad * 8) ^ rsw)]);

    // 64 MFMA in one cluster (compiler interleaves with fine lgkmcnt)
    __builtin_amdgcn_s_setprio(1);
#pragma unroll
    for (int kk = 0; kk < 2; ++kk)
#pragma unroll
      for (int i = 0; i < 4; ++i)
#pragma unroll
        for (int j = 0; j < 4; ++j)
          acc[i][j] = __builtin_amdgcn_mfma_f32_16x16x32_bf16(af[i][kk], bf[j][kk], acc[i][j], 0, 0, 0);
#pragma unroll
    for (int kk = 0; kk < 2; ++kk)
#pragma unroll
      for (int i = 0; i < 4; ++i)
#pragma unroll
        for (int j = 0; j < 4; ++j)
          acc[i + 4][j] = __builtin_amdgcn_mfma_f32_16x16x32_bf16(af2[i][kk], bf[j][kk], acc[i + 4][j], 0, 0, 0);
    __builtin_amdgcn_s_setprio(0);

    // end: all waves done reading buf -> next iter may stage into it
    asm volatile("" ::: "memory");
    __builtin_amdgcn_s_barrier();
    asm volatile("" ::: "memory");
  }

  // epilogue (oscale folded; used to pre-scale Q)
  OutT* Ct = C + ((long)bx * 256 + wm * 128) * ldc + (long)by * 256 + wn * 64;
#pragma unroll
  for (int i = 0; i < 8; ++i)
#pragma unroll
    for (int j = 0; j < 4; ++j) {
      int r0 = i * 16 + quad * 4, cc = j * 16 + l16;
#pragma unroll
      for (int r = 0; r < 4; ++r) {
        float v = acc[i][j][r] * oscale;
        if constexpr (sizeof(OutT) == 2)
          Ct[(long)(r0 + r) * ldc + cc] = f2bf(v);
        else
          Ct[(long)(r0 + r) * ldc + cc] = v;
      }
    }
}

// ---- 128x128 GEMM core, double-buffered + counted vmcnt (T3-min) --------
__device__ __forceinline__ void gemm_core(const u16* __restrict__ A, int lda,
                                          const u16* __restrict__ Bt, int ldb,
                                          int K, u16* As, u16* Bs, f32x4 acc[4][4]) {
  const int tid = threadIdx.x;
  const int lane = tid & 63, wave = tid >> 6;
  const int wr = wave >> 1, wc = wave & 1;
  const int quad = lane >> 4, l16 = lane & 15;
#pragma unroll
  for (int i = 0; i < 4; ++i)
#pragma unroll
    for (int j = 0; j < 4; ++j) acc[i][j] = (f32x4){0.f, 0.f, 0.f, 0.f};

  const int row0 = tid >> 2, offc = (tid & 3) * 8;  // 128 rows x 32 k, 16B chunks
  const int nt = K >> 5;

  // prologue: tile 0
#pragma unroll
  for (int r = 0; r < 2; ++r) {
    int row = r * 64 + row0;
    async16(A + (long)row * lda + offc, As + r * 2048 + wave * 512);
    async16(Bt + (long)row * ldb + offc, Bs + r * 2048 + wave * 512);
  }

  for (int t = 0; t < nt; ++t) {
    const int bo = (t & 1) * 4096, nbo = bo ^ 4096;
    if (t + 1 < nt) {
      const int k0 = (t + 1) * 32;
#pragma unroll
      for (int r = 0; r < 2; ++r) {
        int row = r * 64 + row0;
        async16(A + (long)row * lda + k0 + offc, As + nbo + r * 2048 + wave * 512);
        async16(Bt + (long)row * ldb + k0 + offc, Bs + nbo + r * 2048 + wave * 512);
      }
      asm volatile("s_waitcnt vmcnt(4)" ::: "memory");  // tile t landed
    } else {
      asm volatile("s_waitcnt vmcnt(0)" ::: "memory");
    }
    __builtin_amdgcn_s_barrier();
    asm volatile("" ::: "memory");

    frag8 af[4], bf[4];
#pragma unroll
    for (int i = 0; i < 4; ++i)
      af[i] = *(const frag8*)(As + bo + (wr * 64 + i * 16 + l16) * 32 + quad * 8);
#pragma unroll
    for (int j = 0; j < 4; ++j)
      bf[j] = *(const frag8*)(Bs + bo + (wc * 64 + j * 16 + l16) * 32 + quad * 8);
#pragma unroll
    for (int i = 0; i < 4; ++i)
#pragma unroll
      for (int j = 0; j < 4; ++j)
        acc[i][j] = __builtin_amdgcn_mfma_f32_16x16x32_bf16(af[i], bf[j], acc[i][j], 0, 0, 0);
    asm volatile("" ::: "memory");
    __builtin_amdgcn_s_barrier();  // all reads of buf done before restage
  }
}

#define EPI_COORDS                                             \
  const int lane = threadIdx.x & 63, wave = threadIdx.x >> 6;  \
  const int wr = wave >> 1, wc = wave & 1;                     \
  const int quad = lane >> 4, l16 = lane & 15;

__global__ __launch_bounds__(256) void k_gemm_bf16(const u16* __restrict__ A, int lda,
                                                   const u16* __restrict__ Bt, int ldb,
                                                   u16* __restrict__ C, int ldc, int K) {
  __shared__ alignas(16) u16 smem[4 * TILE * 32];  // 2 bufs x (A,B)
  int bx, by; xcd_map(bx, by);
  f32x4 acc[4][4];
  gemm_core(A + (long)bx * TILE * lda, lda,
            Bt + (long)by * TILE * ldb, ldb, K, smem, smem + 2 * TILE * 32, acc);
  EPI_COORDS
  u16* Ct = C + (long)bx * TILE * ldc + (long)by * TILE;
#pragma unroll
  for (int i = 0; i < 4; ++i)
#pragma unroll
    for (int j = 0; j < 4; ++j) {
      int r0 = wr * 64 + i * 16 + quad * 4, cc = wc * 64 + j * 16 + l16;
#pragma unroll
      for (int r = 0; r < 4; ++r) Ct[(long)(r0 + r) * ldc + cc] = f2bf(acc[i][j][r]);
    }
}

// writes C^T: contiguous 4-element store per acc tile (for V^T layout)
__global__ __launch_bounds__(256) void k_gemm_bf16t(const u16* __restrict__ A, int lda,
                                                    const u16* __restrict__ Bt, int ldb,
                                                    u16* __restrict__ Ct, int ldct, int K) {
  __shared__ alignas(16) u16 smem[4 * TILE * 32];
  int bx, by; xcd_map(bx, by);
  f32x4 acc[4][4];
  gemm_core(A + (long)bx * TILE * lda, lda,
            Bt + (long)by * TILE * ldb, ldb, K, smem, smem + 2 * TILE * 32, acc);
  EPI_COORDS
  u16* Cb = Ct + (long)by * TILE * ldct + (long)bx * TILE;
#pragma unroll
  for (int i = 0; i < 4; ++i)
#pragma unroll
    for (int j = 0; j < 4; ++j) {
      int n = wc * 64 + j * 16 + l16, m0 = wr * 64 + i * 16 + quad * 4;
      ushort4 o;
      o.x = f2bf(acc[i][j][0]); o.y = f2bf(acc[i][j][1]);
      o.z = f2bf(acc[i][j][2]); o.w = f2bf(acc[i][j][3]);
      *(ushort4*)(Cb + (long)n * ldct + m0) = o;
    }
}

// ---- fused local-window attention (R10: 1-barrier, shuffle-free) ---------
__global__ __launch_bounds__(256, 2) void k_attn(const u16* __restrict__ qb,
                                                 const u16* __restrict__ kb,
                                                 const u16* __restrict__ vT,
                                                 u16* __restrict__ O) {
  __shared__ alignas(16) u16 Ks[2][64 * 128];  // [key][hd] swizzled, 32KB
  __shared__ alignas(16) u16 Vs[128 * 64];     // [hd][key] swizzled, 16KB
  __shared__ alignas(16) u16 Ps[4 * 32 * 64];  // wave-private P, 16KB
  const int tid = threadIdx.x, lane = tid & 63, wave = tid >> 6;
  const int quad = lane >> 4, l16 = lane & 15;

  // XCD-group decode: 16 siblings sharing (b,hk,blk) land on one XCD
  const int id = blockIdx.x + 4 * blockIdx.y + 32 * blockIdx.z;  // 0..1023
  const int g = (id & 7) | ((id >> 7) << 3);                     // group 0..63
  const int w = (id >> 3) & 15;                                  // member 0..15
  const int hk = g & 3, blk = (g >> 2) & 7, b = g >> 5;
  const int h = hk * 4 + (w & 3), qi = w >> 2;

  const long tok_q = (long)b * 4096 + blk * 512 + qi * 128;

  frag8 qf[2][4];
#pragma unroll
  for (int i = 0; i < 2; ++i)
#pragma unroll
    for (int kt = 0; kt < 4; ++kt)
      qf[i][kt] = *(const frag8*)(qb + (tok_q + wave * 32 + i * 16 + l16) * 2048 +
                                  h * 128 + kt * 32 + quad * 8);

  // ones fragment (bf16 1.0) for the l = P @ 1 column
  frag8 onef;
#pragma unroll
  for (int e = 0; e < 8; ++e) onef[e] = (short)0x3F80;

  f32x4 o_acc[2][8], l_acc[2];
  float m_r[2][4];
#pragma unroll
  for (int i = 0; i < 2; ++i) {
#pragma unroll
    for (int j = 0; j < 8; ++j) o_acc[i][j] = (f32x4){0.f, 0.f, 0.f, 0.f};
    l_acc[i] = (f32x4){0.f, 0.f, 0.f, 0.f};
#pragma unroll
    for (int r = 0; r < 4; ++r) m_r[i][r] = 0.f;  // finite start: exp2(s) direct
  }

  const int rsw = (l16 & 7) << 3;  // read-side XOR (u16)

  auto stageK = [&](int buf, int ci) {
    const long tk = (long)b * 4096 + (blk - 1) * 512 + ci * 64;
#pragma unroll
    for (int c = 0; c < 4; ++c) {
      const int idx = (wave * 4 + c) * 512 + lane * 8;  // u16 index, linear
      int row = idx >> 7, col = idx & 127;
      async16(kb + (tk + row) * 512 + hk * 128 + (col ^ ((row & 7) << 3)),
              &Ks[buf][(wave * 4 + c) * 512]);
    }
  };
  auto stageV = [&](int ci) {
    const long tk = (long)b * 4096 + (blk - 1) * 512 + ci * 64;
#pragma unroll
    for (int c = 0; c < 4; ++c) {
      const int idx = (wave * 4 + c) * 512 + lane * 8;
      int row = idx >> 6, col = idx & 63;
      async16(vT + ((long)hk * 128 + row) * 8192 + tk + (col ^ ((row & 7) << 3)),
              &Vs[(wave * 4 + c) * 512]);
    }
  };

  const int c0 = blk ? 2 * qi : 8, c1 = 9 + 2 * qi;
  int cur = 0;
  stageK(0, c0);
  stageV(c0);
  asm volatile("s_waitcnt vmcnt(0)" ::: "memory");
  __builtin_amdgcn_s_barrier();
  asm volatile("" ::: "memory");

  for (int ci = c0; ci <= c1; ++ci) {
    if (ci > c0) stageV(ci);              // Vs free: prev end barrier passed
    if (ci < c1) stageK(cur ^ 1, ci + 1); // K prefetch into free buffer

    // S = Q @ K^T  (32 rows x 64 keys per wave)
    f32x4 s_acc[2][4];
#pragma unroll
    for (int i = 0; i < 2; ++i)
#pragma unroll
      for (int j = 0; j < 4; ++j) s_acc[i][j] = (f32x4){0.f, 0.f, 0.f, 0.f};
#pragma unroll
    for (int kt = 0; kt < 4; ++kt) {
      frag8 bfr[4];
#pragma unroll
      for (int j = 0; j < 4; ++j)
        bfr[j] = *(const frag8*)(&Ks[cur][(j * 16 + l16) * 128 + ((kt * 32 + quad * 8) ^ rsw)]);
#pragma unroll
      for (int i = 0; i < 2; ++i)
#pragma unroll
        for (int j = 0; j < 4; ++j)
          s_acc[i][j] = __builtin_amdgcn_mfma_f32_16x16x32_bf16(qf[i][kt], bfr[j], s_acc[i][j], 0, 0, 0);
    }

    // mask + PER-LANE partial max (no cross-lane reduce).
    const bool prev = (ci < 8);
    const int doff = (prev ? ci * 64 : (ci - 8) * 64) - qi * 128;
    float mc[2][4];
#pragma unroll
    for (int i = 0; i < 2; ++i)
#pragma unroll
      for (int r = 0; r < 4; ++r) mc[i][r] = -1e30f;
    if (doff >= 0 && doff <= 64) {  // partial chunk: apply mask
#pragma unroll
      for (int i = 0; i < 2; ++i)
#pragma unroll
        for (int j = 0; j < 4; ++j)
#pragma unroll
          for (int r = 0; r < 4; ++r) {
            int rl = wave * 32 + i * 16 + quad * 4 + r;
            int lk = j * 16 + l16;
            bool ok = prev ? (lk + doff > rl) : (lk + doff <= rl);
            float s = ok ? s_acc[i][j][r] : -1e30f;
            s_acc[i][j][r] = s;
            mc[i][r] = fmaxf(mc[i][r], s);
          }
    } else {  // interior: all keys valid
#pragma unroll
      for (int i = 0; i < 2; ++i)
#pragma unroll
        for (int j = 0; j < 4; ++j)
#pragma unroll
          for (int r = 0; r < 4; ++r) mc[i][r] = fmaxf(mc[i][r], s_acc[i][j][r]);
    }

    // defer-max gate on per-lane partials: true-max > m+8 iff __any(partial).
    bool need = false;
#pragma unroll
    for (int i = 0; i < 2; ++i)
#pragma unroll
      for (int r = 0; r < 4; ++r) need = need || (mc[i][r] > m_r[i][r] + 8.f);
    if (__any(need)) {  // rare slow path: true max + rescale (exact)
#pragma unroll
      for (int o = 1; o < 16; o <<= 1)
#pragma unroll
        for (int i = 0; i < 2; ++i)
#pragma unroll
          for (int r = 0; r < 4; ++r)
            mc[i][r] = fmaxf(mc[i][r], __shfl_xor(mc[i][r], o));
      float alpha[2][4];
#pragma unroll
      for (int i = 0; i < 2; ++i)
#pragma unroll
        for (int r = 0; r < 4; ++r) {
          float mn = fmaxf(m_r[i][r], mc[i][r]);
          alpha[i][r] = fexp2(m_r[i][r] - mn);
          m_r[i][r] = mn;
        }
#pragma unroll
      for (int i = 0; i < 2; ++i) {
#pragma unroll
        for (int j = 0; j < 8; ++j)
#pragma unroll
          for (int r = 0; r < 4; ++r) o_acc[i][j][r] *= alpha[i][r];
#pragma unroll
        for (int r = 0; r < 4; ++r) l_acc[i][r] *= alpha[i][r];
      }
    }

    // P = exp2(S - m); masked entries underflow to 0 (s = -1e30)
#pragma unroll
    for (int i = 0; i < 2; ++i)
#pragma unroll
      for (int j = 0; j < 4; ++j)
#pragma unroll
        for (int r = 0; r < 4; ++r)
          s_acc[i][j][r] = fexp2(s_acc[i][j][r] - m_r[i][r]);

    // P -> wave-private Ps region (no barrier needed)
    u16* PsW = &Ps[wave * 2048];
#pragma unroll
    for (int i = 0; i < 2; ++i)
#pragma unroll
      for (int r = 0; r < 4; ++r) {
        int xw = ((quad * 4 + r) & 7) << 3;
#pragma unroll
        for (int j = 0; j < 4; ++j)
          PsW[(i * 16 + quad * 4 + r) * 64 + ((j * 16 + l16) ^ xw)] = f2bf(s_acc[i][j][r]);
      }

    // pre-PV: V[ci] landed; K[ci+1] (newest 4) stays in flight (T4)
    if (ci < c1)
      asm volatile("s_waitcnt vmcnt(4)" ::: "memory");
    else
      asm volatile("s_waitcnt vmcnt(0)" ::: "memory");

    // O += P @ V ; l += P @ 1 (ones-column MFMA, replaces sum butterfly)
#pragma unroll
    for (int kt = 0; kt < 2; ++kt) {
      frag8 pf[2], vf[8];
#pragma unroll
      for (int i = 0; i < 2; ++i)
        pf[i] = *(const frag8*)(PsW + (i * 16 + l16) * 64 + ((kt * 32 + quad * 8) ^ rsw));
#pragma unroll
      for (int j = 0; j < 8; ++j)
        vf[j] = *(const frag8*)(&Vs[(j * 16 + l16) * 64 + ((kt * 32 + quad * 8) ^ rsw)]);
#pragma unroll
      for (int i = 0; i < 2; ++i) {
#pragma unroll
        for (int j = 0; j < 8; ++j)
          o_acc[i][j] = __builtin_amdgcn_mfma_f32_16x16x32_bf16(pf[i], vf[j], o_acc[i][j], 0, 0, 0);
        l_acc[i] = __builtin_amdgcn_mfma_f32_16x16x32_bf16(pf[i], onef, l_acc[i], 0, 0, 0);
      }
    }

    // end: K[ci+1] landed; all waves done with Ks[cur]/Vs -> restage safe
    asm volatile("s_waitcnt vmcnt(0)" ::: "memory");
    __builtin_amdgcn_s_barrier();
    asm volatile("" ::: "memory");
    cur ^= 1;
  }

  float inv[2][4];
#pragma unroll
  for (int i = 0; i < 2; ++i)
#pragma unroll
    for (int r = 0; r < 4; ++r) inv[i][r] = 1.0f / l_acc[i][r];
  u16* Ob = &Ks[0][0];  // 32KB contiguous: [128 row][128 u16]
#pragma unroll
  for (int i = 0; i < 2; ++i)
#pragma unroll
    for (int j = 0; j < 8; ++j)
#pragma unroll
      for (int r = 0; r < 4; ++r)
        Ob[(wave * 32 + i * 16 + quad * 4 + r) * 128 + j * 16 + l16] =
            f2bf(o_acc[i][j][r] * inv[i][r]);
  __syncthreads();
#pragma unroll
  for (int p = 0; p < 8; ++p) {
    int idx = p * 256 + tid;
    int row = idx >> 4, col = (idx & 15) * 8;
    *(frag8*)(O + (tok_q + row) * 2048 + h * 128 + col) = *(const frag8*)(Ob + row * 128 + col);
  }
}

__global__ void k_convert(const float4* __restrict__ x, ushort4* __restrict__ xb) {
  int i = blockIdx.x * 256 + threadIdx.x;
  float4 f = x[i];
  ushort4 o;
  o.x = f2bf(f.x); o.y = f2bf(f.y); o.z = f2bf(f.z); o.w = f2bf(f.w);
  xb[i] = o;
}

// W [K,N] fp32 -> W^T [N,K] bf16
__global__ void k_transpose(const float* __restrict__ W, u16* __restrict__ WT, int K, int N) {
  __shared__ float sh[32][33];
  int n0 = blockIdx.x * 32, k0 = blockIdx.y * 32;
  int tx = threadIdx.x, ty = threadIdx.y;  // (32, 8)
#pragma unroll
  for (int i = 0; i < 32; i += 8) sh[ty + i][tx] = W[(long)(k0 + ty + i) * N + n0 + tx];
  __syncthreads();
#pragma unroll
  for (int i = 0; i < 32; i += 8) WT[(long)(n0 + ty + i) * K + k0 + tx] = f2bf(sh[tx][ty + i]);
}

extern "C" void kernel_launch(void* const* d_in, const int* in_sizes, int n_in,
                              void* d_out, int out_size, void* d_ws, size_t ws_size,
                              hipStream_t stream) {
  const float* x  = (const float*)d_in[0];
  const float* Wq = (const float*)d_in[1];
  const float* Wk = (const float*)d_in[2];
  const float* Wv = (const float*)d_in[3];
  const float* Wo = (const float*)d_in[4];
  float* out = (float*)d_out;

  const long BT = 8192, D = 2048, NKV = 512;
  size_t off = 0;
  auto alloc = [&](size_t bytes) -> char* {
    off = (off + 255) & ~(size_t)255;
    char* p = (char*)d_ws + off;
    off += bytes;
    return p;
  };

  u16* xb  = (u16*)alloc((size_t)BT * D * 2);  // reused as attention output
  u16* WqT = (u16*)alloc((size_t)D * D * 2);
  u16* WkT = (u16*)alloc((size_t)NKV * D * 2);
  u16* WvT = (u16*)alloc((size_t)NKV * D * 2);
  u16* WoT = (u16*)alloc((size_t)D * D * 2);
  u16* qb  = (u16*)alloc((size_t)BT * D * 2);
  u16* kb  = (u16*)alloc((size_t)BT * NKV * 2);
  u16* vT  = (u16*)alloc((size_t)NKV * BT * 2);
  u16* Oa  = xb;

  k_convert<<<16384, 256, 0, stream>>>((const float4*)x, (ushort4*)xb);
  dim3 tb(32, 8);
  k_transpose<<<dim3(64, 64), tb, 0, stream>>>(Wq, WqT, 2048, 2048);
  k_transpose<<<dim3(16, 64), tb, 0, stream>>>(Wk, WkT, 2048, 512);
  k_transpose<<<dim3(16, 64), tb, 0, stream>>>(Wv, WvT, 2048, 512);
  k_transpose<<<dim3(64, 64), tb, 0, stream>>>(Wo, WoT, 2048, 2048);

  // Q projection pre-scales by (1/sqrt(HD)) * log2(e)  (softmax in exp2 domain)
  const float qscale = 0.08838834764831845f * 1.4426950408889634f;
  k_gemm256<u16><<<dim3(32, 8), 512, 0, stream>>>(xb, 2048, WqT, 2048, qb, 2048, 2048,
                                                  qscale);
  k_gemm_bf16 <<<dim3(64, 4),  256, 0, stream>>>(xb, 2048, WkT, 2048, kb, 512, 2048);
  k_gemm_bf16t<<<dim3(64, 4),  256, 0, stream>>>(xb, 2048, WvT, 2048, vT, 8192, 2048);

  k_attn<<<dim3(4, 8, 32), 256, 0, stream>>>(qb, kb, vT, Oa);

  k_gemm256<float><<<dim3(32, 8), 512, 0, stream>>>(Oa, 2048, WoT, 2048, out, 2048, 2048,
                                                    1.0f);
}

// Round 10
// 404.859 us; speedup vs baseline: 1.3466x; 1.0180x over previous
//
#include <hip/hip_runtime.h>
#include <stdint.h>

// LocalWindowAttention: B=2,T=4096,D=2048,H=16,HK=4,HD=128,WIN=512
// R12: k_gemm256 -> m201-style phase schedule (4 phases/K-tile, 2 barriers
//      each, per-phase ds-read subtile + MFMA quadrant, staging spread to
//      phases 2 (A) and 3 (B) where the target regions are read-free,
//      vmcnt(8) once per K-tile at phase 3 -> 6-phase load flight, T4).
//      Hazard ledger: A-region free after p1-end (p0 reads rows {0-63,
//      128-191}, p1 {64-127,192-255}); B-region free after p2-end.
//      attn (R10) and 128^2 gemms unchanged.

typedef unsigned short u16;
typedef __attribute__((ext_vector_type(8))) short frag8;   // 8 bf16 = 4 VGPRs
typedef __attribute__((ext_vector_type(4))) float f32x4;   // MFMA acc

#define TILE 128

__device__ __forceinline__ u16 f2bf(float f) {
  union { float f; unsigned u; } c; c.f = f;
  unsigned u = c.u;
  return (u16)((u + 0x7fffu + ((u >> 16) & 1u)) >> 16);
}

__device__ __forceinline__ float fexp2(float x) {  // D = 2^S0 (v_exp_f32)
  float r;
  asm("v_exp_f32 %0, %1" : "=v"(r) : "v"(x));
  return r;
}

// async global->LDS, 16B per lane; LDS dest = wave-uniform base + lane*16
__device__ __forceinline__ void async16(const u16* g, u16* l) {
  __builtin_amdgcn_global_load_lds((const __attribute__((address_space(1))) void*)g,
                                   (__attribute__((address_space(3))) void*)l, 16, 0, 0);
}

// T1: XCD-chunked remap. Requires gridDim.x % 8 == 0.
__device__ __forceinline__ void xcd_map(int& bx, int& by) {
  const int gx = gridDim.x;
  const int cx = gx >> 3;
  int id = blockIdx.y * gx + blockIdx.x;
  int xcd = id & 7, local = id >> 3;
  bx = xcd * cx + (local % cx);
  by = local / cx;
}

#define FENCE asm volatile("" ::: "memory")

// ======================= 256^2 GEMM (m201 phase schedule) ================
// A [M,K] row-major bf16, Bt = B^T [N,K] row-major bf16, C [M,N] (u16|f32).
// Tile 256x256, BK=64, dbuf. LDS [256 rows][64 k] with col^=(row&7)<<3
// swizzle via inverse-swizzled global src (linear gload_lds dest).
template <typename OutT>
__global__ __launch_bounds__(512, 2) void k_gemm256(const u16* __restrict__ A, int lda,
                                                    const u16* __restrict__ Bt, int ldb,
                                                    OutT* __restrict__ C, int ldc, int K,
                                                    float oscale) {
  __shared__ alignas(16) u16 Ab[2][256 * 64];  // 64 KB
  __shared__ alignas(16) u16 Bb[2][256 * 64];  // 64 KB
  const int tid = threadIdx.x, lane = tid & 63, wave = tid >> 6;
  const int wm = wave >> 2, wn = wave & 3;     // 2M x 4N wave grid
  const int quad = lane >> 4, l16 = lane & 15;

  int bx, by;
  xcd_map(bx, by);

  // staging coords: issue c, wave w, lane l -> row = c*64+w*8+(l>>3),
  // src col = ((l&7)^(l>>3))*8  (row&7 == l>>3 -> involution holds)
  const int rsub = wave * 8 + (lane >> 3);
  const int csub = ((lane & 7) ^ (lane >> 3)) * 8;
  const u16* Ag = A + ((long)bx * 256 + rsub) * lda + csub;
  const u16* Bg = Bt + ((long)by * 256 + rsub) * ldb + csub;
  const long a64 = (long)64 * lda, b64 = (long)64 * ldb;

  const int rsw = (l16 & 7) << 3;  // read-side XOR (u16 units)

  f32x4 acc[8][4];
#pragma unroll
  for (int i = 0; i < 8; ++i)
#pragma unroll
    for (int j = 0; j < 4; ++j) acc[i][j] = (f32x4){0.f, 0.f, 0.f, 0.f};

  const int nt = K >> 6;

  // prologue: stage tiles 0 and 1 (16 loads/wave); tile 0 landed -> publish
#pragma unroll
  for (int c = 0; c < 4; ++c) {
    async16(Ag + c * a64, &Ab[0][c * 4096 + wave * 512]);
    async16(Bg + c * b64, &Bb[0][c * 4096 + wave * 512]);
  }
#pragma unroll
  for (int c = 0; c < 4; ++c) {
    async16(Ag + c * a64 + 64, &Ab[1][c * 4096 + wave * 512]);
    async16(Bg + c * b64 + 64, &Bb[1][c * 4096 + wave * 512]);
  }
  asm volatile("s_waitcnt vmcnt(8)" ::: "memory");  // tile 0 fully landed
  __builtin_amdgcn_s_barrier();
  FENCE;

  for (int t = 0; t < nt; ++t) {
    const int buf = t & 1;
    const bool st = (t + 2 < nt);
    const long koff = (long)(t + 2) << 6;
    frag8 af_lo[4][2], af_hi[4][2], bf_lo[2][2], bf_hi[2][2];

    // ---- phase 0: read af_lo(8) + bf_lo(4); MFMA quadrant (M0,N0) -------
#pragma unroll
    for (int i = 0; i < 4; ++i)
#pragma unroll
      for (int kk = 0; kk < 2; ++kk)
        af_lo[i][kk] = *(const frag8*)(&Ab[buf][(wm * 128 + i * 16 + l16) * 64 +
                                               ((kk * 32 + quad * 8) ^ rsw)]);
#pragma unroll
    for (int j = 0; j < 2; ++j)
#pragma unroll
      for (int kk = 0; kk < 2; ++kk)
        bf_lo[j][kk] = *(const frag8*)(&Bb[buf][(wn * 64 + j * 16 + l16) * 64 +
                                               ((kk * 32 + quad * 8) ^ rsw)]);
    FENCE;
    __builtin_amdgcn_s_barrier();
    FENCE;
    __builtin_amdgcn_s_setprio(1);
#pragma unroll
    for (int kk = 0; kk < 2; ++kk)
#pragma unroll
      for (int i = 0; i < 4; ++i)
#pragma unroll
        for (int j = 0; j < 2; ++j)
          acc[i][j] = __builtin_amdgcn_mfma_f32_16x16x32_bf16(af_lo[i][kk], bf_lo[j][kk], acc[i][j], 0, 0, 0);
    __builtin_amdgcn_s_setprio(0);
    FENCE;
    __builtin_amdgcn_s_barrier();
    FENCE;

    // ---- phase 1: read af_hi(8); MFMA (M1,N0) — reuse bf_lo -------------
#pragma unroll
    for (int i = 0; i < 4; ++i)
#pragma unroll
      for (int kk = 0; kk < 2; ++kk)
        af_hi[i][kk] = *(const frag8*)(&Ab[buf][(wm * 128 + (i + 4) * 16 + l16) * 64 +
                                               ((kk * 32 + quad * 8) ^ rsw)]);
    FENCE;
    __builtin_amdgcn_s_barrier();
    FENCE;
    __builtin_amdgcn_s_setprio(1);
#pragma unroll
    for (int kk = 0; kk < 2; ++kk)
#pragma unroll
      for (int i = 0; i < 4; ++i)
#pragma unroll
        for (int j = 0; j < 2; ++j)
          acc[i + 4][j] = __builtin_amdgcn_mfma_f32_16x16x32_bf16(af_hi[i][kk], bf_lo[j][kk], acc[i + 4][j], 0, 0, 0);
    __builtin_amdgcn_s_setprio(0);
    FENCE;
    __builtin_amdgcn_s_barrier();
    FENCE;

    // ---- phase 2: read bf_hi(4); stage A(t+2) (A-region read-free since
    //      p1 end barrier); MFMA (M0,N1) — reuse af_lo --------------------
#pragma unroll
    for (int j = 0; j < 2; ++j)
#pragma unroll
      for (int kk = 0; kk < 2; ++kk)
        bf_hi[j][kk] = *(const frag8*)(&Bb[buf][(wn * 64 + (j + 2) * 16 + l16) * 64 +
                                               ((kk * 32 + quad * 8) ^ rsw)]);
    if (st) {
#pragma unroll
      for (int c = 0; c < 4; ++c)
        async16(Ag + c * a64 + koff, &Ab[buf][c * 4096 + wave * 512]);
    }
    FENCE;
    __builtin_amdgcn_s_barrier();
    FENCE;
    __builtin_amdgcn_s_setprio(1);
#pragma unroll
    for (int kk = 0; kk < 2; ++kk)
#pragma unroll
      for (int i = 0; i < 4; ++i)
#pragma unroll
        for (int j = 0; j < 2; ++j)
          acc[i][j + 2] = __builtin_amdgcn_mfma_f32_16x16x32_bf16(af_lo[i][kk], bf_hi[j][kk], acc[i][j + 2], 0, 0, 0);
    __builtin_amdgcn_s_setprio(0);
    FENCE;
    __builtin_amdgcn_s_barrier();
    FENCE;

    // ---- phase 3: stage B(t+2) (B-region read-free since p2 end);
    //      MFMA (M1,N1); vmcnt(8) -> tile t+1 landed; end bar publishes ---
    if (st) {
#pragma unroll
      for (int c = 0; c < 4; ++c)
        async16(Bg + c * b64 + koff, &Bb[buf][c * 4096 + wave * 512]);
    }
    FENCE;
    __builtin_amdgcn_s_barrier();
    FENCE;
    __builtin_amdgcn_s_setprio(1);
#pragma unroll
    for (int kk = 0; kk < 2; ++kk)
#pragma unroll
      for (int i = 0; i < 4; ++i)
#pragma unroll
        for (int j = 0; j < 2; ++j)
          acc[i + 4][j + 2] = __builtin_amdgcn_mfma_f32_16x16x32_bf16(af_hi[i][kk], bf_hi[j][kk], acc[i + 4][j + 2], 0, 0, 0);
    __builtin_amdgcn_s_setprio(0);
    if (st)
      asm volatile("s_waitcnt vmcnt(8)" ::: "memory");  // t+1 landed; t+2 in flight
    else
      asm volatile("s_waitcnt vmcnt(0)" ::: "memory");
    __builtin_amdgcn_s_barrier();
    FENCE;
  }

  // epilogue (oscale folded; used to pre-scale Q)
  OutT* Ct = C + ((long)bx * 256 + wm * 128) * ldc + (long)by * 256 + wn * 64;
#pragma unroll
  for (int i = 0; i < 8; ++i)
#pragma unroll
    for (int j = 0; j < 4; ++j) {
      int r0 = i * 16 + quad * 4, cc = j * 16 + l16;
#pragma unroll
      for (int r = 0; r < 4; ++r) {
        float v = acc[i][j][r] * oscale;
        if constexpr (sizeof(OutT) == 2)
          Ct[(long)(r0 + r) * ldc + cc] = f2bf(v);
        else
          Ct[(long)(r0 + r) * ldc + cc] = v;
      }
    }
}

// ---- 128x128 GEMM core, double-buffered + counted vmcnt (T3-min) --------
__device__ __forceinline__ void gemm_core(const u16* __restrict__ A, int lda,
                                          const u16* __restrict__ Bt, int ldb,
                                          int K, u16* As, u16* Bs, f32x4 acc[4][4]) {
  const int tid = threadIdx.x;
  const int lane = tid & 63, wave = tid >> 6;
  const int wr = wave >> 1, wc = wave & 1;
  const int quad = lane >> 4, l16 = lane & 15;
#pragma unroll
  for (int i = 0; i < 4; ++i)
#pragma unroll
    for (int j = 0; j < 4; ++j) acc[i][j] = (f32x4){0.f, 0.f, 0.f, 0.f};

  const int row0 = tid >> 2, offc = (tid & 3) * 8;  // 128 rows x 32 k, 16B chunks
  const int nt = K >> 5;

  // prologue: tile 0
#pragma unroll
  for (int r = 0; r < 2; ++r) {
    int row = r * 64 + row0;
    async16(A + (long)row * lda + offc, As + r * 2048 + wave * 512);
    async16(Bt + (long)row * ldb + offc, Bs + r * 2048 + wave * 512);
  }

  for (int t = 0; t < nt; ++t) {
    const int bo = (t & 1) * 4096, nbo = bo ^ 4096;
    if (t + 1 < nt) {
      const int k0 = (t + 1) * 32;
#pragma unroll
      for (int r = 0; r < 2; ++r) {
        int row = r * 64 + row0;
        async16(A + (long)row * lda + k0 + offc, As + nbo + r * 2048 + wave * 512);
        async16(Bt + (long)row * ldb + k0 + offc, Bs + nbo + r * 2048 + wave * 512);
      }
      asm volatile("s_waitcnt vmcnt(4)" ::: "memory");  // tile t landed
    } else {
      asm volatile("s_waitcnt vmcnt(0)" ::: "memory");
    }
    __builtin_amdgcn_s_barrier();
    FENCE;

    frag8 af[4], bf[4];
#pragma unroll
    for (int i = 0; i < 4; ++i)
      af[i] = *(const frag8*)(As + bo + (wr * 64 + i * 16 + l16) * 32 + quad * 8);
#pragma unroll
    for (int j = 0; j < 4; ++j)
      bf[j] = *(const frag8*)(Bs + bo + (wc * 64 + j * 16 + l16) * 32 + quad * 8);
#pragma unroll
    for (int i = 0; i < 4; ++i)
#pragma unroll
      for (int j = 0; j < 4; ++j)
        acc[i][j] = __builtin_amdgcn_mfma_f32_16x16x32_bf16(af[i], bf[j], acc[i][j], 0, 0, 0);
    FENCE;
    __builtin_amdgcn_s_barrier();  // all reads of buf done before restage
  }
}

#define EPI_COORDS                                             \
  const int lane = threadIdx.x & 63, wave = threadIdx.x >> 6;  \
  const int wr = wave >> 1, wc = wave & 1;                     \
  const int quad = lane >> 4, l16 = lane & 15;

__global__ __launch_bounds__(256) void k_gemm_bf16(const u16* __restrict__ A, int lda,
                                                   const u16* __restrict__ Bt, int ldb,
                                                   u16* __restrict__ C, int ldc, int K) {
  __shared__ alignas(16) u16 smem[4 * TILE * 32];  // 2 bufs x (A,B)
  int bx, by; xcd_map(bx, by);
  f32x4 acc[4][4];
  gemm_core(A + (long)bx * TILE * lda, lda,
            Bt + (long)by * TILE * ldb, ldb, K, smem, smem + 2 * TILE * 32, acc);
  EPI_COORDS
  u16* Ct = C + (long)bx * TILE * ldc + (long)by * TILE;
#pragma unroll
  for (int i = 0; i < 4; ++i)
#pragma unroll
    for (int j = 0; j < 4; ++j) {
      int r0 = wr * 64 + i * 16 + quad * 4, cc = wc * 64 + j * 16 + l16;
#pragma unroll
      for (int r = 0; r < 4; ++r) Ct[(long)(r0 + r) * ldc + cc] = f2bf(acc[i][j][r]);
    }
}

// writes C^T: contiguous 4-element store per acc tile (for V^T layout)
__global__ __launch_bounds__(256) void k_gemm_bf16t(const u16* __restrict__ A, int lda,
                                                    const u16* __restrict__ Bt, int ldb,
                                                    u16* __restrict__ Ct, int ldct, int K) {
  __shared__ alignas(16) u16 smem[4 * TILE * 32];
  int bx, by; xcd_map(bx, by);
  f32x4 acc[4][4];
  gemm_core(A + (long)bx * TILE * lda, lda,
            Bt + (long)by * TILE * ldb, ldb, K, smem, smem + 2 * TILE * 32, acc);
  EPI_COORDS
  u16* Cb = Ct + (long)by * TILE * ldct + (long)bx * TILE;
#pragma unroll
  for (int i = 0; i < 4; ++i)
#pragma unroll
    for (int j = 0; j < 4; ++j) {
      int n = wc * 64 + j * 16 + l16, m0 = wr * 64 + i * 16 + quad * 4;
      ushort4 o;
      o.x = f2bf(acc[i][j][0]); o.y = f2bf(acc[i][j][1]);
      o.z = f2bf(acc[i][j][2]); o.w = f2bf(acc[i][j][3]);
      *(ushort4*)(Cb + (long)n * ldct + m0) = o;
    }
}

// ---- fused local-window attention (R10: 1-barrier, shuffle-free) ---------
__global__ __launch_bounds__(256, 2) void k_attn(const u16* __restrict__ qb,
                                                 const u16* __restrict__ kb,
                                                 const u16* __restrict__ vT,
                                                 u16* __restrict__ O) {
  __shared__ alignas(16) u16 Ks[2][64 * 128];  // [key][hd] swizzled, 32KB
  __shared__ alignas(16) u16 Vs[128 * 64];     // [hd][key] swizzled, 16KB
  __shared__ alignas(16) u16 Ps[4 * 32 * 64];  // wave-private P, 16KB
  const int tid = threadIdx.x, lane = tid & 63, wave = tid >> 6;
  const int quad = lane >> 4, l16 = lane & 15;

  // XCD-group decode: 16 siblings sharing (b,hk,blk) land on one XCD
  const int id = blockIdx.x + 4 * blockIdx.y + 32 * blockIdx.z;  // 0..1023
  const int g = (id & 7) | ((id >> 7) << 3);                     // group 0..63
  const int w = (id >> 3) & 15;                                  // member 0..15
  const int hk = g & 3, blk = (g >> 2) & 7, b = g >> 5;
  const int h = hk * 4 + (w & 3), qi = w >> 2;

  const long tok_q = (long)b * 4096 + blk * 512 + qi * 128;

  frag8 qf[2][4];
#pragma unroll
  for (int i = 0; i < 2; ++i)
#pragma unroll
    for (int kt = 0; kt < 4; ++kt)
      qf[i][kt] = *(const frag8*)(qb + (tok_q + wave * 32 + i * 16 + l16) * 2048 +
                                  h * 128 + kt * 32 + quad * 8);

  // ones fragment (bf16 1.0) for the l = P @ 1 column
  frag8 onef;
#pragma unroll
  for (int e = 0; e < 8; ++e) onef[e] = (short)0x3F80;

  f32x4 o_acc[2][8], l_acc[2];
  float m_r[2][4];
#pragma unroll
  for (int i = 0; i < 2; ++i) {
#pragma unroll
    for (int j = 0; j < 8; ++j) o_acc[i][j] = (f32x4){0.f, 0.f, 0.f, 0.f};
    l_acc[i] = (f32x4){0.f, 0.f, 0.f, 0.f};
#pragma unroll
    for (int r = 0; r < 4; ++r) m_r[i][r] = 0.f;  // finite start: exp2(s) direct
  }

  const int rsw = (l16 & 7) << 3;  // read-side XOR (u16)

  auto stageK = [&](int buf, int ci) {
    const long tk = (long)b * 4096 + (blk - 1) * 512 + ci * 64;
#pragma unroll
    for (int c = 0; c < 4; ++c) {
      const int idx = (wave * 4 + c) * 512 + lane * 8;  // u16 index, linear
      int row = idx >> 7, col = idx & 127;
      async16(kb + (tk + row) * 512 + hk * 128 + (col ^ ((row & 7) << 3)),
              &Ks[buf][(wave * 4 + c) * 512]);
    }
  };
  auto stageV = [&](int ci) {
    const long tk = (long)b * 4096 + (blk - 1) * 512 + ci * 64;
#pragma unroll
    for (int c = 0; c < 4; ++c) {
      const int idx = (wave * 4 + c) * 512 + lane * 8;
      int row = idx >> 6, col = idx & 63;
      async16(vT + ((long)hk * 128 + row) * 8192 + tk + (col ^ ((row & 7) << 3)),
              &Vs[(wave * 4 + c) * 512]);
    }
  };

  const int c0 = blk ? 2 * qi : 8, c1 = 9 + 2 * qi;
  int cur = 0;
  stageK(0, c0);
  stageV(c0);
  asm volatile("s_waitcnt vmcnt(0)" ::: "memory");
  __builtin_amdgcn_s_barrier();
  FENCE;

  for (int ci = c0; ci <= c1; ++ci) {
    if (ci > c0) stageV(ci);              // Vs free: prev end barrier passed
    if (ci < c1) stageK(cur ^ 1, ci + 1); // K prefetch into free buffer

    // S = Q @ K^T  (32 rows x 64 keys per wave)
    f32x4 s_acc[2][4];
#pragma unroll
    for (int i = 0; i < 2; ++i)
#pragma unroll
      for (int j = 0; j < 4; ++j) s_acc[i][j] = (f32x4){0.f, 0.f, 0.f, 0.f};
#pragma unroll
    for (int kt = 0; kt < 4; ++kt) {
      frag8 bfr[4];
#pragma unroll
      for (int j = 0; j < 4; ++j)
        bfr[j] = *(const frag8*)(&Ks[cur][(j * 16 + l16) * 128 + ((kt * 32 + quad * 8) ^ rsw)]);
#pragma unroll
      for (int i = 0; i < 2; ++i)
#pragma unroll
        for (int j = 0; j < 4; ++j)
          s_acc[i][j] = __builtin_amdgcn_mfma_f32_16x16x32_bf16(qf[i][kt], bfr[j], s_acc[i][j], 0, 0, 0);
    }

    // mask + PER-LANE partial max (no cross-lane reduce).
    const bool prev = (ci < 8);
    const int doff = (prev ? ci * 64 : (ci - 8) * 64) - qi * 128;
    float mc[2][4];
#pragma unroll
    for (int i = 0; i < 2; ++i)
#pragma unroll
      for (int r = 0; r < 4; ++r) mc[i][r] = -1e30f;
    if (doff >= 0 && doff <= 64) {  // partial chunk: apply mask
#pragma unroll
      for (int i = 0; i < 2; ++i)
#pragma unroll
        for (int j = 0; j < 4; ++j)
#pragma unroll
          for (int r = 0; r < 4; ++r) {
            int rl = wave * 32 + i * 16 + quad * 4 + r;
            int lk = j * 16 + l16;
            bool ok = prev ? (lk + doff > rl) : (lk + doff <= rl);
            float s = ok ? s_acc[i][j][r] : -1e30f;
            s_acc[i][j][r] = s;
            mc[i][r] = fmaxf(mc[i][r], s);
          }
    } else {  // interior: all keys valid
#pragma unroll
      for (int i = 0; i < 2; ++i)
#pragma unroll
        for (int j = 0; j < 4; ++j)
#pragma unroll
          for (int r = 0; r < 4; ++r) mc[i][r] = fmaxf(mc[i][r], s_acc[i][j][r]);
    }

    // defer-max gate on per-lane partials: true-max > m+8 iff __any(partial).
    bool need = false;
#pragma unroll
    for (int i = 0; i < 2; ++i)
#pragma unroll
      for (int r = 0; r < 4; ++r) need = need || (mc[i][r] > m_r[i][r] + 8.f);
    if (__any(need)) {  // rare slow path: true max + rescale (exact)
#pragma unroll
      for (int o = 1; o < 16; o <<= 1)
#pragma unroll
        for (int i = 0; i < 2; ++i)
#pragma unroll
          for (int r = 0; r < 4; ++r)
            mc[i][r] = fmaxf(mc[i][r], __shfl_xor(mc[i][r], o));
      float alpha[2][4];
#pragma unroll
      for (int i = 0; i < 2; ++i)
#pragma unroll
        for (int r = 0; r < 4; ++r) {
          float mn = fmaxf(m_r[i][r], mc[i][r]);
          alpha[i][r] = fexp2(m_r[i][r] - mn);
          m_r[i][r] = mn;
        }
#pragma unroll
      for (int i = 0; i < 2; ++i) {
#pragma unroll
        for (int j = 0; j < 8; ++j)
#pragma unroll
          for (int r = 0; r < 4; ++r) o_acc[i][j][r] *= alpha[i][r];
#pragma unroll
        for (int r = 0; r < 4; ++r) l_acc[i][r] *= alpha[i][r];
      }
    }

    // P = exp2(S - m); masked entries underflow to 0 (s = -1e30)
#pragma unroll
    for (int i = 0; i < 2; ++i)
#pragma unroll
      for (int j = 0; j < 4; ++j)
#pragma unroll
        for (int r = 0; r < 4; ++r)
          s_acc[i][j][r] = fexp2(s_acc[i][j][r] - m_r[i][r]);

    // P -> wave-private Ps region (no barrier needed)
    u16* PsW = &Ps[wave * 2048];
#pragma unroll
    for (int i = 0; i < 2; ++i)
#pragma unroll
      for (int r = 0; r < 4; ++r) {
        int xw = ((quad * 4 + r) & 7) << 3;
#pragma unroll
        for (int j = 0; j < 4; ++j)
          PsW[(i * 16 + quad * 4 + r) * 64 + ((j * 16 + l16) ^ xw)] = f2bf(s_acc[i][j][r]);
      }

    // pre-PV: V[ci] landed; K[ci+1] (newest 4) stays in flight (T4)
    if (ci < c1)
      asm volatile("s_waitcnt vmcnt(4)" ::: "memory");
    else
      asm volatile("s_waitcnt vmcnt(0)" ::: "memory");

    // O += P @ V ; l += P @ 1 (ones-column MFMA, replaces sum butterfly)
#pragma unroll
    for (int kt = 0; kt < 2; ++kt) {
      frag8 pf[2], vf[8];
#pragma unroll
      for (int i = 0; i < 2; ++i)
        pf[i] = *(const frag8*)(PsW + (i * 16 + l16) * 64 + ((kt * 32 + quad * 8) ^ rsw));
#pragma unroll
      for (int j = 0; j < 8; ++j)
        vf[j] = *(const frag8*)(&Vs[(j * 16 + l16) * 64 + ((kt * 32 + quad * 8) ^ rsw)]);
#pragma unroll
      for (int i = 0; i < 2; ++i) {
#pragma unroll
        for (int j = 0; j < 8; ++j)
          o_acc[i][j] = __builtin_amdgcn_mfma_f32_16x16x32_bf16(pf[i], vf[j], o_acc[i][j], 0, 0, 0);
        l_acc[i] = __builtin_amdgcn_mfma_f32_16x16x32_bf16(pf[i], onef, l_acc[i], 0, 0, 0);
      }
    }

    // end: K[ci+1] landed; all waves done with Ks[cur]/Vs -> restage safe
    asm volatile("s_waitcnt vmcnt(0)" ::: "memory");
    __builtin_amdgcn_s_barrier();
    FENCE;
    cur ^= 1;
  }

  float inv[2][4];
#pragma unroll
  for (int i = 0; i < 2; ++i)
#pragma unroll
    for (int r = 0; r < 4; ++r) inv[i][r] = 1.0f / l_acc[i][r];
  u16* Ob = &Ks[0][0];  // 32KB contiguous: [128 row][128 u16]
#pragma unroll
  for (int i = 0; i < 2; ++i)
#pragma unroll
    for (int j = 0; j < 8; ++j)
#pragma unroll
      for (int r = 0; r < 4; ++r)
        Ob[(wave * 32 + i * 16 + quad * 4 + r) * 128 + j * 16 + l16] =
            f2bf(o_acc[i][j][r] * inv[i][r]);
  __syncthreads();
#pragma unroll
  for (int p = 0; p < 8; ++p) {
    int idx = p * 256 + tid;
    int row = idx >> 4, col = (idx & 15) * 8;
    *(frag8*)(O + (tok_q + row) * 2048 + h * 128 + col) = *(const frag8*)(Ob + row * 128 + col);
  }
}

__global__ void k_convert(const float4* __restrict__ x, ushort4* __restrict__ xb) {
  int i = blockIdx.x * 256 + threadIdx.x;
  float4 f = x[i];
  ushort4 o;
  o.x = f2bf(f.x); o.y = f2bf(f.y); o.z = f2bf(f.z); o.w = f2bf(f.w);
  xb[i] = o;
}

// W [K,N] fp32 -> W^T [N,K] bf16
__global__ void k_transpose(const float* __restrict__ W, u16* __restrict__ WT, int K, int N) {
  __shared__ float sh[32][33];
  int n0 = blockIdx.x * 32, k0 = blockIdx.y * 32;
  int tx = threadIdx.x, ty = threadIdx.y;  // (32, 8)
#pragma unroll
  for (int i = 0; i < 32; i += 8) sh[ty + i][tx] = W[(long)(k0 + ty + i) * N + n0 + tx];
  __syncthreads();
#pragma unroll
  for (int i = 0; i < 32; i += 8) WT[(long)(n0 + ty + i) * K + k0 + tx] = f2bf(sh[tx][ty + i]);
}

extern "C" void kernel_launch(void* const* d_in, const int* in_sizes, int n_in,
                              void* d_out, int out_size, void* d_ws, size_t ws_size,
                              hipStream_t stream) {
  const float* x  = (const float*)d_in[0];
  const float* Wq = (const float*)d_in[1];
  const float* Wk = (const float*)d_in[2];
  const float* Wv = (const float*)d_in[3];
  const float* Wo = (const float*)d_in[4];
  float* out = (float*)d_out;

  const long BT = 8192, D = 2048, NKV = 512;
  size_t off = 0;
  auto alloc = [&](size_t bytes) -> char* {
    off = (off + 255) & ~(size_t)255;
    char* p = (char*)d_ws + off;
    off += bytes;
    return p;
  };

  u16* xb  = (u16*)alloc((size_t)BT * D * 2);  // reused as attention output
  u16* WqT = (u16*)alloc((size_t)D * D * 2);
  u16* WkT = (u16*)alloc((size_t)NKV * D * 2);
  u16* WvT = (u16*)alloc((size_t)NKV * D * 2);
  u16* WoT = (u16*)alloc((size_t)D * D * 2);
  u16* qb  = (u16*)alloc((size_t)BT * D * 2);
  u16* kb  = (u16*)alloc((size_t)BT * NKV * 2);
  u16* vT  = (u16*)alloc((size_t)NKV * BT * 2);
  u16* Oa  = xb;

  k_convert<<<16384, 256, 0, stream>>>((const float4*)x, (ushort4*)xb);
  dim3 tb(32, 8);
  k_transpose<<<dim3(64, 64), tb, 0, stream>>>(Wq, WqT, 2048, 2048);
  k_transpose<<<dim3(16, 64), tb, 0, stream>>>(Wk, WkT, 2048, 512);
  k_transpose<<<dim3(16, 64), tb, 0, stream>>>(Wv, WvT, 2048, 512);
  k_transpose<<<dim3(64, 64), tb, 0, stream>>>(Wo, WoT, 2048, 2048);

  // Q projection pre-scales by (1/sqrt(HD)) * log2(e)  (softmax in exp2 domain)
  const float qscale = 0.08838834764831845f * 1.4426950408889634f;
  k_gemm256<u16><<<dim3(32, 8), 512, 0, stream>>>(xb, 2048, WqT, 2048, qb, 2048, 2048,
                                                  qscale);
  k_gemm_bf16 <<<dim3(64, 4),  256, 0, stream>>>(xb, 2048, WkT, 2048, kb, 512, 2048);
  k_gemm_bf16t<<<dim3(64, 4),  256, 0, stream>>>(xb, 2048, WvT, 2048, vT, 8192, 2048);

  k_attn<<<dim3(4, 8, 32), 256, 0, stream>>>(qb, kb, vT, Oa);

  k_gemm256<float><<<dim3(32, 8), 512, 0, stream>>>(Oa, 2048, WoT, 2048, out, 2048, 2048,
                                                    1.0f);
}

// Round 11
// 384.161 us; speedup vs baseline: 1.4191x; 1.0539x over previous
//
#include <hip/hip_runtime.h>
#include <stdint.h>

// LocalWindowAttention: B=2,T=4096,D=2048,H=16,HK=4,HD=128,WIN=512
// R13: launch-count reduction (10 -> 5 dispatches; ~100us of the 405 total
//      was unaccounted = launch gaps):
//      (1) k_prep: convert + all 4 weight transposes in ONE flat-grid
//          kernel (block-uniform branch on blockIdx range).
//      (2) k_gemm_kv: K and V projections fused in one launch, grid
//          (64,8) = 512 blocks = 2 blocks/CU (each was 256 blocks = 1/CU,
//          half-occupancy, serialized). by<4 -> kb, by>=4 -> vT^T store.
//      gemm256 (R12 phase schedule) and attn (R10) unchanged.

typedef unsigned short u16;
typedef __attribute__((ext_vector_type(8))) short frag8;   // 8 bf16 = 4 VGPRs
typedef __attribute__((ext_vector_type(4))) float f32x4;   // MFMA acc

#define TILE 128

__device__ __forceinline__ u16 f2bf(float f) {
  union { float f; unsigned u; } c; c.f = f;
  unsigned u = c.u;
  return (u16)((u + 0x7fffu + ((u >> 16) & 1u)) >> 16);
}

__device__ __forceinline__ float fexp2(float x) {  // D = 2^S0 (v_exp_f32)
  float r;
  asm("v_exp_f32 %0, %1" : "=v"(r) : "v"(x));
  return r;
}

// async global->LDS, 16B per lane; LDS dest = wave-uniform base + lane*16
__device__ __forceinline__ void async16(const u16* g, u16* l) {
  __builtin_amdgcn_global_load_lds((const __attribute__((address_space(1))) void*)g,
                                   (__attribute__((address_space(3))) void*)l, 16, 0, 0);
}

// T1: XCD-chunked remap. Requires (gridDim.x*gridDim.y) % 8 == 0.
__device__ __forceinline__ void xcd_map(int& bx, int& by) {
  const int gx = gridDim.x;
  const int cx = gx >> 3;
  int id = blockIdx.y * gx + blockIdx.x;
  int xcd = id & 7, local = id >> 3;
  bx = xcd * cx + (local % cx);
  by = local / cx;
}

#define FENCE asm volatile("" ::: "memory")

// ======================= 256^2 GEMM (m201 phase schedule) ================
// A [M,K] row-major bf16, Bt = B^T [N,K] row-major bf16, C [M,N] (u16|f32).
// Tile 256x256, BK=64, dbuf. LDS [256 rows][64 k] with col^=(row&7)<<3
// swizzle via inverse-swizzled global src (linear gload_lds dest).
template <typename OutT>
__global__ __launch_bounds__(512, 2) void k_gemm256(const u16* __restrict__ A, int lda,
                                                    const u16* __restrict__ Bt, int ldb,
                                                    OutT* __restrict__ C, int ldc, int K,
                                                    float oscale) {
  __shared__ alignas(16) u16 Ab[2][256 * 64];  // 64 KB
  __shared__ alignas(16) u16 Bb[2][256 * 64];  // 64 KB
  const int tid = threadIdx.x, lane = tid & 63, wave = tid >> 6;
  const int wm = wave >> 2, wn = wave & 3;     // 2M x 4N wave grid
  const int quad = lane >> 4, l16 = lane & 15;

  int bx, by;
  xcd_map(bx, by);

  // staging coords: issue c, wave w, lane l -> row = c*64+w*8+(l>>3),
  // src col = ((l&7)^(l>>3))*8  (row&7 == l>>3 -> involution holds)
  const int rsub = wave * 8 + (lane >> 3);
  const int csub = ((lane & 7) ^ (lane >> 3)) * 8;
  const u16* Ag = A + ((long)bx * 256 + rsub) * lda + csub;
  const u16* Bg = Bt + ((long)by * 256 + rsub) * ldb + csub;
  const long a64 = (long)64 * lda, b64 = (long)64 * ldb;

  const int rsw = (l16 & 7) << 3;  // read-side XOR (u16 units)

  f32x4 acc[8][4];
#pragma unroll
  for (int i = 0; i < 8; ++i)
#pragma unroll
    for (int j = 0; j < 4; ++j) acc[i][j] = (f32x4){0.f, 0.f, 0.f, 0.f};

  const int nt = K >> 6;

  // prologue: stage tiles 0 and 1 (16 loads/wave); tile 0 landed -> publish
#pragma unroll
  for (int c = 0; c < 4; ++c) {
    async16(Ag + c * a64, &Ab[0][c * 4096 + wave * 512]);
    async16(Bg + c * b64, &Bb[0][c * 4096 + wave * 512]);
  }
#pragma unroll
  for (int c = 0; c < 4; ++c) {
    async16(Ag + c * a64 + 64, &Ab[1][c * 4096 + wave * 512]);
    async16(Bg + c * b64 + 64, &Bb[1][c * 4096 + wave * 512]);
  }
  asm volatile("s_waitcnt vmcnt(8)" ::: "memory");  // tile 0 fully landed
  __builtin_amdgcn_s_barrier();
  FENCE;

  for (int t = 0; t < nt; ++t) {
    const int buf = t & 1;
    const bool st = (t + 2 < nt);
    const long koff = (long)(t + 2) << 6;
    frag8 af_lo[4][2], af_hi[4][2], bf_lo[2][2], bf_hi[2][2];

    // ---- phase 0: read af_lo(8) + bf_lo(4); MFMA quadrant (M0,N0) -------
#pragma unroll
    for (int i = 0; i < 4; ++i)
#pragma unroll
      for (int kk = 0; kk < 2; ++kk)
        af_lo[i][kk] = *(const frag8*)(&Ab[buf][(wm * 128 + i * 16 + l16) * 64 +
                                               ((kk * 32 + quad * 8) ^ rsw)]);
#pragma unroll
    for (int j = 0; j < 2; ++j)
#pragma unroll
      for (int kk = 0; kk < 2; ++kk)
        bf_lo[j][kk] = *(const frag8*)(&Bb[buf][(wn * 64 + j * 16 + l16) * 64 +
                                               ((kk * 32 + quad * 8) ^ rsw)]);
    FENCE;
    __builtin_amdgcn_s_barrier();
    FENCE;
    __builtin_amdgcn_s_setprio(1);
#pragma unroll
    for (int kk = 0; kk < 2; ++kk)
#pragma unroll
      for (int i = 0; i < 4; ++i)
#pragma unroll
        for (int j = 0; j < 2; ++j)
          acc[i][j] = __builtin_amdgcn_mfma_f32_16x16x32_bf16(af_lo[i][kk], bf_lo[j][kk], acc[i][j], 0, 0, 0);
    __builtin_amdgcn_s_setprio(0);
    FENCE;
    __builtin_amdgcn_s_barrier();
    FENCE;

    // ---- phase 1: read af_hi(8); MFMA (M1,N0) — reuse bf_lo -------------
#pragma unroll
    for (int i = 0; i < 4; ++i)
#pragma unroll
      for (int kk = 0; kk < 2; ++kk)
        af_hi[i][kk] = *(const frag8*)(&Ab[buf][(wm * 128 + (i + 4) * 16 + l16) * 64 +
                                               ((kk * 32 + quad * 8) ^ rsw)]);
    FENCE;
    __builtin_amdgcn_s_barrier();
    FENCE;
    __builtin_amdgcn_s_setprio(1);
#pragma unroll
    for (int kk = 0; kk < 2; ++kk)
#pragma unroll
      for (int i = 0; i < 4; ++i)
#pragma unroll
        for (int j = 0; j < 2; ++j)
          acc[i + 4][j] = __builtin_amdgcn_mfma_f32_16x16x32_bf16(af_hi[i][kk], bf_lo[j][kk], acc[i + 4][j], 0, 0, 0);
    __builtin_amdgcn_s_setprio(0);
    FENCE;
    __builtin_amdgcn_s_barrier();
    FENCE;

    // ---- phase 2: read bf_hi(4); stage A(t+2) (A-region read-free since
    //      p1 end barrier); MFMA (M0,N1) — reuse af_lo --------------------
#pragma unroll
    for (int j = 0; j < 2; ++j)
#pragma unroll
      for (int kk = 0; kk < 2; ++kk)
        bf_hi[j][kk] = *(const frag8*)(&Bb[buf][(wn * 64 + (j + 2) * 16 + l16) * 64 +
                                               ((kk * 32 + quad * 8) ^ rsw)]);
    if (st) {
#pragma unroll
      for (int c = 0; c < 4; ++c)
        async16(Ag + c * a64 + koff, &Ab[buf][c * 4096 + wave * 512]);
    }
    FENCE;
    __builtin_amdgcn_s_barrier();
    FENCE;
    __builtin_amdgcn_s_setprio(1);
#pragma unroll
    for (int kk = 0; kk < 2; ++kk)
#pragma unroll
      for (int i = 0; i < 4; ++i)
#pragma unroll
        for (int j = 0; j < 2; ++j)
          acc[i][j + 2] = __builtin_amdgcn_mfma_f32_16x16x32_bf16(af_lo[i][kk], bf_hi[j][kk], acc[i][j + 2], 0, 0, 0);
    __builtin_amdgcn_s_setprio(0);
    FENCE;
    __builtin_amdgcn_s_barrier();
    FENCE;

    // ---- phase 3: stage B(t+2) (B-region read-free since p2 end);
    //      MFMA (M1,N1); vmcnt(8) -> tile t+1 landed; end bar publishes ---
    if (st) {
#pragma unroll
      for (int c = 0; c < 4; ++c)
        async16(Bg + c * b64 + koff, &Bb[buf][c * 4096 + wave * 512]);
    }
    FENCE;
    __builtin_amdgcn_s_barrier();
    FENCE;
    __builtin_amdgcn_s_setprio(1);
#pragma unroll
    for (int kk = 0; kk < 2; ++kk)
#pragma unroll
      for (int i = 0; i < 4; ++i)
#pragma unroll
        for (int j = 0; j < 2; ++j)
          acc[i + 4][j + 2] = __builtin_amdgcn_mfma_f32_16x16x32_bf16(af_hi[i][kk], bf_hi[j][kk], acc[i + 4][j + 2], 0, 0, 0);
    __builtin_amdgcn_s_setprio(0);
    if (st)
      asm volatile("s_waitcnt vmcnt(8)" ::: "memory");  // t+1 landed; t+2 in flight
    else
      asm volatile("s_waitcnt vmcnt(0)" ::: "memory");
    __builtin_amdgcn_s_barrier();
    FENCE;
  }

  // epilogue (oscale folded; used to pre-scale Q)
  OutT* Ct = C + ((long)bx * 256 + wm * 128) * ldc + (long)by * 256 + wn * 64;
#pragma unroll
  for (int i = 0; i < 8; ++i)
#pragma unroll
    for (int j = 0; j < 4; ++j) {
      int r0 = i * 16 + quad * 4, cc = j * 16 + l16;
#pragma unroll
      for (int r = 0; r < 4; ++r) {
        float v = acc[i][j][r] * oscale;
        if constexpr (sizeof(OutT) == 2)
          Ct[(long)(r0 + r) * ldc + cc] = f2bf(v);
        else
          Ct[(long)(r0 + r) * ldc + cc] = v;
      }
    }
}

// ---- 128x128 GEMM core, double-buffered + counted vmcnt (T3-min) --------
__device__ __forceinline__ void gemm_core(const u16* __restrict__ A, int lda,
                                          const u16* __restrict__ Bt, int ldb,
                                          int K, u16* As, u16* Bs, f32x4 acc[4][4]) {
  const int tid = threadIdx.x;
  const int lane = tid & 63, wave = tid >> 6;
  const int wr = wave >> 1, wc = wave & 1;
  const int quad = lane >> 4, l16 = lane & 15;
#pragma unroll
  for (int i = 0; i < 4; ++i)
#pragma unroll
    for (int j = 0; j < 4; ++j) acc[i][j] = (f32x4){0.f, 0.f, 0.f, 0.f};

  const int row0 = tid >> 2, offc = (tid & 3) * 8;  // 128 rows x 32 k, 16B chunks
  const int nt = K >> 5;

  // prologue: tile 0
#pragma unroll
  for (int r = 0; r < 2; ++r) {
    int row = r * 64 + row0;
    async16(A + (long)row * lda + offc, As + r * 2048 + wave * 512);
    async16(Bt + (long)row * ldb + offc, Bs + r * 2048 + wave * 512);
  }

  for (int t = 0; t < nt; ++t) {
    const int bo = (t & 1) * 4096, nbo = bo ^ 4096;
    if (t + 1 < nt) {
      const int k0 = (t + 1) * 32;
#pragma unroll
      for (int r = 0; r < 2; ++r) {
        int row = r * 64 + row0;
        async16(A + (long)row * lda + k0 + offc, As + nbo + r * 2048 + wave * 512);
        async16(Bt + (long)row * ldb + k0 + offc, Bs + nbo + r * 2048 + wave * 512);
      }
      asm volatile("s_waitcnt vmcnt(4)" ::: "memory");  // tile t landed
    } else {
      asm volatile("s_waitcnt vmcnt(0)" ::: "memory");
    }
    __builtin_amdgcn_s_barrier();
    FENCE;

    frag8 af[4], bf[4];
#pragma unroll
    for (int i = 0; i < 4; ++i)
      af[i] = *(const frag8*)(As + bo + (wr * 64 + i * 16 + l16) * 32 + quad * 8);
#pragma unroll
    for (int j = 0; j < 4; ++j)
      bf[j] = *(const frag8*)(Bs + bo + (wc * 64 + j * 16 + l16) * 32 + quad * 8);
#pragma unroll
    for (int i = 0; i < 4; ++i)
#pragma unroll
      for (int j = 0; j < 4; ++j)
        acc[i][j] = __builtin_amdgcn_mfma_f32_16x16x32_bf16(af[i], bf[j], acc[i][j], 0, 0, 0);
    FENCE;
    __builtin_amdgcn_s_barrier();  // all reads of buf done before restage
  }
}

// ---- fused K+V projection: grid (64,8); by<4 -> kb, by>=4 -> vT^T -------
__global__ __launch_bounds__(256) void k_gemm_kv(const u16* __restrict__ A,
                                                 const u16* __restrict__ WkT,
                                                 const u16* __restrict__ WvT,
                                                 u16* __restrict__ kb,
                                                 u16* __restrict__ vT) {
  __shared__ alignas(16) u16 smem[4 * TILE * 32];  // 2 bufs x (A,B)
  int bx, by; xcd_map(bx, by);                     // 512 blocks, %8==0
  const bool isV = (by >= 4);
  const int byl = isV ? by - 4 : by;
  const u16* Bt = (isV ? WvT : WkT) + (long)byl * TILE * 2048;
  f32x4 acc[4][4];
  gemm_core(A + (long)bx * TILE * 2048, 2048, Bt, 2048, 2048,
            smem, smem + 2 * TILE * 32, acc);
  const int lane = threadIdx.x & 63, wave = threadIdx.x >> 6;
  const int wr = wave >> 1, wc = wave & 1;
  const int quad = lane >> 4, l16 = lane & 15;
  if (!isV) {  // kb [8192][512]
    u16* Ct = kb + (long)bx * TILE * 512 + (long)byl * TILE;
#pragma unroll
    for (int i = 0; i < 4; ++i)
#pragma unroll
      for (int j = 0; j < 4; ++j) {
        int r0 = wr * 64 + i * 16 + quad * 4, cc = wc * 64 + j * 16 + l16;
#pragma unroll
        for (int r = 0; r < 4; ++r) Ct[(long)(r0 + r) * 512 + cc] = f2bf(acc[i][j][r]);
      }
  } else {  // vT [512][8192] (C^T: contiguous 4-elem store along m)
    u16* Cb = vT + (long)byl * TILE * 8192 + (long)bx * TILE;
#pragma unroll
    for (int i = 0; i < 4; ++i)
#pragma unroll
      for (int j = 0; j < 4; ++j) {
        int n = wc * 64 + j * 16 + l16, m0 = wr * 64 + i * 16 + quad * 4;
        ushort4 o;
        o.x = f2bf(acc[i][j][0]); o.y = f2bf(acc[i][j][1]);
        o.z = f2bf(acc[i][j][2]); o.w = f2bf(acc[i][j][3]);
        *(ushort4*)(Cb + (long)n * 8192 + m0) = o;
      }
  }
}

// ---- fused local-window attention (R10: 1-barrier, shuffle-free) ---------
__global__ __launch_bounds__(256, 2) void k_attn(const u16* __restrict__ qb,
                                                 const u16* __restrict__ kb,
                                                 const u16* __restrict__ vT,
                                                 u16* __restrict__ O) {
  __shared__ alignas(16) u16 Ks[2][64 * 128];  // [key][hd] swizzled, 32KB
  __shared__ alignas(16) u16 Vs[128 * 64];     // [hd][key] swizzled, 16KB
  __shared__ alignas(16) u16 Ps[4 * 32 * 64];  // wave-private P, 16KB
  const int tid = threadIdx.x, lane = tid & 63, wave = tid >> 6;
  const int quad = lane >> 4, l16 = lane & 15;

  // XCD-group decode: 16 siblings sharing (b,hk,blk) land on one XCD
  const int id = blockIdx.x + 4 * blockIdx.y + 32 * blockIdx.z;  // 0..1023
  const int g = (id & 7) | ((id >> 7) << 3);                     // group 0..63
  const int w = (id >> 3) & 15;                                  // member 0..15
  const int hk = g & 3, blk = (g >> 2) & 7, b = g >> 5;
  const int h = hk * 4 + (w & 3), qi = w >> 2;

  const long tok_q = (long)b * 4096 + blk * 512 + qi * 128;

  frag8 qf[2][4];
#pragma unroll
  for (int i = 0; i < 2; ++i)
#pragma unroll
    for (int kt = 0; kt < 4; ++kt)
      qf[i][kt] = *(const frag8*)(qb + (tok_q + wave * 32 + i * 16 + l16) * 2048 +
                                  h * 128 + kt * 32 + quad * 8);

  // ones fragment (bf16 1.0) for the l = P @ 1 column
  frag8 onef;
#pragma unroll
  for (int e = 0; e < 8; ++e) onef[e] = (short)0x3F80;

  f32x4 o_acc[2][8], l_acc[2];
  float m_r[2][4];
#pragma unroll
  for (int i = 0; i < 2; ++i) {
#pragma unroll
    for (int j = 0; j < 8; ++j) o_acc[i][j] = (f32x4){0.f, 0.f, 0.f, 0.f};
    l_acc[i] = (f32x4){0.f, 0.f, 0.f, 0.f};
#pragma unroll
    for (int r = 0; r < 4; ++r) m_r[i][r] = 0.f;  // finite start: exp2(s) direct
  }

  const int rsw = (l16 & 7) << 3;  // read-side XOR (u16)

  auto stageK = [&](int buf, int ci) {
    const long tk = (long)b * 4096 + (blk - 1) * 512 + ci * 64;
#pragma unroll
    for (int c = 0; c < 4; ++c) {
      const int idx = (wave * 4 + c) * 512 + lane * 8;  // u16 index, linear
      int row = idx >> 7, col = idx & 127;
      async16(kb + (tk + row) * 512 + hk * 128 + (col ^ ((row & 7) << 3)),
              &Ks[buf][(wave * 4 + c) * 512]);
    }
  };
  auto stageV = [&](int ci) {
    const long tk = (long)b * 4096 + (blk - 1) * 512 + ci * 64;
#pragma unroll
    for (int c = 0; c < 4; ++c) {
      const int idx = (wave * 4 + c) * 512 + lane * 8;
      int row = idx >> 6, col = idx & 63;
      async16(vT + ((long)hk * 128 + row) * 8192 + tk + (col ^ ((row & 7) << 3)),
              &Vs[(wave * 4 + c) * 512]);
    }
  };

  const int c0 = blk ? 2 * qi : 8, c1 = 9 + 2 * qi;
  int cur = 0;
  stageK(0, c0);
  stageV(c0);
  asm volatile("s_waitcnt vmcnt(0)" ::: "memory");
  __builtin_amdgcn_s_barrier();
  FENCE;

  for (int ci = c0; ci <= c1; ++ci) {
    if (ci > c0) stageV(ci);              // Vs free: prev end barrier passed
    if (ci < c1) stageK(cur ^ 1, ci + 1); // K prefetch into free buffer

    // S = Q @ K^T  (32 rows x 64 keys per wave)
    f32x4 s_acc[2][4];
#pragma unroll
    for (int i = 0; i < 2; ++i)
#pragma unroll
      for (int j = 0; j < 4; ++j) s_acc[i][j] = (f32x4){0.f, 0.f, 0.f, 0.f};
#pragma unroll
    for (int kt = 0; kt < 4; ++kt) {
      frag8 bfr[4];
#pragma unroll
      for (int j = 0; j < 4; ++j)
        bfr[j] = *(const frag8*)(&Ks[cur][(j * 16 + l16) * 128 + ((kt * 32 + quad * 8) ^ rsw)]);
#pragma unroll
      for (int i = 0; i < 2; ++i)
#pragma unroll
        for (int j = 0; j < 4; ++j)
          s_acc[i][j] = __builtin_amdgcn_mfma_f32_16x16x32_bf16(qf[i][kt], bfr[j], s_acc[i][j], 0, 0, 0);
    }

    // mask + PER-LANE partial max (no cross-lane reduce).
    const bool prev = (ci < 8);
    const int doff = (prev ? ci * 64 : (ci - 8) * 64) - qi * 128;
    float mc[2][4];
#pragma unroll
    for (int i = 0; i < 2; ++i)
#pragma unroll
      for (int r = 0; r < 4; ++r) mc[i][r] = -1e30f;
    if (doff >= 0 && doff <= 64) {  // partial chunk: apply mask
#pragma unroll
      for (int i = 0; i < 2; ++i)
#pragma unroll
        for (int j = 0; j < 4; ++j)
#pragma unroll
          for (int r = 0; r < 4; ++r) {
            int rl = wave * 32 + i * 16 + quad * 4 + r;
            int lk = j * 16 + l16;
            bool ok = prev ? (lk + doff > rl) : (lk + doff <= rl);
            float s = ok ? s_acc[i][j][r] : -1e30f;
            s_acc[i][j][r] = s;
            mc[i][r] = fmaxf(mc[i][r], s);
          }
    } else {  // interior: all keys valid
#pragma unroll
      for (int i = 0; i < 2; ++i)
#pragma unroll
        for (int j = 0; j < 4; ++j)
#pragma unroll
          for (int r = 0; r < 4; ++r) mc[i][r] = fmaxf(mc[i][r], s_acc[i][j][r]);
    }

    // defer-max gate on per-lane partials: true-max > m+8 iff __any(partial).
    bool need = false;
#pragma unroll
    for (int i = 0; i < 2; ++i)
#pragma unroll
      for (int r = 0; r < 4; ++r) need = need || (mc[i][r] > m_r[i][r] + 8.f);
    if (__any(need)) {  // rare slow path: true max + rescale (exact)
#pragma unroll
      for (int o = 1; o < 16; o <<= 1)
#pragma unroll
        for (int i = 0; i < 2; ++i)
#pragma unroll
          for (int r = 0; r < 4; ++r)
            mc[i][r] = fmaxf(mc[i][r], __shfl_xor(mc[i][r], o));
      float alpha[2][4];
#pragma unroll
      for (int i = 0; i < 2; ++i)
#pragma unroll
        for (int r = 0; r < 4; ++r) {
          float mn = fmaxf(m_r[i][r], mc[i][r]);
          alpha[i][r] = fexp2(m_r[i][r] - mn);
          m_r[i][r] = mn;
        }
#pragma unroll
      for (int i = 0; i < 2; ++i) {
#pragma unroll
        for (int j = 0; j < 8; ++j)
#pragma unroll
          for (int r = 0; r < 4; ++r) o_acc[i][j][r] *= alpha[i][r];
#pragma unroll
        for (int r = 0; r < 4; ++r) l_acc[i][r] *= alpha[i][r];
      }
    }

    // P = exp2(S - m); masked entries underflow to 0 (s = -1e30)
#pragma unroll
    for (int i = 0; i < 2; ++i)
#pragma unroll
      for (int j = 0; j < 4; ++j)
#pragma unroll
        for (int r = 0; r < 4; ++r)
          s_acc[i][j][r] = fexp2(s_acc[i][j][r] - m_r[i][r]);

    // P -> wave-private Ps region (no barrier needed)
    u16* PsW = &Ps[wave * 2048];
#pragma unroll
    for (int i = 0; i < 2; ++i)
#pragma unroll
      for (int r = 0; r < 4; ++r) {
        int xw = ((quad * 4 + r) & 7) << 3;
#pragma unroll
        for (int j = 0; j < 4; ++j)
          PsW[(i * 16 + quad * 4 + r) * 64 + ((j * 16 + l16) ^ xw)] = f2bf(s_acc[i][j][r]);
      }

    // pre-PV: V[ci] landed; K[ci+1] (newest 4) stays in flight (T4)
    if (ci < c1)
      asm volatile("s_waitcnt vmcnt(4)" ::: "memory");
    else
      asm volatile("s_waitcnt vmcnt(0)" ::: "memory");

    // O += P @ V ; l += P @ 1 (ones-column MFMA, replaces sum butterfly)
#pragma unroll
    for (int kt = 0; kt < 2; ++kt) {
      frag8 pf[2], vf[8];
#pragma unroll
      for (int i = 0; i < 2; ++i)
        pf[i] = *(const frag8*)(PsW + (i * 16 + l16) * 64 + ((kt * 32 + quad * 8) ^ rsw));
#pragma unroll
      for (int j = 0; j < 8; ++j)
        vf[j] = *(const frag8*)(&Vs[(j * 16 + l16) * 64 + ((kt * 32 + quad * 8) ^ rsw)]);
#pragma unroll
      for (int i = 0; i < 2; ++i) {
#pragma unroll
        for (int j = 0; j < 8; ++j)
          o_acc[i][j] = __builtin_amdgcn_mfma_f32_16x16x32_bf16(pf[i], vf[j], o_acc[i][j], 0, 0, 0);
        l_acc[i] = __builtin_amdgcn_mfma_f32_16x16x32_bf16(pf[i], onef, l_acc[i], 0, 0, 0);
      }
    }

    // end: K[ci+1] landed; all waves done with Ks[cur]/Vs -> restage safe
    asm volatile("s_waitcnt vmcnt(0)" ::: "memory");
    __builtin_amdgcn_s_barrier();
    FENCE;
    cur ^= 1;
  }

  float inv[2][4];
#pragma unroll
  for (int i = 0; i < 2; ++i)
#pragma unroll
    for (int r = 0; r < 4; ++r) inv[i][r] = 1.0f / l_acc[i][r];
  u16* Ob = &Ks[0][0];  // 32KB contiguous: [128 row][128 u16]
#pragma unroll
  for (int i = 0; i < 2; ++i)
#pragma unroll
    for (int j = 0; j < 8; ++j)
#pragma unroll
      for (int r = 0; r < 4; ++r)
        Ob[(wave * 32 + i * 16 + quad * 4 + r) * 128 + j * 16 + l16] =
            f2bf(o_acc[i][j][r] * inv[i][r]);
  __syncthreads();
#pragma unroll
  for (int p = 0; p < 8; ++p) {
    int idx = p * 256 + tid;
    int row = idx >> 4, col = (idx & 15) * 8;
    *(frag8*)(O + (tok_q + row) * 2048 + h * 128 + col) = *(const frag8*)(Ob + row * 128 + col);
  }
}

// ---- fused preprocessing: convert + all 4 weight transposes --------------
// grid: [0,16384)          convert x (fp32) -> xb (bf16), float4 granules
//       [16384,20480)      Wq transpose  (64x64 tiles of 32)
//       [20480,21504)      Wk transpose  (16x64)
//       [21504,22528)      Wv transpose  (16x64)
//       [22528,26624)      Wo transpose  (64x64)
// Branch is block-uniform -> __syncthreads inside is legal.
__global__ __launch_bounds__(256) void k_prep(const float4* __restrict__ x4,
                                              ushort4* __restrict__ xb4,
                                              const float* __restrict__ Wq, u16* __restrict__ WqT,
                                              const float* __restrict__ Wk, u16* __restrict__ WkT,
                                              const float* __restrict__ Wv, u16* __restrict__ WvT,
                                              const float* __restrict__ Wo, u16* __restrict__ WoT) {
  int bid = blockIdx.x;
  const int tid = threadIdx.x;
  if (bid < 16384) {
    int i = bid * 256 + tid;
    float4 f = x4[i];
    ushort4 o;
    o.x = f2bf(f.x); o.y = f2bf(f.y); o.z = f2bf(f.z); o.w = f2bf(f.w);
    xb4[i] = o;
    return;
  }
  bid -= 16384;
  const float* W; u16* WT; int N, bx, byk;
  if (bid < 4096)       { W = Wq; WT = WqT; N = 2048; bx = bid & 63; byk = bid >> 6; }
  else if (bid < 5120)  { bid -= 4096; W = Wk; WT = WkT; N = 512; bx = bid & 15; byk = bid >> 4; }
  else if (bid < 6144)  { bid -= 5120; W = Wv; WT = WvT; N = 512; bx = bid & 15; byk = bid >> 4; }
  else                  { bid -= 6144; W = Wo; WT = WoT; N = 2048; bx = bid & 63; byk = bid >> 6; }
  __shared__ float sh[32][33];
  const int n0 = bx * 32, k0 = byk * 32;
  const int tx = tid & 31, ty = tid >> 5;  // 32 x 8
#pragma unroll
  for (int i = 0; i < 32; i += 8) sh[ty + i][tx] = W[(long)(k0 + ty + i) * N + n0 + tx];
  __syncthreads();
#pragma unroll
  for (int i = 0; i < 32; i += 8) WT[(long)(n0 + ty + i) * 2048 + k0 + tx] = f2bf(sh[tx][ty + i]);
}

extern "C" void kernel_launch(void* const* d_in, const int* in_sizes, int n_in,
                              void* d_out, int out_size, void* d_ws, size_t ws_size,
                              hipStream_t stream) {
  const float* x  = (const float*)d_in[0];
  const float* Wq = (const float*)d_in[1];
  const float* Wk = (const float*)d_in[2];
  const float* Wv = (const float*)d_in[3];
  const float* Wo = (const float*)d_in[4];
  float* out = (float*)d_out;

  const long BT = 8192, D = 2048, NKV = 512;
  size_t off = 0;
  auto alloc = [&](size_t bytes) -> char* {
    off = (off + 255) & ~(size_t)255;
    char* p = (char*)d_ws + off;
    off += bytes;
    return p;
  };

  u16* xb  = (u16*)alloc((size_t)BT * D * 2);  // reused as attention output
  u16* WqT = (u16*)alloc((size_t)D * D * 2);
  u16* WkT = (u16*)alloc((size_t)NKV * D * 2);
  u16* WvT = (u16*)alloc((size_t)NKV * D * 2);
  u16* WoT = (u16*)alloc((size_t)D * D * 2);
  u16* qb  = (u16*)alloc((size_t)BT * D * 2);
  u16* kb  = (u16*)alloc((size_t)BT * NKV * 2);
  u16* vT  = (u16*)alloc((size_t)NKV * BT * 2);
  u16* Oa  = xb;

  k_prep<<<26624, 256, 0, stream>>>((const float4*)x, (ushort4*)xb,
                                    Wq, WqT, Wk, WkT, Wv, WvT, Wo, WoT);

  // Q projection pre-scales by (1/sqrt(HD)) * log2(e)  (softmax in exp2 domain)
  const float qscale = 0.08838834764831845f * 1.4426950408889634f;
  k_gemm256<u16><<<dim3(32, 8), 512, 0, stream>>>(xb, 2048, WqT, 2048, qb, 2048, 2048,
                                                  qscale);
  k_gemm_kv<<<dim3(64, 8), 256, 0, stream>>>(xb, WkT, WvT, kb, vT);

  k_attn<<<dim3(4, 8, 32), 256, 0, stream>>>(qb, kb, vT, Oa);

  k_gemm256<float><<<dim3(32, 8), 512, 0, stream>>>(Oa, 2048, WoT, 2048, out, 2048, 2048,
                                                    1.0f);
}